// Round 1
// 2085.064 us; speedup vs baseline: 1.1185x; 1.1185x over previous
//
#include <hip/hip_runtime.h>
#include <hip/hip_bf16.h>
#include <stdint.h>

// Problem constants
#define B_ 4
#define T_ 2048
#define C_ 2048
#define H_ 16
#define DK_ 64
#define DV_ 128
#define BT_ (B_ * T_)   // 8192

typedef __attribute__((ext_vector_type(8))) __bf16 bf16x8;
typedef __attribute__((ext_vector_type(4))) float f32x4;

__device__ __forceinline__ unsigned short f2bf(float f) {
    union { float f; uint32_t u; } v; v.f = f;
    uint32_t u = v.u;
    uint32_t r = u + 0x7FFFu + ((u >> 16) & 1u);   // RNE
    return (unsigned short)(r >> 16);
}
__device__ __forceinline__ float bf2f(unsigned short h) {
    union { uint32_t u; float f; } v; v.u = ((uint32_t)h) << 16; return v.f;
}
__device__ __forceinline__ float siluf(float x) { return x / (1.f + expf(-x)); }

// DPP quad-reduce helpers: sum across the 4 lanes of a quad (lanes grouped as tid&3).
// quad_perm(1,0,3,2) = 0xB1 (xor 1), quad_perm(2,3,0,1) = 0x4E (xor 2).
// VALU-only (~8 cy) vs ds_swizzle-based __shfl_xor (~40-60 cy + lgkmcnt serialization).
__device__ __forceinline__ float dpp_xor1_add(float x) {
    int t = __builtin_amdgcn_update_dpp(0, __float_as_int(x), 0xB1, 0xF, 0xF, true);
    return x + __int_as_float(t);
}
__device__ __forceinline__ float dpp_xor2_add(float x) {
    int t = __builtin_amdgcn_update_dpp(0, __float_as_int(x), 0x4E, 0xF, 0xF, true);
    return x + __int_as_float(t);
}

// hi = RNE bf16 of x; lo = trunc bf16 of (x - hi). x ≈ hi + lo to ~2^-17 rel.
__device__ __forceinline__ void split_hl(float x, unsigned short& h, unsigned short& l) {
    unsigned short hu = f2bf(x);
    float lo = x - bf2f(hu);
    h = hu;
    l = (unsigned short)(__float_as_uint(lo) >> 16);
}

// ---------------------------------------------------------------- casts
__global__ void cast_split_k(const float* __restrict__ in,
                             unsigned short* __restrict__ oh, unsigned short* __restrict__ ol, int n4) {
    int i = blockIdx.x * blockDim.x + threadIdx.x;
    if (i >= n4) return;
    float4 v = ((const float4*)in)[i];
    ushort4 h, l;
    split_hl(v.x, h.x, l.x); split_hl(v.y, h.y, l.y);
    split_hl(v.z, h.z, l.z); split_hl(v.w, h.w, l.w);
    ((ushort4*)oh)[i] = h;
    ((ushort4*)ol)[i] = l;
}

__global__ void cast_plain_k(const float* __restrict__ in, unsigned short* __restrict__ out, int n4) {
    int i = blockIdx.x * blockDim.x + threadIdx.x;
    if (i >= n4) return;
    float4 v = ((const float4*)in)[i];
    ushort4 o;
    o.x = f2bf(v.x); o.y = f2bf(v.y); o.z = f2bf(v.z); o.w = f2bf(v.w);
    ((ushort4*)out)[i] = o;
}

// ---------------------------------------------------------------- async global->LDS (16B/lane)
__device__ __forceinline__ void gld_lds16(const unsigned short* gptr,
                                          unsigned short* lds_base) {
    __builtin_amdgcn_global_load_lds(
        (const __attribute__((address_space(1))) uint32_t*)(uintptr_t)gptr,
        (__attribute__((address_space(3))) uint32_t*)(uint32_t)(uintptr_t)lds_base,
        16, 0, 0);
}

// ---------------------------------------------------------------- split-precision GEMM
// C[M,N] = A[M,K](f32) * W[N,K]^T where W pre-split (Wh+Wl bf16). A split to hi/lo
// bf16 at staging. DO_LO: 3-pass (AhWh+AhWl+AlWh, ~1e-4 rel); else hi-only bf16 GEMM.
template<bool DO_LO, bool F32OUT>
__global__ __launch_bounds__(256)
void gemm_split(const float* __restrict__ A, int lda,
                const unsigned short* __restrict__ Wh, const unsigned short* __restrict__ Wl,
                void* __restrict__ Cout, int M, int N, int K) {
    __shared__ __align__(16) unsigned short sAh[128 * 64];
    __shared__ __align__(16) unsigned short sAl[128 * 64];
    __shared__ __align__(16) unsigned short sWh[128 * 64];
    __shared__ __align__(16) unsigned short sWl[128 * 64];
    const int tid  = threadIdx.x;
    const int wave = tid >> 6;
    const int lane = tid & 63;
    const int wm = (wave >> 1) * 64;
    const int wn = (wave & 1) * 64;
    const int bm = blockIdx.y, bn = blockIdx.x;

    const int wrow = lane >> 3;        // W staging: row within 8-row group
    const int wcol = (lane & 7) * 8;   // k offset (8 bf16 = 16B)

    const float*          Ag = A  + (size_t)(bm * 128) * lda;
    const unsigned short* Whg = Wh + (size_t)(bn * 128) * K;
    const unsigned short* Wlg = DO_LO ? (Wl + (size_t)(bn * 128) * K) : nullptr;

    f32x4 acc[4][4];
#pragma unroll
    for (int i = 0; i < 4; i++)
#pragma unroll
        for (int j = 0; j < 4; j++) { acc[i][j][0]=0.f; acc[i][j][1]=0.f; acc[i][j][2]=0.f; acc[i][j][3]=0.f; }

    const int mrow = lane & 15;
    const int kq   = (lane >> 4) * 8;

    for (int k0 = 0; k0 < K; k0 += 64) {
        // A staging: 128x64 f32 tile -> split hi/lo bf16 in LDS. 8 float4/thread.
#pragma unroll
        for (int it = 0; it < 8; it++) {
            int idx = it * 256 + tid;
            int r   = idx >> 4;
            int c4  = (idx & 15) * 4;
            float4 v = *(const float4*)(Ag + (size_t)r * lda + k0 + c4);
            ushort4 h, l;
            split_hl(v.x, h.x, l.x); split_hl(v.y, h.y, l.y);
            split_hl(v.z, h.z, l.z); split_hl(v.w, h.w, l.w);
            *(ushort4*)(sAh + r * 64 + c4) = h;
            if (DO_LO) *(ushort4*)(sAl + r * 64 + c4) = l;
        }
        // W staging via async gld
#pragma unroll
        for (int i = 0; i < 4; i++) {
            int rbase = wave * 32 + i * 8;
            gld_lds16(Whg + (size_t)(rbase + wrow) * K + k0 + wcol, sWh + rbase * 64);
            if (DO_LO)
                gld_lds16(Wlg + (size_t)(rbase + wrow) * K + k0 + wcol, sWl + rbase * 64);
        }
        __syncthreads();
#pragma unroll
        for (int kk = 0; kk < 2; kk++) {
            bf16x8 afh[4], wfh[4];
#pragma unroll
            for (int i = 0; i < 4; i++)
                afh[i] = *(const bf16x8*)(sAh + (wm + i * 16 + mrow) * 64 + kk * 32 + kq);
#pragma unroll
            for (int j = 0; j < 4; j++)
                wfh[j] = *(const bf16x8*)(sWh + (wn + j * 16 + mrow) * 64 + kk * 32 + kq);
#pragma unroll
            for (int i = 0; i < 4; i++)
#pragma unroll
                for (int j = 0; j < 4; j++)
                    acc[i][j] = __builtin_amdgcn_mfma_f32_16x16x32_bf16(afh[i], wfh[j], acc[i][j], 0, 0, 0);
            if (DO_LO) {
                bf16x8 afl[4], wfl[4];
#pragma unroll
                for (int i = 0; i < 4; i++)
                    afl[i] = *(const bf16x8*)(sAl + (wm + i * 16 + mrow) * 64 + kk * 32 + kq);
#pragma unroll
                for (int j = 0; j < 4; j++)
                    wfl[j] = *(const bf16x8*)(sWl + (wn + j * 16 + mrow) * 64 + kk * 32 + kq);
#pragma unroll
                for (int i = 0; i < 4; i++)
#pragma unroll
                    for (int j = 0; j < 4; j++) {
                        acc[i][j] = __builtin_amdgcn_mfma_f32_16x16x32_bf16(afh[i], wfl[j], acc[i][j], 0, 0, 0);
                        acc[i][j] = __builtin_amdgcn_mfma_f32_16x16x32_bf16(afl[i], wfh[j], acc[i][j], 0, 0, 0);
                    }
            }
        }
        __syncthreads();
    }
    // epilogue: D[m][n]: m=(lane>>4)*4+r, n=lane&15 (m89-verified)
    const int r0 = (lane >> 4) * 4;
    const int cn = lane & 15;
#pragma unroll
    for (int i = 0; i < 4; i++) {
#pragma unroll
        for (int r = 0; r < 4; r++) {
            int row = bm * 128 + wm + i * 16 + r0 + r;
            size_t base = (size_t)row * N + bn * 128 + wn + cn;
            if constexpr (F32OUT) {
                float* Crow = (float*)Cout + base;
#pragma unroll
                for (int j = 0; j < 4; j++) Crow[j * 16] = acc[i][j][r];
            } else {
                unsigned short* Crow = (unsigned short*)Cout + base;
#pragma unroll
                for (int j = 0; j < 4; j++) Crow[j * 16] = f2bf(acc[i][j][r]);
            }
        }
    }
}

// ---------------------------------------------------------------- plain bf16 GEMM (final): A bf16 w/ lda, out f32
__global__ __launch_bounds__(256)
void gemm_bt(const unsigned short* __restrict__ A, int lda, const unsigned short* __restrict__ W,
             float* __restrict__ C, int M, int N, int K) {
    __shared__ __align__(16) unsigned short sA[128 * 64];
    __shared__ __align__(16) unsigned short sB[128 * 64];
    const int tid  = threadIdx.x;
    const int wave = tid >> 6;
    const int lane = tid & 63;
    const int wm = (wave >> 1) * 64;
    const int wn = (wave & 1) * 64;
    const int bm = blockIdx.y, bn = blockIdx.x;
    const int srow = lane >> 3;
    const int scol = (lane & 7) * 8;

    const unsigned short* Ag = A + (size_t)(bm * 128) * lda;
    const unsigned short* Wg = W + (size_t)(bn * 128) * K;

    f32x4 acc[4][4];
#pragma unroll
    for (int i = 0; i < 4; i++)
#pragma unroll
        for (int j = 0; j < 4; j++) { acc[i][j][0]=0.f; acc[i][j][1]=0.f; acc[i][j][2]=0.f; acc[i][j][3]=0.f; }

    const int mrow = lane & 15;
    const int kq   = (lane >> 4) * 8;

    for (int k0 = 0; k0 < K; k0 += 64) {
#pragma unroll
        for (int i = 0; i < 4; i++) {
            int rbase = wave * 32 + i * 8;
            gld_lds16(Ag + (size_t)(rbase + srow) * lda + k0 + scol, sA + rbase * 64);
            gld_lds16(Wg + (size_t)(rbase + srow) * K   + k0 + scol, sB + rbase * 64);
        }
        __syncthreads();
#pragma unroll
        for (int kk = 0; kk < 2; kk++) {
            bf16x8 af[4], bfr[4];
#pragma unroll
            for (int i = 0; i < 4; i++)
                af[i] = *(const bf16x8*)(sA + (wm + i * 16 + mrow) * 64 + kk * 32 + kq);
#pragma unroll
            for (int j = 0; j < 4; j++)
                bfr[j] = *(const bf16x8*)(sB + (wn + j * 16 + mrow) * 64 + kk * 32 + kq);
#pragma unroll
            for (int i = 0; i < 4; i++)
#pragma unroll
                for (int j = 0; j < 4; j++)
                    acc[i][j] = __builtin_amdgcn_mfma_f32_16x16x32_bf16(af[i], bfr[j], acc[i][j], 0, 0, 0);
        }
        __syncthreads();
    }
    const int r0 = (lane >> 4) * 4;
    const int cn = lane & 15;
#pragma unroll
    for (int i = 0; i < 4; i++) {
#pragma unroll
        for (int r = 0; r < 4; r++) {
            int row = bm * 128 + wm + i * 16 + r0 + r;
            float* Crow = C + (size_t)row * N + bn * 128 + wn + cn;
#pragma unroll
            for (int j = 0; j < 4; j++)
                Crow[j * 16] = acc[i][j][r];
        }
    }
}

// ---------------------------------------------------------------- per-head gates (exact fp32)
__device__ __forceinline__ float softplusf(float x) {
    return (x > 20.f) ? x : log1pf(expf(x));
}

__global__ __launch_bounds__(256)
void gates_k(const float* __restrict__ x, const float* __restrict__ a_w, const float* __restrict__ b_w,
             const float* __restrict__ b_bias, const float* __restrict__ beta_bias,
             const float* __restrict__ A_log, const float* __restrict__ dt_bias,
             float* __restrict__ g, float* __restrict__ beta) {
    int bt = blockIdx.x;
    int wave = threadIdx.x >> 6, lane = threadIdx.x & 63;
    const float* xr = x + (size_t)bt * C_;
#pragma unroll
    for (int dd = 0; dd < 8; dd++) {
        int d = wave * 8 + dd;
        int h = d & 15;
        const float* wr = (d < 16 ? a_w : b_w) + (size_t)h * C_;
        float acc = 0.f;
#pragma unroll
        for (int it = 0; it < 8; it++) {
            float4 xv = ((const float4*)xr)[lane + it * 64];
            float4 wv = ((const float4*)wr)[lane + it * 64];
            acc += xv.x * wv.x + xv.y * wv.y + xv.z * wv.z + xv.w * wv.w;
        }
        acc += __shfl_xor(acc, 1);  acc += __shfl_xor(acc, 2);  acc += __shfl_xor(acc, 4);
        acc += __shfl_xor(acc, 8);  acc += __shfl_xor(acc, 16); acc += __shfl_xor(acc, 32);
        if (lane == 0) {
            if (d < 16) {
                g[(size_t)bt * H_ + h] = -expf(A_log[h]) * softplusf(acc + dt_bias[h]);
            } else {
                float s = 1.f / (1.f + expf(-(acc + b_bias[h] + beta_bias[h])));
                beta[(size_t)bt * H_ + h] = 2.f * s;
            }
        }
    }
}

// ---------------------------------------------------------------- fused conv+silu+l2norm+scan (all f32)
// 128 blocks (b,h,vh). Reads raw q,k from qk (d_out f32, [q|k] cols) and raw v from
// vbuf; causal dwconv(4)+silu computed in-LDS with 3-row carry across chunks;
// writes o f32 in-place over consumed v rows of vbuf.
// Step loop: DPP quad reduces (no ds_swizzle), double-buffered kf/qf prefetch
// (LDS latency hidden under FMAs), decay folded out of the m-chain:
// mem = dec*(k.S_old); S = dec*S + k*delta.
#define CT_ 32

// load step t2's fragments from LDS into registers (issued one step ahead)
#define LOAD_STEP(t2, kf, qf, vt, dec, btt)                                  \
    {                                                                        \
        _Pragma("unroll")                                                    \
        for (int u = 0; u < 4; u++) {                                        \
            float4 k4 = ((const float4*)(sk + (t2) * 68 + dk0))[u];          \
            float4 q4 = ((const float4*)(sq + (t2) * 68 + dk0))[u];          \
            kf[u*4+0]=k4.x; kf[u*4+1]=k4.y; kf[u*4+2]=k4.z; kf[u*4+3]=k4.w;  \
            qf[u*4+0]=q4.x; qf[u*4+1]=q4.y; qf[u*4+2]=q4.z; qf[u*4+3]=q4.w;  \
        }                                                                    \
        vt  = sv[(t2) * 68 + dvl];                                           \
        dec = sg[(t2)];                                                      \
        btt = sb[(t2)];                                                      \
    }

// one delta-rule step. m-dot runs on PRE-decay S; mem = dec*m (identical algebra),
// so the S*=dec pass overlaps the DPP reduce instead of preceding the dot.
#define DO_STEP(t2, kf, qf, vt, dec, btt)                                    \
    {                                                                        \
        float m0=0.f, m1=0.f, m2=0.f, m3=0.f;                                \
        _Pragma("unroll")                                                    \
        for (int u = 0; u < 4; u++) {                                        \
            m0 += kf[u*4+0]*S[u*4+0]; m1 += kf[u*4+1]*S[u*4+1];              \
            m2 += kf[u*4+2]*S[u*4+2]; m3 += kf[u*4+3]*S[u*4+3];              \
        }                                                                    \
        float m = (m0 + m1) + (m2 + m3);                                     \
        m = dpp_xor1_add(m);                                                 \
        m = dpp_xor2_add(m);                                                 \
        _Pragma("unroll")                                                    \
        for (int i = 0; i < 16; i++) S[i] *= dec;                            \
        float delta = (vt - m * dec) * btt;                                  \
        float o0=0.f, o1=0.f, o2=0.f, o3=0.f;                                \
        _Pragma("unroll")                                                    \
        for (int u = 0; u < 4; u++) {                                        \
            S[u*4+0] += kf[u*4+0]*delta; o0 += qf[u*4+0]*S[u*4+0];           \
            S[u*4+1] += kf[u*4+1]*delta; o1 += qf[u*4+1]*S[u*4+1];           \
            S[u*4+2] += kf[u*4+2]*delta; o2 += qf[u*4+2]*S[u*4+2];           \
            S[u*4+3] += kf[u*4+3]*delta; o3 += qf[u*4+3]*S[u*4+3];           \
        }                                                                    \
        float ov = (o0 + o1) + (o2 + o3);                                    \
        ov = dpp_xor1_add(ov);                                               \
        ov = dpp_xor2_add(ov);                                               \
        if (dkq == 0)                                                        \
            vbuf[vbase + (size_t)(tc + (t2)) * 2048 + dvl] = ov;             \
    }

__global__ __launch_bounds__(256)
void scan_fused(const float* __restrict__ qk, float* __restrict__ vbuf,
                const float* __restrict__ qcw, const float* __restrict__ kcw, const float* __restrict__ vcw,
                const float* __restrict__ g, const float* __restrict__ beta) {
    int blk = blockIdx.x;
    int vh  = blk & 1;
    int bh  = blk >> 1;
    int b   = bh >> 4;
    int h   = bh & 15;
    int tid = threadIdx.x;
    int dkq = tid & 3;
    int dvl = tid >> 2;
    int dk0 = dkq * 16;

    __shared__ __align__(16) float rawq[(CT_ + 3) * 64];
    __shared__ __align__(16) float rawk[(CT_ + 3) * 64];
    __shared__ __align__(16) float rawv[(CT_ + 3) * 64];
    __shared__ __align__(16) float sq[CT_ * 68];
    __shared__ __align__(16) float sk[CT_ * 68];
    __shared__ __align__(16) float sv[CT_ * 68];
    __shared__ __align__(16) float wqs[64 * 4];
    __shared__ __align__(16) float wks[64 * 4];
    __shared__ __align__(16) float wvs[64 * 4];
    __shared__ float sg[CT_];
    __shared__ float sb[CT_];

    // preload conv weights for this head
    if (tid < 64) {
        *(float4*)(wqs + tid * 4) = *(const float4*)(qcw + (size_t)(h * 64 + tid) * 4);
        *(float4*)(wks + tid * 4) = *(const float4*)(kcw + (size_t)(h * 64 + tid) * 4);
        *(float4*)(wvs + tid * 4) = *(const float4*)(vcw + (size_t)(h * 128 + vh * 64 + tid) * 4);
    }
    // zero carry-source rows CT..CT+3 (first chunk's causal zero-pad)
    if (tid < 192) {
        int bsel = tid >> 6, c = tid & 63;
        float* rb = bsel == 0 ? rawq : (bsel == 1 ? rawk : rawv);
#pragma unroll
        for (int j = 0; j < 3; j++) rb[(CT_ + j) * 64 + c] = 0.f;
    }

    float S[16];
#pragma unroll
    for (int i = 0; i < 16; i++) S[i] = 0.f;

    const size_t qbase = (size_t)b * T_ * 2048 + h * 64;
    const size_t kbase = qbase + 1024;
    const size_t vbase = (size_t)b * T_ * 2048 + h * 128 + vh * 64;
    const size_t gbase = (size_t)b * T_ * H_ + h;

    for (int tc = 0; tc < T_; tc += CT_) {
        __syncthreads();   // prev chunk fully consumed (raw + s-bufs)
        // carry last 3 raw rows to front
        if (tid < 192) {
            int bsel = tid >> 6, c = tid & 63;
            float* rb = bsel == 0 ? rawq : (bsel == 1 ? rawk : rawv);
#pragma unroll
            for (int j = 0; j < 3; j++) rb[j * 64 + c] = rb[(CT_ + j) * 64 + c];
        }
        __syncthreads();
        // fresh stage: rows [tc, tc+CT) of raw q,k,v + gates
#pragma unroll
        for (int u = 0; u < 2; u++) {
            int idx = u * 256 + tid;
            int r   = idx >> 4;
            int c4  = (idx & 15) * 4;
            size_t row = (size_t)(tc + r) * 2048;
            *(float4*)(rawq + (3 + r) * 64 + c4) = *(const float4*)(qk + qbase + row + c4);
            *(float4*)(rawk + (3 + r) * 64 + c4) = *(const float4*)(qk + kbase + row + c4);
            *(float4*)(rawv + (3 + r) * 64 + c4) = *(const float4*)(vbuf + vbase + row + c4);
        }
        if (tid < CT_)           sg[tid]       = expf(g[gbase + (size_t)(tc + tid) * H_]);
        else if (tid < 2 * CT_)  sb[tid - CT_] = beta[gbase + (size_t)(tc + tid - CT_) * H_];
        __syncthreads();
        // conv(4) + silu: out row r uses raw rows r..r+3 (raw[3+r]=x[tc+r])
        {
            int c  = tid & 63;
            int r0 = tid >> 6;
#pragma unroll
            for (int it = 0; it < 8; it++) {
                int r = r0 + it * 4;
                float aq = 0.f, ak = 0.f, av = 0.f;
#pragma unroll
                for (int j = 0; j < 4; j++) {
                    aq += wqs[c * 4 + j] * rawq[(r + j) * 64 + c];
                    ak += wks[c * 4 + j] * rawk[(r + j) * 64 + c];
                    av += wvs[c * 4 + j] * rawv[(r + j) * 64 + c];
                }
                sq[r * 68 + c] = siluf(aq);
                sk[r * 68 + c] = siluf(ak);
                sv[r * 68 + c] = siluf(av);
            }
        }
        __syncthreads();
        // l2norm q,k rows (8 lanes/row)
        {
            int r = tid >> 3;
            int j = tid & 7;
            float* kr = sk + r * 68 + j * 8;
            float* qr = sq + r * 68 + j * 8;
            float ssk = 0.f, ssq = 0.f;
#pragma unroll
            for (int i = 0; i < 8; i++) { float a = kr[i]; ssk += a * a; float c2 = qr[i]; ssq += c2 * c2; }
            ssk += __shfl_xor(ssk, 1); ssk += __shfl_xor(ssk, 2); ssk += __shfl_xor(ssk, 4);
            ssq += __shfl_xor(ssq, 1); ssq += __shfl_xor(ssq, 2); ssq += __shfl_xor(ssq, 4);
            float rk = rsqrtf(ssk + 1e-6f);
            float rq = rsqrtf(ssq + 1e-6f) * 0.125f;   // fold SCALE = DK^-0.5
#pragma unroll
            for (int i = 0; i < 8; i++) { kr[i] *= rk; qr[i] *= rq; }
        }
        __syncthreads();
        // sequential steps: unroll x2, prefetch next step's fragments (double-buffered)
        {
            float kfa[16], qfa[16], kfb[16], qfb[16];
            float vta, deca, btta, vtb, decb, bttb;
            LOAD_STEP(0, kfa, qfa, vta, deca, btta);
#pragma unroll 1
            for (int t2 = 0; t2 < CT_; t2 += 2) {
                LOAD_STEP(t2 + 1, kfb, qfb, vtb, decb, bttb);
                DO_STEP(t2, kfa, qfa, vta, deca, btta);
                if (t2 + 2 < CT_)
                    LOAD_STEP(t2 + 2, kfa, qfa, vta, deca, btta);
                DO_STEP(t2 + 1, kfb, qfb, vtb, decb, bttb);
            }
        }
    }
}

// ---------------------------------------------------------------- postnorm: rms(o)*silu(g_out) -> og bf16
// o f32 in vbuf rows (stride 2048 f32); g_out bf16 in d_out (stride 2048 ushort);
// og bf16 written IN-PLACE over vbuf rows (stride 4096 ushort).
__global__ __launch_bounds__(256)
void postnorm_k(float* __restrict__ vbuf, const unsigned short* __restrict__ gout) {
    int bt  = blockIdx.x;
    int tid = threadIdx.x;
    const float* orow = vbuf + (size_t)bt * 2048 + tid * 8;
    float4 a = ((const float4*)orow)[0];
    float4 c = ((const float4*)orow)[1];
    float ss = a.x*a.x + a.y*a.y + a.z*a.z + a.w*a.w
             + c.x*c.x + c.y*c.y + c.z*c.z + c.w*c.w;
    ss += __shfl_xor(ss, 1); ss += __shfl_xor(ss, 2); ss += __shfl_xor(ss, 4); ss += __shfl_xor(ss, 8);
    float rms = rsqrtf(ss * (1.f / 128.f) + 1.1920928955078125e-07f);
    const unsigned short* grow = gout + (size_t)bt * 2048 + tid * 8;
    ushort4 g1 = ((const ushort4*)grow)[0];
    ushort4 g2 = ((const ushort4*)grow)[1];
    ushort4 r0, r1;
    r0.x = f2bf(a.x * rms * siluf(bf2f(g1.x)));
    r0.y = f2bf(a.y * rms * siluf(bf2f(g1.y)));
    r0.z = f2bf(a.z * rms * siluf(bf2f(g1.z)));
    r0.w = f2bf(a.w * rms * siluf(bf2f(g1.w)));
    r1.x = f2bf(c.x * rms * siluf(bf2f(g2.x)));
    r1.y = f2bf(c.y * rms * siluf(bf2f(g2.y)));
    r1.z = f2bf(c.z * rms * siluf(bf2f(g2.z)));
    r1.w = f2bf(c.w * rms * siluf(bf2f(g2.w)));
    __syncthreads();   // all reads of this row done before in-place overwrite
    unsigned short* og = (unsigned short*)vbuf + (size_t)bt * 4096 + tid * 8;
    *(ushort4*)og       = r0;
    *(ushort4*)(og + 4) = r1;
}

// ---------------------------------------------------------------- launch
// ws (121 MiB peak):
//   [0,8)    qkw_h    [8,16)   qkw_l
//   [16,32)  vgw_h    [32,48)  vgw_l   (full 4096 rows; lo used for v-half only)
//   [48,56)  ow_bf
//   [56,120) vbuf f32: GEMM2v out -> o (scan, in-place) -> og bf16 (postnorm, stride 4096)
//   [120,121) gbuf, bbuf
// d_out (64 MiB f32): qk f32 (GEMM1) -> consumed by scan -> g_out bf16 [0,32MiB)
//   (GEMM2g, after scan) -> final f32 output (overwrites everything).
extern "C" void kernel_launch(void* const* d_in, const int* in_sizes, int n_in,
                              void* d_out, int out_size, void* d_ws, size_t ws_size,
                              hipStream_t stream) {
    (void)in_sizes; (void)n_in; (void)out_size; (void)ws_size;
    const float* x        = (const float*)d_in[0];
    const float* qk_w     = (const float*)d_in[1];
    const float* vg_w     = (const float*)d_in[2];
    const float* o_w      = (const float*)d_in[3];
    const float* a_w      = (const float*)d_in[4];
    const float* b_w      = (const float*)d_in[5];
    const float* b_bias   = (const float*)d_in[6];
    const float* beta_b   = (const float*)d_in[7];
    const float* A_log    = (const float*)d_in[8];
    const float* dt_bias  = (const float*)d_in[9];
    const float* q_conv_w = (const float*)d_in[10];
    const float* k_conv_w = (const float*)d_in[11];
    const float* v_conv_w = (const float*)d_in[12];

    char* ws = (char*)d_ws;
    unsigned short* qkw_h = (unsigned short*)(ws);
    unsigned short* qkw_l = (unsigned short*)(ws + (8u  << 20));
    unsigned short* vgw_h = (unsigned short*)(ws + (16u << 20));
    unsigned short* vgw_l = (unsigned short*)(ws + (32u << 20));
    unsigned short* ow_bf = (unsigned short*)(ws + (48u << 20));
    float*          vbuf  = (float*)(ws + (56u << 20));
    float*          gbuf  = (float*)(ws + (120u << 20));
    float*          bbuf  = (float*)(ws + (120u << 20) + (512u << 10));

    float* qkf            = (float*)d_out;                 // qk f32 (GEMM1)
    unsigned short* goutb = (unsigned short*)d_out;        // g_out bf16 (after scan)
    float* outp           = (float*)d_out;                 // final f32 output

    // 1) weight casts
    cast_split_k<<<(2048 * 2048 / 4 + 255) / 256, 256, 0, stream>>>(qk_w, qkw_h, qkw_l, 2048 * 2048 / 4);
    cast_split_k<<<(4096 * 2048 / 4 + 255) / 256, 256, 0, stream>>>(vg_w, vgw_h, vgw_l, 4096 * 2048 / 4);
    cast_plain_k<<<(2048 * 2048 / 4 + 255) / 256, 256, 0, stream>>>(o_w, ow_bf, 2048 * 2048 / 4);

    // 2) split-precision GEMMs: qk f32 -> d_out; v f32 -> vbuf
    gemm_split<true, true><<<dim3(16, 64), 256, 0, stream>>>(x, 2048, qkw_h, qkw_l, qkf, BT_, 2048, 2048);
    gemm_split<true, true><<<dim3(16, 64), 256, 0, stream>>>(x, 2048, vgw_h, vgw_l, vbuf, BT_, 2048, 2048);

    // 3) gates (exact fp32)
    gates_k<<<BT_, 256, 0, stream>>>(x, a_w, b_w, b_bias, beta_b, A_log, dt_bias, gbuf, bbuf);

    // 4) fused conv+silu+l2norm+scan -> o f32 in-place over vbuf
    scan_fused<<<B_ * H_ * 2, 256, 0, stream>>>(qkf, vbuf, q_conv_w, k_conv_w, v_conv_w, gbuf, bbuf);

    // 5) g_out = x @ vg_w[2048:].T, hi-only bf16 -> d_out[0,32MiB) (qk consumed)
    gemm_split<false, false><<<dim3(16, 64), 256, 0, stream>>>(
        x, 2048, vgw_h + (size_t)2048 * 2048, nullptr, goutb, BT_, 2048, 2048);

    // 6) postnorm -> og bf16 in-place over vbuf (stride 4096 ushort)
    postnorm_k<<<BT_, 256, 0, stream>>>(vbuf, goutb);

    // 7) final GEMM: og @ o_w.T -> d_out f32
    gemm_bt<<<dim3(16, 64), 256, 0, stream>>>((unsigned short*)vbuf, 4096, ow_bf, outp, BT_, 2048, 2048);
}

// Round 2
// 1877.446 us; speedup vs baseline: 1.2422x; 1.1106x over previous
//
#include <hip/hip_runtime.h>
#include <hip/hip_bf16.h>
#include <stdint.h>

// Problem constants
#define B_ 4
#define T_ 2048
#define C_ 2048
#define H_ 16
#define DK_ 64
#define DV_ 128
#define BT_ (B_ * T_)   // 8192

typedef __attribute__((ext_vector_type(8))) __bf16 bf16x8;
typedef __attribute__((ext_vector_type(4))) float f32x4;

__device__ __forceinline__ unsigned short f2bf(float f) {
    union { float f; uint32_t u; } v; v.f = f;
    uint32_t u = v.u;
    uint32_t r = u + 0x7FFFu + ((u >> 16) & 1u);   // RNE
    return (unsigned short)(r >> 16);
}
__device__ __forceinline__ float bf2f(unsigned short h) {
    union { uint32_t u; float f; } v; v.u = ((uint32_t)h) << 16; return v.f;
}
__device__ __forceinline__ float siluf(float x) { return x / (1.f + expf(-x)); }

// DPP quad-reduce helpers: sum across the 4 lanes of a quad (lanes grouped as tid&3).
__device__ __forceinline__ float dpp_xor1_add(float x) {
    int t = __builtin_amdgcn_update_dpp(0, __float_as_int(x), 0xB1, 0xF, 0xF, true);
    return x + __int_as_float(t);
}
__device__ __forceinline__ float dpp_xor2_add(float x) {
    int t = __builtin_amdgcn_update_dpp(0, __float_as_int(x), 0x4E, 0xF, 0xF, true);
    return x + __int_as_float(t);
}

// hi = RNE bf16 of x; lo = trunc bf16 of (x - hi). x ≈ hi + lo to ~2^-17 rel.
__device__ __forceinline__ void split_hl(float x, unsigned short& h, unsigned short& l) {
    unsigned short hu = f2bf(x);
    float lo = x - bf2f(hu);
    h = hu;
    l = (unsigned short)(__float_as_uint(lo) >> 16);
}

// ---------------------------------------------------------------- casts
__global__ void cast_split_k(const float* __restrict__ in,
                             unsigned short* __restrict__ oh, unsigned short* __restrict__ ol, int n4) {
    int i = blockIdx.x * blockDim.x + threadIdx.x;
    if (i >= n4) return;
    float4 v = ((const float4*)in)[i];
    ushort4 h, l;
    split_hl(v.x, h.x, l.x); split_hl(v.y, h.y, l.y);
    split_hl(v.z, h.z, l.z); split_hl(v.w, h.w, l.w);
    ((ushort4*)oh)[i] = h;
    ((ushort4*)ol)[i] = l;
}

__global__ void cast_plain_k(const float* __restrict__ in, unsigned short* __restrict__ out, int n4) {
    int i = blockIdx.x * blockDim.x + threadIdx.x;
    if (i >= n4) return;
    float4 v = ((const float4*)in)[i];
    ushort4 o;
    o.x = f2bf(v.x); o.y = f2bf(v.y); o.z = f2bf(v.z); o.w = f2bf(v.w);
    ((ushort4*)out)[i] = o;
}

// ---------------------------------------------------------------- async global->LDS (16B/lane)
__device__ __forceinline__ void gld_lds16(const unsigned short* gptr,
                                          unsigned short* lds_base) {
    __builtin_amdgcn_global_load_lds(
        (const __attribute__((address_space(1))) uint32_t*)(uintptr_t)gptr,
        (__attribute__((address_space(3))) uint32_t*)(uint32_t)(uintptr_t)lds_base,
        16, 0, 0);
}

// ---------------------------------------------------------------- split-precision GEMM
template<bool DO_LO, bool F32OUT>
__global__ __launch_bounds__(256)
void gemm_split(const float* __restrict__ A, int lda,
                const unsigned short* __restrict__ Wh, const unsigned short* __restrict__ Wl,
                void* __restrict__ Cout, int M, int N, int K) {
    __shared__ __align__(16) unsigned short sAh[128 * 64];
    __shared__ __align__(16) unsigned short sAl[128 * 64];
    __shared__ __align__(16) unsigned short sWh[128 * 64];
    __shared__ __align__(16) unsigned short sWl[128 * 64];
    const int tid  = threadIdx.x;
    const int wave = tid >> 6;
    const int lane = tid & 63;
    const int wm = (wave >> 1) * 64;
    const int wn = (wave & 1) * 64;
    const int bm = blockIdx.y, bn = blockIdx.x;

    const int wrow = lane >> 3;        // W staging: row within 8-row group
    const int wcol = (lane & 7) * 8;   // k offset (8 bf16 = 16B)

    const float*          Ag = A  + (size_t)(bm * 128) * lda;
    const unsigned short* Whg = Wh + (size_t)(bn * 128) * K;
    const unsigned short* Wlg = DO_LO ? (Wl + (size_t)(bn * 128) * K) : nullptr;

    f32x4 acc[4][4];
#pragma unroll
    for (int i = 0; i < 4; i++)
#pragma unroll
        for (int j = 0; j < 4; j++) { acc[i][j][0]=0.f; acc[i][j][1]=0.f; acc[i][j][2]=0.f; acc[i][j][3]=0.f; }

    const int mrow = lane & 15;
    const int kq   = (lane >> 4) * 8;

    for (int k0 = 0; k0 < K; k0 += 64) {
        // A staging: 128x64 f32 tile -> split hi/lo bf16 in LDS. 8 float4/thread.
#pragma unroll
        for (int it = 0; it < 8; it++) {
            int idx = it * 256 + tid;
            int r   = idx >> 4;
            int c4  = (idx & 15) * 4;
            float4 v = *(const float4*)(Ag + (size_t)r * lda + k0 + c4);
            ushort4 h, l;
            split_hl(v.x, h.x, l.x); split_hl(v.y, h.y, l.y);
            split_hl(v.z, h.z, l.z); split_hl(v.w, h.w, l.w);
            *(ushort4*)(sAh + r * 64 + c4) = h;
            if (DO_LO) *(ushort4*)(sAl + r * 64 + c4) = l;
        }
        // W staging via async gld
#pragma unroll
        for (int i = 0; i < 4; i++) {
            int rbase = wave * 32 + i * 8;
            gld_lds16(Whg + (size_t)(rbase + wrow) * K + k0 + wcol, sWh + rbase * 64);
            if (DO_LO)
                gld_lds16(Wlg + (size_t)(rbase + wrow) * K + k0 + wcol, sWl + rbase * 64);
        }
        __syncthreads();
#pragma unroll
        for (int kk = 0; kk < 2; kk++) {
            bf16x8 afh[4], wfh[4];
#pragma unroll
            for (int i = 0; i < 4; i++)
                afh[i] = *(const bf16x8*)(sAh + (wm + i * 16 + mrow) * 64 + kk * 32 + kq);
#pragma unroll
            for (int j = 0; j < 4; j++)
                wfh[j] = *(const bf16x8*)(sWh + (wn + j * 16 + mrow) * 64 + kk * 32 + kq);
#pragma unroll
            for (int i = 0; i < 4; i++)
#pragma unroll
                for (int j = 0; j < 4; j++)
                    acc[i][j] = __builtin_amdgcn_mfma_f32_16x16x32_bf16(afh[i], wfh[j], acc[i][j], 0, 0, 0);
            if (DO_LO) {
                bf16x8 afl[4], wfl[4];
#pragma unroll
                for (int i = 0; i < 4; i++)
                    afl[i] = *(const bf16x8*)(sAl + (wm + i * 16 + mrow) * 64 + kk * 32 + kq);
#pragma unroll
                for (int j = 0; j < 4; j++)
                    wfl[j] = *(const bf16x8*)(sWl + (wn + j * 16 + mrow) * 64 + kk * 32 + kq);
#pragma unroll
                for (int i = 0; i < 4; i++)
#pragma unroll
                    for (int j = 0; j < 4; j++) {
                        acc[i][j] = __builtin_amdgcn_mfma_f32_16x16x32_bf16(afh[i], wfl[j], acc[i][j], 0, 0, 0);
                        acc[i][j] = __builtin_amdgcn_mfma_f32_16x16x32_bf16(afl[i], wfh[j], acc[i][j], 0, 0, 0);
                    }
            }
        }
        __syncthreads();
    }
    // epilogue: D[m][n]: m=(lane>>4)*4+r, n=lane&15 (m89-verified)
    const int r0 = (lane >> 4) * 4;
    const int cn = lane & 15;
#pragma unroll
    for (int i = 0; i < 4; i++) {
#pragma unroll
        for (int r = 0; r < 4; r++) {
            int row = bm * 128 + wm + i * 16 + r0 + r;
            size_t base = (size_t)row * N + bn * 128 + wn + cn;
            if constexpr (F32OUT) {
                float* Crow = (float*)Cout + base;
#pragma unroll
                for (int j = 0; j < 4; j++) Crow[j * 16] = acc[i][j][r];
            } else {
                unsigned short* Crow = (unsigned short*)Cout + base;
#pragma unroll
                for (int j = 0; j < 4; j++) Crow[j * 16] = f2bf(acc[i][j][r]);
            }
        }
    }
}

// ---------------------------------------------------------------- plain bf16 GEMM (final): A bf16 w/ lda, out f32
__global__ __launch_bounds__(256)
void gemm_bt(const unsigned short* __restrict__ A, int lda, const unsigned short* __restrict__ W,
             float* __restrict__ C, int M, int N, int K) {
    __shared__ __align__(16) unsigned short sA[128 * 64];
    __shared__ __align__(16) unsigned short sB[128 * 64];
    const int tid  = threadIdx.x;
    const int wave = tid >> 6;
    const int lane = tid & 63;
    const int wm = (wave >> 1) * 64;
    const int wn = (wave & 1) * 64;
    const int bm = blockIdx.y, bn = blockIdx.x;
    const int srow = lane >> 3;
    const int scol = (lane & 7) * 8;

    const unsigned short* Ag = A + (size_t)(bm * 128) * lda;
    const unsigned short* Wg = W + (size_t)(bn * 128) * K;

    f32x4 acc[4][4];
#pragma unroll
    for (int i = 0; i < 4; i++)
#pragma unroll
        for (int j = 0; j < 4; j++) { acc[i][j][0]=0.f; acc[i][j][1]=0.f; acc[i][j][2]=0.f; acc[i][j][3]=0.f; }

    const int mrow = lane & 15;
    const int kq   = (lane >> 4) * 8;

    for (int k0 = 0; k0 < K; k0 += 64) {
#pragma unroll
        for (int i = 0; i < 4; i++) {
            int rbase = wave * 32 + i * 8;
            gld_lds16(Ag + (size_t)(rbase + srow) * lda + k0 + scol, sA + rbase * 64);
            gld_lds16(Wg + (size_t)(rbase + srow) * K   + k0 + scol, sB + rbase * 64);
        }
        __syncthreads();
#pragma unroll
        for (int kk = 0; kk < 2; kk++) {
            bf16x8 af[4], bfr[4];
#pragma unroll
            for (int i = 0; i < 4; i++)
                af[i] = *(const bf16x8*)(sA + (wm + i * 16 + mrow) * 64 + kk * 32 + kq);
#pragma unroll
            for (int j = 0; j < 4; j++)
                bfr[j] = *(const bf16x8*)(sB + (wn + j * 16 + mrow) * 64 + kk * 32 + kq);
#pragma unroll
            for (int i = 0; i < 4; i++)
#pragma unroll
                for (int j = 0; j < 4; j++)
                    acc[i][j] = __builtin_amdgcn_mfma_f32_16x16x32_bf16(af[i], bfr[j], acc[i][j], 0, 0, 0);
        }
        __syncthreads();
    }
    const int r0 = (lane >> 4) * 4;
    const int cn = lane & 15;
#pragma unroll
    for (int i = 0; i < 4; i++) {
#pragma unroll
        for (int r = 0; r < 4; r++) {
            int row = bm * 128 + wm + i * 16 + r0 + r;
            float* Crow = C + (size_t)row * N + bn * 128 + wn + cn;
#pragma unroll
            for (int j = 0; j < 4; j++)
                Crow[j * 16] = acc[i][j][r];
        }
    }
}

// ---------------------------------------------------------------- per-head gates (exact fp32)
__device__ __forceinline__ float softplusf(float x) {
    return (x > 20.f) ? x : log1pf(expf(x));
}

__global__ __launch_bounds__(256)
void gates_k(const float* __restrict__ x, const float* __restrict__ a_w, const float* __restrict__ b_w,
             const float* __restrict__ b_bias, const float* __restrict__ beta_bias,
             const float* __restrict__ A_log, const float* __restrict__ dt_bias,
             float* __restrict__ g, float* __restrict__ beta) {
    int bt = blockIdx.x;
    int wave = threadIdx.x >> 6, lane = threadIdx.x & 63;
    const float* xr = x + (size_t)bt * C_;
#pragma unroll
    for (int dd = 0; dd < 8; dd++) {
        int d = wave * 8 + dd;
        int h = d & 15;
        const float* wr = (d < 16 ? a_w : b_w) + (size_t)h * C_;
        float acc = 0.f;
#pragma unroll
        for (int it = 0; it < 8; it++) {
            float4 xv = ((const float4*)xr)[lane + it * 64];
            float4 wv = ((const float4*)wr)[lane + it * 64];
            acc += xv.x * wv.x + xv.y * wv.y + xv.z * wv.z + xv.w * wv.w;
        }
        acc += __shfl_xor(acc, 1);  acc += __shfl_xor(acc, 2);  acc += __shfl_xor(acc, 4);
        acc += __shfl_xor(acc, 8);  acc += __shfl_xor(acc, 16); acc += __shfl_xor(acc, 32);
        if (lane == 0) {
            if (d < 16) {
                g[(size_t)bt * H_ + h] = -expf(A_log[h]) * softplusf(acc + dt_bias[h]);
            } else {
                float s = 1.f / (1.f + expf(-(acc + b_bias[h] + beta_bias[h])));
                beta[(size_t)bt * H_ + h] = 2.f * s;
            }
        }
    }
}

// ---------------------------------------------------------------- fused conv+silu+l2norm+scan (all f32)
// 128 blocks (b,h,vh) x 512 threads (8 waves).
// PRODUCER/CONSUMER wave specialization:
//   waves 0-3 (tid<256): sequential delta-rule step loop on chunk c (reads s-bufs[c&1])
//   waves 4-7 (tid>=256): stage raw q/k/v + gates, conv(4)+silu, l2norm for chunk c+1
//                         into s-bufs[(c+1)&1] (double-buffered)
// 3 phase barriers/chunk couple the two roles; preprocessing overlaps the scan and
// each SIMD carries 2 waves (1 cons + 1 prod) so stalls cross-hide.
// Conv weights live in producer REGISTERS (old wqs[c*4+j] LDS reads were 8-way
// bank-conflicted). Math identical to previous version.
#define CT_ 32
#define NCH_ (T_ / CT_)

// load step t2's fragments from LDS into registers (issued one step ahead)
#define LOAD_STEP(t2, kf, qf, vt, dec, btt)                                  \
    {                                                                        \
        _Pragma("unroll")                                                    \
        for (int u = 0; u < 4; u++) {                                        \
            float4 k4 = ((const float4*)(skp + (t2) * 68 + dk0))[u];         \
            float4 q4 = ((const float4*)(sqp + (t2) * 68 + dk0))[u];         \
            kf[u*4+0]=k4.x; kf[u*4+1]=k4.y; kf[u*4+2]=k4.z; kf[u*4+3]=k4.w;  \
            qf[u*4+0]=q4.x; qf[u*4+1]=q4.y; qf[u*4+2]=q4.z; qf[u*4+3]=q4.w;  \
        }                                                                    \
        vt  = svp[(t2) * 68 + dvl];                                          \
        dec = sgp_[(t2)];                                                    \
        btt = sbp_[(t2)];                                                    \
    }

// one delta-rule step. m-dot runs on PRE-decay S; mem = dec*m (identical algebra).
#define DO_STEP(t2, kf, qf, vt, dec, btt)                                    \
    {                                                                        \
        float m0=0.f, m1=0.f, m2=0.f, m3=0.f;                                \
        _Pragma("unroll")                                                    \
        for (int u = 0; u < 4; u++) {                                        \
            m0 += kf[u*4+0]*S[u*4+0]; m1 += kf[u*4+1]*S[u*4+1];              \
            m2 += kf[u*4+2]*S[u*4+2]; m3 += kf[u*4+3]*S[u*4+3];              \
        }                                                                    \
        float m = (m0 + m1) + (m2 + m3);                                     \
        m = dpp_xor1_add(m);                                                 \
        m = dpp_xor2_add(m);                                                 \
        _Pragma("unroll")                                                    \
        for (int i = 0; i < 16; i++) S[i] *= dec;                            \
        float delta = (vt - m * dec) * btt;                                  \
        float o0=0.f, o1=0.f, o2=0.f, o3=0.f;                                \
        _Pragma("unroll")                                                    \
        for (int u = 0; u < 4; u++) {                                        \
            S[u*4+0] += kf[u*4+0]*delta; o0 += qf[u*4+0]*S[u*4+0];           \
            S[u*4+1] += kf[u*4+1]*delta; o1 += qf[u*4+1]*S[u*4+1];           \
            S[u*4+2] += kf[u*4+2]*delta; o2 += qf[u*4+2]*S[u*4+2];           \
            S[u*4+3] += kf[u*4+3]*delta; o3 += qf[u*4+3]*S[u*4+3];           \
        }                                                                    \
        float ov = (o0 + o1) + (o2 + o3);                                    \
        ov = dpp_xor1_add(ov);                                               \
        ov = dpp_xor2_add(ov);                                               \
        if (dkq == 0)                                                        \
            vbuf[vbase + (size_t)(tc + (t2)) * 2048 + dvl] = ov;             \
    }

// run steps [TB,TE) with 2-deep register double-buffered prefetch
#define CONSUME_GROUP(TB, TE)                                                \
    {                                                                        \
        float kfa[16], qfa[16], kfb[16], qfb[16];                            \
        float vta, deca, btta, vtb, decb, bttb;                              \
        LOAD_STEP(TB, kfa, qfa, vta, deca, btta);                            \
        int t2 = TB;                                                         \
        _Pragma("unroll 1")                                                  \
        for (; t2 + 2 <= (TE); t2 += 2) {                                    \
            LOAD_STEP(t2 + 1, kfb, qfb, vtb, decb, bttb);                    \
            DO_STEP(t2, kfa, qfa, vta, deca, btta);                          \
            if (t2 + 2 < (TE))                                               \
                LOAD_STEP(t2 + 2, kfa, qfa, vta, deca, btta);                \
            DO_STEP(t2 + 1, kfb, qfb, vtb, decb, bttb);                      \
        }                                                                    \
        if (t2 < (TE))                                                       \
            DO_STEP(t2, kfa, qfa, vta, deca, btta);                          \
    }

__global__ __launch_bounds__(512)
void scan_fused(const float* __restrict__ qk, float* __restrict__ vbuf,
                const float* __restrict__ qcw, const float* __restrict__ kcw, const float* __restrict__ vcw,
                const float* __restrict__ g, const float* __restrict__ beta) {
    int blk = blockIdx.x;
    int vh  = blk & 1;
    int bh  = blk >> 1;
    int b   = bh >> 4;
    int h   = bh & 15;
    int tid = threadIdx.x;

    __shared__ __align__(16) float rawq[2][(CT_ + 3) * 64];
    __shared__ __align__(16) float rawk[2][(CT_ + 3) * 64];
    __shared__ __align__(16) float rawv[2][(CT_ + 3) * 64];
    __shared__ __align__(16) float sq[2][CT_ * 68];
    __shared__ __align__(16) float sk[2][CT_ * 68];
    __shared__ __align__(16) float sv[2][CT_ * 68];
    __shared__ float sg[2][CT_];
    __shared__ float sb[2][CT_];

    const size_t qbase = (size_t)b * T_ * 2048 + h * 64;
    const size_t kbase = qbase + 1024;
    const size_t vbase = (size_t)b * T_ * 2048 + h * 128 + vh * 64;
    const size_t gbase = (size_t)b * T_ * H_ + h;

    const bool is_cons = (tid < 256);

    // ---------------- producer-local state (waves 4-7)
    const int ptid = tid - 256;
    const int pc   = ptid & 63;   // column 0..63
    const int pw   = ptid >> 6;   // producer wave 0..3
    float wqa[4], wka[4], wva[4];
    if (!is_cons) {
        float4 a4 = *(const float4*)(qcw + (size_t)(h * 64 + pc) * 4);
        float4 b4 = *(const float4*)(kcw + (size_t)(h * 64 + pc) * 4);
        float4 c4 = *(const float4*)(vcw + (size_t)(h * 128 + vh * 64 + pc) * 4);
        wqa[0]=a4.x; wqa[1]=a4.y; wqa[2]=a4.z; wqa[3]=a4.w;
        wka[0]=b4.x; wka[1]=b4.y; wka[2]=b4.z; wka[3]=b4.w;
        wva[0]=c4.x; wva[1]=c4.y; wva[2]=c4.z; wva[3]=c4.w;
        // chunk 0 pulls its causal zero-pad carry from buffer 1: zero those rows.
        if (ptid < 192) {
            int bsel = ptid >> 6, c = ptid & 63;
            float* rb = bsel == 0 ? rawq[1] : (bsel == 1 ? rawk[1] : rawv[1]);
#pragma unroll
            for (int j = 0; j < 3; j++) rb[(CT_ + j) * 64 + c] = 0.f;
        }
    }

    // phase1: carry-copy (from OTHER raw buffer) + fresh global stage + gates
    auto prod_phase1 = [&](int ci) {
        int rp = ci & 1;
        int tcc = ci * CT_;
        float* rq = rawq[rp]; float* rk = rawk[rp]; float* rv = rawv[rp];
        const float* pq = rawq[rp ^ 1]; const float* pk = rawk[rp ^ 1]; const float* pv = rawv[rp ^ 1];
        if (ptid < 192) {
            int bsel = ptid >> 6, c = ptid & 63;
            float*       db = bsel == 0 ? rq : (bsel == 1 ? rk : rv);
            const float* sc = bsel == 0 ? pq : (bsel == 1 ? pk : pv);
#pragma unroll
            for (int j = 0; j < 3; j++) db[j * 64 + c] = sc[(CT_ + j) * 64 + c];
        }
#pragma unroll
        for (int u = 0; u < 2; u++) {
            int idx = u * 256 + ptid;
            int r   = idx >> 4;
            int c4  = (idx & 15) * 4;
            size_t row = (size_t)(tcc + r) * 2048;
            *(float4*)(rq + (3 + r) * 64 + c4) = *(const float4*)(qk + qbase + row + c4);
            *(float4*)(rk + (3 + r) * 64 + c4) = *(const float4*)(qk + kbase + row + c4);
            *(float4*)(rv + (3 + r) * 64 + c4) = *(const float4*)(vbuf + vbase + row + c4);
        }
        if (ptid < CT_)          sg[rp][ptid]       = expf(g[gbase + (size_t)(tcc + ptid) * H_]);
        else if (ptid < 2 * CT_) sb[rp][ptid - CT_] = beta[gbase + (size_t)(tcc + ptid - CT_) * H_];
    };

    // phase2: conv(4)+silu, weights in registers
    auto prod_phase2 = [&](int ci) {
        int rp = ci & 1;
        const float* rq = rawq[rp]; const float* rk = rawk[rp]; const float* rv = rawv[rp];
        float* dq = sq[rp]; float* dk = sk[rp]; float* dv = sv[rp];
#pragma unroll
        for (int it = 0; it < 8; it++) {
            int r = pw + it * 4;
            float aq = 0.f, ak = 0.f, av = 0.f;
#pragma unroll
            for (int j = 0; j < 4; j++) {
                aq += wqa[j] * rq[(r + j) * 64 + pc];
                ak += wka[j] * rk[(r + j) * 64 + pc];
                av += wva[j] * rv[(r + j) * 64 + pc];
            }
            dq[r * 68 + pc] = siluf(aq);
            dk[r * 68 + pc] = siluf(ak);
            dv[r * 68 + pc] = siluf(av);
        }
    };

    // phase3: l2norm q,k rows (8 lanes/row), float4 loads/stores
    auto prod_phase3 = [&](int ci) {
        int rp = ci & 1;
        int r = ptid >> 3;
        int j = ptid & 7;
        float* kr = sk[rp] + r * 68 + j * 8;
        float* qr = sq[rp] + r * 68 + j * 8;
        float4 k0 = ((const float4*)kr)[0], k1 = ((const float4*)kr)[1];
        float4 q0 = ((const float4*)qr)[0], q1 = ((const float4*)qr)[1];
        float ssk = k0.x*k0.x + k0.y*k0.y + k0.z*k0.z + k0.w*k0.w
                  + k1.x*k1.x + k1.y*k1.y + k1.z*k1.z + k1.w*k1.w;
        float ssq = q0.x*q0.x + q0.y*q0.y + q0.z*q0.z + q0.w*q0.w
                  + q1.x*q1.x + q1.y*q1.y + q1.z*q1.z + q1.w*q1.w;
        ssk += __shfl_xor(ssk, 1); ssk += __shfl_xor(ssk, 2); ssk += __shfl_xor(ssk, 4);
        ssq += __shfl_xor(ssq, 1); ssq += __shfl_xor(ssq, 2); ssq += __shfl_xor(ssq, 4);
        float rk_ = rsqrtf(ssk + 1e-6f);
        float rq_ = rsqrtf(ssq + 1e-6f) * 0.125f;   // fold SCALE = DK^-0.5
        k0.x*=rk_; k0.y*=rk_; k0.z*=rk_; k0.w*=rk_;
        k1.x*=rk_; k1.y*=rk_; k1.z*=rk_; k1.w*=rk_;
        q0.x*=rq_; q0.y*=rq_; q0.z*=rq_; q0.w*=rq_;
        q1.x*=rq_; q1.y*=rq_; q1.z*=rq_; q1.w*=rq_;
        ((float4*)kr)[0] = k0; ((float4*)kr)[1] = k1;
        ((float4*)qr)[0] = q0; ((float4*)qr)[1] = q1;
    };

    // ---------------- consumer-local state (waves 0-3)
    const int dkq = tid & 3;
    const int dvl = tid >> 2;
    const int dk0 = dkq * 16;
    float S[16];
#pragma unroll
    for (int i = 0; i < 16; i++) S[i] = 0.f;

    // prologue: produce chunk 0 into buffer 0 (consumers idle at barriers)
    if (!is_cons) prod_phase1(0);
    __syncthreads();
    if (!is_cons) prod_phase2(0);
    __syncthreads();
    if (!is_cons) prod_phase3(0);
    __syncthreads();

    for (int ci = 0; ci < NCH_; ci++) {
        const int p  = ci & 1;
        const int tc = ci * CT_;
        const float* sqp  = sq[p];
        const float* skp  = sk[p];
        const float* svp  = sv[p];
        const float* sgp_ = sg[p];
        const float* sbp_ = sb[p];

        if (is_cons) { CONSUME_GROUP(0, 11); }
        else if (ci + 1 < NCH_) prod_phase1(ci + 1);
        __syncthreads();
        if (is_cons) { CONSUME_GROUP(11, 22); }
        else if (ci + 1 < NCH_) prod_phase2(ci + 1);
        __syncthreads();
        if (is_cons) { CONSUME_GROUP(22, 32); }
        else if (ci + 1 < NCH_) prod_phase3(ci + 1);
        __syncthreads();
    }
}

// ---------------------------------------------------------------- postnorm: rms(o)*silu(g_out) -> og bf16
__global__ __launch_bounds__(256)
void postnorm_k(float* __restrict__ vbuf, const unsigned short* __restrict__ gout) {
    int bt  = blockIdx.x;
    int tid = threadIdx.x;
    const float* orow = vbuf + (size_t)bt * 2048 + tid * 8;
    float4 a = ((const float4*)orow)[0];
    float4 c = ((const float4*)orow)[1];
    float ss = a.x*a.x + a.y*a.y + a.z*a.z + a.w*a.w
             + c.x*c.x + c.y*c.y + c.z*c.z + c.w*c.w;
    ss += __shfl_xor(ss, 1); ss += __shfl_xor(ss, 2); ss += __shfl_xor(ss, 4); ss += __shfl_xor(ss, 8);
    float rms = rsqrtf(ss * (1.f / 128.f) + 1.1920928955078125e-07f);
    const unsigned short* grow = gout + (size_t)bt * 2048 + tid * 8;
    ushort4 g1 = ((const ushort4*)grow)[0];
    ushort4 g2 = ((const ushort4*)grow)[1];
    ushort4 r0, r1;
    r0.x = f2bf(a.x * rms * siluf(bf2f(g1.x)));
    r0.y = f2bf(a.y * rms * siluf(bf2f(g1.y)));
    r0.z = f2bf(a.z * rms * siluf(bf2f(g1.z)));
    r0.w = f2bf(a.w * rms * siluf(bf2f(g1.w)));
    r1.x = f2bf(c.x * rms * siluf(bf2f(g2.x)));
    r1.y = f2bf(c.y * rms * siluf(bf2f(g2.y)));
    r1.z = f2bf(c.z * rms * siluf(bf2f(g2.z)));
    r1.w = f2bf(c.w * rms * siluf(bf2f(g2.w)));
    __syncthreads();   // all reads of this row done before in-place overwrite
    unsigned short* og = (unsigned short*)vbuf + (size_t)bt * 4096 + tid * 8;
    *(ushort4*)og       = r0;
    *(ushort4*)(og + 4) = r1;
}

// ---------------------------------------------------------------- launch
extern "C" void kernel_launch(void* const* d_in, const int* in_sizes, int n_in,
                              void* d_out, int out_size, void* d_ws, size_t ws_size,
                              hipStream_t stream) {
    (void)in_sizes; (void)n_in; (void)out_size; (void)ws_size;
    const float* x        = (const float*)d_in[0];
    const float* qk_w     = (const float*)d_in[1];
    const float* vg_w     = (const float*)d_in[2];
    const float* o_w      = (const float*)d_in[3];
    const float* a_w      = (const float*)d_in[4];
    const float* b_w      = (const float*)d_in[5];
    const float* b_bias   = (const float*)d_in[6];
    const float* beta_b   = (const float*)d_in[7];
    const float* A_log    = (const float*)d_in[8];
    const float* dt_bias  = (const float*)d_in[9];
    const float* q_conv_w = (const float*)d_in[10];
    const float* k_conv_w = (const float*)d_in[11];
    const float* v_conv_w = (const float*)d_in[12];

    char* ws = (char*)d_ws;
    unsigned short* qkw_h = (unsigned short*)(ws);
    unsigned short* qkw_l = (unsigned short*)(ws + (8u  << 20));
    unsigned short* vgw_h = (unsigned short*)(ws + (16u << 20));
    unsigned short* vgw_l = (unsigned short*)(ws + (32u << 20));
    unsigned short* ow_bf = (unsigned short*)(ws + (48u << 20));
    float*          vbuf  = (float*)(ws + (56u << 20));
    float*          gbuf  = (float*)(ws + (120u << 20));
    float*          bbuf  = (float*)(ws + (120u << 20) + (512u << 10));

    float* qkf            = (float*)d_out;                 // qk f32 (GEMM1)
    unsigned short* goutb = (unsigned short*)d_out;        // g_out bf16 (after scan)
    float* outp           = (float*)d_out;                 // final f32 output

    // 1) weight casts
    cast_split_k<<<(2048 * 2048 / 4 + 255) / 256, 256, 0, stream>>>(qk_w, qkw_h, qkw_l, 2048 * 2048 / 4);
    cast_split_k<<<(4096 * 2048 / 4 + 255) / 256, 256, 0, stream>>>(vg_w, vgw_h, vgw_l, 4096 * 2048 / 4);
    cast_plain_k<<<(2048 * 2048 / 4 + 255) / 256, 256, 0, stream>>>(o_w, ow_bf, 2048 * 2048 / 4);

    // 2) split-precision GEMMs: qk f32 -> d_out; v f32 -> vbuf
    gemm_split<true, true><<<dim3(16, 64), 256, 0, stream>>>(x, 2048, qkw_h, qkw_l, qkf, BT_, 2048, 2048);
    gemm_split<true, true><<<dim3(16, 64), 256, 0, stream>>>(x, 2048, vgw_h, vgw_l, vbuf, BT_, 2048, 2048);

    // 3) gates (exact fp32)
    gates_k<<<BT_, 256, 0, stream>>>(x, a_w, b_w, b_bias, beta_b, A_log, dt_bias, gbuf, bbuf);

    // 4) fused conv+silu+l2norm+scan -> o f32 in-place over vbuf (producer/consumer, 512 thr)
    scan_fused<<<B_ * H_ * 2, 512, 0, stream>>>(qkf, vbuf, q_conv_w, k_conv_w, v_conv_w, gbuf, bbuf);

    // 5) g_out = x @ vg_w[2048:].T, hi-only bf16 -> d_out[0,32MiB) (qk consumed)
    gemm_split<false, false><<<dim3(16, 64), 256, 0, stream>>>(
        x, 2048, vgw_h + (size_t)2048 * 2048, nullptr, goutb, BT_, 2048, 2048);

    // 6) postnorm -> og bf16 in-place over vbuf (stride 4096 ushort)
    postnorm_k<<<BT_, 256, 0, stream>>>(vbuf, goutb);

    // 7) final GEMM: og @ o_w.T -> d_out f32
    gemm_bt<<<dim3(16, 64), 256, 0, stream>>>((unsigned short*)vbuf, 4096, ow_bf, outp, BT_, 2048, 2048);
}

// Round 3
// 1704.224 us; speedup vs baseline: 1.3685x; 1.1016x over previous
//
#include <hip/hip_runtime.h>
#include <hip/hip_bf16.h>
#include <stdint.h>

// Problem constants
#define B_ 4
#define T_ 2048
#define C_ 2048
#define H_ 16
#define DK_ 64
#define DV_ 128
#define BT_ (B_ * T_)   // 8192

typedef __attribute__((ext_vector_type(8))) __bf16 bf16x8;
typedef __attribute__((ext_vector_type(4))) float f32x4;

__device__ __forceinline__ unsigned short f2bf(float f) {
    union { float f; uint32_t u; } v; v.f = f;
    uint32_t u = v.u;
    uint32_t r = u + 0x7FFFu + ((u >> 16) & 1u);   // RNE
    return (unsigned short)(r >> 16);
}
__device__ __forceinline__ float bf2f(unsigned short h) {
    union { uint32_t u; float f; } v; v.u = ((uint32_t)h) << 16; return v.f;
}
__device__ __forceinline__ float siluf(float x) { return x / (1.f + expf(-x)); }

// DPP quad-reduce helpers: sum across the 4 lanes of a quad (lanes grouped as tid&3).
__device__ __forceinline__ float dpp_xor1_add(float x) {
    int t = __builtin_amdgcn_update_dpp(0, __float_as_int(x), 0xB1, 0xF, 0xF, true);
    return x + __int_as_float(t);
}
__device__ __forceinline__ float dpp_xor2_add(float x) {
    int t = __builtin_amdgcn_update_dpp(0, __float_as_int(x), 0x4E, 0xF, 0xF, true);
    return x + __int_as_float(t);
}

// hi = RNE bf16 of x; lo = trunc bf16 of (x - hi). x ≈ hi + lo to ~2^-17 rel.
__device__ __forceinline__ void split_hl(float x, unsigned short& h, unsigned short& l) {
    unsigned short hu = f2bf(x);
    float lo = x - bf2f(hu);
    h = hu;
    l = (unsigned short)(__float_as_uint(lo) >> 16);
}

// ---------------------------------------------------------------- casts
__global__ void cast_split_k(const float* __restrict__ in,
                             unsigned short* __restrict__ oh, unsigned short* __restrict__ ol, int n4) {
    int i = blockIdx.x * blockDim.x + threadIdx.x;
    if (i >= n4) return;
    float4 v = ((const float4*)in)[i];
    ushort4 h, l;
    split_hl(v.x, h.x, l.x); split_hl(v.y, h.y, l.y);
    split_hl(v.z, h.z, l.z); split_hl(v.w, h.w, l.w);
    ((ushort4*)oh)[i] = h;
    ((ushort4*)ol)[i] = l;
}

__global__ void cast_plain_k(const float* __restrict__ in, unsigned short* __restrict__ out, int n4) {
    int i = blockIdx.x * blockDim.x + threadIdx.x;
    if (i >= n4) return;
    float4 v = ((const float4*)in)[i];
    ushort4 o;
    o.x = f2bf(v.x); o.y = f2bf(v.y); o.z = f2bf(v.z); o.w = f2bf(v.w);
    ((ushort4*)out)[i] = o;
}

// ---------------------------------------------------------------- async global->LDS (16B/lane)
__device__ __forceinline__ void gld_lds16(const unsigned short* gptr,
                                          unsigned short* lds_base) {
    __builtin_amdgcn_global_load_lds(
        (const __attribute__((address_space(1))) uint32_t*)(uintptr_t)gptr,
        (__attribute__((address_space(3))) uint32_t*)(uint32_t)(uintptr_t)lds_base,
        16, 0, 0);
}

// ---------------------------------------------------------------- producer/consumer GEMM
// C[M,N] = A[M,K] * W[N,K]^T. 512 threads: waves 0-3 = pure-MFMA consumers on LDS
// buffer p; waves 4-7 = producers staging buffer p^1 (double-buffered, 1 barrier/K-step).
// A_F32: A is f32, producers split to hi/lo bf16 in LDS (math identical to the old
// gemm_split: same split_hl, same MFMA accumulation order -> bitwise-identical C).
// !A_F32: A is bf16 with row stride lda, staged via global_load_lds.
// DO_LO: 3-product accumulation AhWh + AhWl + AlWh (~1e-4 rel); else hi-only.
template<bool DO_LO, bool F32OUT, bool A_F32>
__global__ __launch_bounds__(512, 2)
void gemm_pc(const void* __restrict__ Aptr, int lda,
             const unsigned short* __restrict__ Wh, const unsigned short* __restrict__ Wl,
             void* __restrict__ Cout, int M, int N, int K) {
    __shared__ __align__(16) unsigned short sAh[2][128 * 64];
    __shared__ __align__(16) unsigned short sWh[2][128 * 64];
    __shared__ __align__(16) unsigned short sAl[DO_LO ? 2 : 1][DO_LO ? 128 * 64 : 16];
    __shared__ __align__(16) unsigned short sWl[DO_LO ? 2 : 1][DO_LO ? 128 * 64 : 16];

    const int tid  = threadIdx.x;
    const bool is_cons = (tid < 256);
    const int bm = blockIdx.y, bn = blockIdx.x;
    const int NK = K >> 6;

    // ---- producer locals (waves 4-7)
    const int ptid  = tid - 256;
    const int pw    = ptid >> 6;        // producer wave 0..3
    const int plane = ptid & 63;
    const int wrow  = plane >> 3;       // row within 8-row group
    const int wcol  = (plane & 7) * 8;  // k offset (8 bf16 = 16B)

    const float*          Agf = (const float*)Aptr + (size_t)(bm * 128) * lda;
    const unsigned short* Agb = (const unsigned short*)Aptr + (size_t)(bm * 128) * lda;
    const unsigned short* Whg = Wh + (size_t)(bn * 128) * K;
    const unsigned short* Wlg = DO_LO ? (Wl + (size_t)(bn * 128) * K) : nullptr;

    auto stage = [&](int p, int k0) {
        // W staging via async gld (and A if bf16)
#pragma unroll
        for (int i = 0; i < 4; i++) {
            int rbase = pw * 32 + i * 8;
            gld_lds16(Whg + (size_t)(rbase + wrow) * K + k0 + wcol, sWh[p] + rbase * 64);
            if (DO_LO)
                gld_lds16(Wlg + (size_t)(rbase + wrow) * K + k0 + wcol, sWl[p] + rbase * 64);
            if (!A_F32)
                gld_lds16(Agb + (size_t)(rbase + wrow) * lda + k0 + wcol, sAh[p] + rbase * 64);
        }
        if (A_F32) {
            // A staging: 128x64 f32 tile -> split hi/lo bf16 in LDS. 8 float4/thread.
#pragma unroll
            for (int it = 0; it < 8; it++) {
                int idx = it * 256 + ptid;
                int r   = idx >> 4;
                int c4  = (idx & 15) * 4;
                float4 v = *(const float4*)(Agf + (size_t)r * lda + k0 + c4);
                ushort4 h, l;
                split_hl(v.x, h.x, l.x); split_hl(v.y, h.y, l.y);
                split_hl(v.z, h.z, l.z); split_hl(v.w, h.w, l.w);
                *(ushort4*)(sAh[p] + r * 64 + c4) = h;
                if (DO_LO) *(ushort4*)(sAl[p] + r * 64 + c4) = l;
            }
        }
    };

    // ---- consumer locals (waves 0-3)
    const int wave = tid >> 6;
    const int lane = tid & 63;
    const int wm = (wave >> 1) * 64;
    const int wn = (wave & 1) * 64;
    const int mrow = lane & 15;
    const int kq   = (lane >> 4) * 8;

    f32x4 acc[4][4];
#pragma unroll
    for (int i = 0; i < 4; i++)
#pragma unroll
        for (int j = 0; j < 4; j++) { acc[i][j][0]=0.f; acc[i][j][1]=0.f; acc[i][j][2]=0.f; acc[i][j][3]=0.f; }

    // prologue: stage buffer 0
    if (!is_cons) stage(0, 0);
    __syncthreads();

    for (int ks = 0; ks < NK; ks++) {
        const int p = ks & 1;
        if (is_cons) {
            const unsigned short* pAh = sAh[p];
            const unsigned short* pWh = sWh[p];
            const unsigned short* pAl = sAl[DO_LO ? p : 0];
            const unsigned short* pWl = sWl[DO_LO ? p : 0];
#pragma unroll
            for (int kk = 0; kk < 2; kk++) {
                bf16x8 afh[4], wfh[4];
#pragma unroll
                for (int i = 0; i < 4; i++)
                    afh[i] = *(const bf16x8*)(pAh + (wm + i * 16 + mrow) * 64 + kk * 32 + kq);
#pragma unroll
                for (int j = 0; j < 4; j++)
                    wfh[j] = *(const bf16x8*)(pWh + (wn + j * 16 + mrow) * 64 + kk * 32 + kq);
#pragma unroll
                for (int i = 0; i < 4; i++)
#pragma unroll
                    for (int j = 0; j < 4; j++)
                        acc[i][j] = __builtin_amdgcn_mfma_f32_16x16x32_bf16(afh[i], wfh[j], acc[i][j], 0, 0, 0);
                if (DO_LO) {
                    bf16x8 afl[4], wfl[4];
#pragma unroll
                    for (int i = 0; i < 4; i++)
                        afl[i] = *(const bf16x8*)(pAl + (wm + i * 16 + mrow) * 64 + kk * 32 + kq);
#pragma unroll
                    for (int j = 0; j < 4; j++)
                        wfl[j] = *(const bf16x8*)(pWl + (wn + j * 16 + mrow) * 64 + kk * 32 + kq);
#pragma unroll
                    for (int i = 0; i < 4; i++)
#pragma unroll
                        for (int j = 0; j < 4; j++) {
                            acc[i][j] = __builtin_amdgcn_mfma_f32_16x16x32_bf16(afh[i], wfl[j], acc[i][j], 0, 0, 0);
                            acc[i][j] = __builtin_amdgcn_mfma_f32_16x16x32_bf16(afl[i], wfh[j], acc[i][j], 0, 0, 0);
                        }
                }
            }
        } else if (ks + 1 < NK) {
            stage(p ^ 1, (ks + 1) * 64);
        }
        __syncthreads();
    }

    if (is_cons) {
        // epilogue: D[m][n]: m=(lane>>4)*4+r, n=lane&15 (m89-verified)
        const int r0 = (lane >> 4) * 4;
        const int cn = lane & 15;
#pragma unroll
        for (int i = 0; i < 4; i++) {
#pragma unroll
            for (int r = 0; r < 4; r++) {
                int row = bm * 128 + wm + i * 16 + r0 + r;
                size_t base = (size_t)row * N + bn * 128 + wn + cn;
                if constexpr (F32OUT) {
                    float* Crow = (float*)Cout + base;
#pragma unroll
                    for (int j = 0; j < 4; j++) Crow[j * 16] = acc[i][j][r];
                } else {
                    unsigned short* Crow = (unsigned short*)Cout + base;
#pragma unroll
                    for (int j = 0; j < 4; j++) Crow[j * 16] = f2bf(acc[i][j][r]);
                }
            }
        }
    }
}

// ---------------------------------------------------------------- per-head gates (exact fp32)
__device__ __forceinline__ float softplusf(float x) {
    return (x > 20.f) ? x : log1pf(expf(x));
}

__global__ __launch_bounds__(256)
void gates_k(const float* __restrict__ x, const float* __restrict__ a_w, const float* __restrict__ b_w,
             const float* __restrict__ b_bias, const float* __restrict__ beta_bias,
             const float* __restrict__ A_log, const float* __restrict__ dt_bias,
             float* __restrict__ g, float* __restrict__ beta) {
    int bt = blockIdx.x;
    int wave = threadIdx.x >> 6, lane = threadIdx.x & 63;
    const float* xr = x + (size_t)bt * C_;
#pragma unroll
    for (int dd = 0; dd < 8; dd++) {
        int d = wave * 8 + dd;
        int h = d & 15;
        const float* wr = (d < 16 ? a_w : b_w) + (size_t)h * C_;
        float acc = 0.f;
#pragma unroll
        for (int it = 0; it < 8; it++) {
            float4 xv = ((const float4*)xr)[lane + it * 64];
            float4 wv = ((const float4*)wr)[lane + it * 64];
            acc += xv.x * wv.x + xv.y * wv.y + xv.z * wv.z + xv.w * wv.w;
        }
        acc += __shfl_xor(acc, 1);  acc += __shfl_xor(acc, 2);  acc += __shfl_xor(acc, 4);
        acc += __shfl_xor(acc, 8);  acc += __shfl_xor(acc, 16); acc += __shfl_xor(acc, 32);
        if (lane == 0) {
            if (d < 16) {
                g[(size_t)bt * H_ + h] = -expf(A_log[h]) * softplusf(acc + dt_bias[h]);
            } else {
                float s = 1.f / (1.f + expf(-(acc + b_bias[h] + beta_bias[h])));
                beta[(size_t)bt * H_ + h] = 2.f * s;
            }
        }
    }
}

// ---------------------------------------------------------------- fused conv+silu+l2norm+scan (all f32)
// 128 blocks (b,h,vh) x 512 threads (8 waves).
// PRODUCER/CONSUMER wave specialization:
//   waves 0-3 (tid<256): sequential delta-rule step loop on chunk c (reads s-bufs[c&1])
//   waves 4-7 (tid>=256): stage raw q/k/v + gates, conv(4)+silu, l2norm for chunk c+1
//                         into s-bufs[(c+1)&1] (double-buffered)
#define CT_ 32
#define NCH_ (T_ / CT_)

// load step t2's fragments from LDS into registers (issued one step ahead)
#define LOAD_STEP(t2, kf, qf, vt, dec, btt)                                  \
    {                                                                        \
        _Pragma("unroll")                                                    \
        for (int u = 0; u < 4; u++) {                                        \
            float4 k4 = ((const float4*)(skp + (t2) * 68 + dk0))[u];         \
            float4 q4 = ((const float4*)(sqp + (t2) * 68 + dk0))[u];         \
            kf[u*4+0]=k4.x; kf[u*4+1]=k4.y; kf[u*4+2]=k4.z; kf[u*4+3]=k4.w;  \
            qf[u*4+0]=q4.x; qf[u*4+1]=q4.y; qf[u*4+2]=q4.z; qf[u*4+3]=q4.w;  \
        }                                                                    \
        vt  = svp[(t2) * 68 + dvl];                                          \
        dec = sgp_[(t2)];                                                    \
        btt = sbp_[(t2)];                                                    \
    }

// one delta-rule step. m-dot runs on PRE-decay S; mem = dec*m (identical algebra).
#define DO_STEP(t2, kf, qf, vt, dec, btt)                                    \
    {                                                                        \
        float m0=0.f, m1=0.f, m2=0.f, m3=0.f;                                \
        _Pragma("unroll")                                                    \
        for (int u = 0; u < 4; u++) {                                        \
            m0 += kf[u*4+0]*S[u*4+0]; m1 += kf[u*4+1]*S[u*4+1];              \
            m2 += kf[u*4+2]*S[u*4+2]; m3 += kf[u*4+3]*S[u*4+3];              \
        }                                                                    \
        float m = (m0 + m1) + (m2 + m3);                                     \
        m = dpp_xor1_add(m);                                                 \
        m = dpp_xor2_add(m);                                                 \
        _Pragma("unroll")                                                    \
        for (int i = 0; i < 16; i++) S[i] *= dec;                            \
        float delta = (vt - m * dec) * btt;                                  \
        float o0=0.f, o1=0.f, o2=0.f, o3=0.f;                                \
        _Pragma("unroll")                                                    \
        for (int u = 0; u < 4; u++) {                                        \
            S[u*4+0] += kf[u*4+0]*delta; o0 += qf[u*4+0]*S[u*4+0];           \
            S[u*4+1] += kf[u*4+1]*delta; o1 += qf[u*4+1]*S[u*4+1];           \
            S[u*4+2] += kf[u*4+2]*delta; o2 += qf[u*4+2]*S[u*4+2];           \
            S[u*4+3] += kf[u*4+3]*delta; o3 += qf[u*4+3]*S[u*4+3];           \
        }                                                                    \
        float ov = (o0 + o1) + (o2 + o3);                                    \
        ov = dpp_xor1_add(ov);                                               \
        ov = dpp_xor2_add(ov);                                               \
        if (dkq == 0)                                                        \
            vbuf[vbase + (size_t)(tc + (t2)) * 2048 + dvl] = ov;             \
    }

// run steps [TB,TE) with 2-deep register double-buffered prefetch
#define CONSUME_GROUP(TB, TE)                                                \
    {                                                                        \
        float kfa[16], qfa[16], kfb[16], qfb[16];                            \
        float vta, deca, btta, vtb, decb, bttb;                              \
        LOAD_STEP(TB, kfa, qfa, vta, deca, btta);                            \
        int t2 = TB;                                                         \
        _Pragma("unroll 1")                                                  \
        for (; t2 + 2 <= (TE); t2 += 2) {                                    \
            LOAD_STEP(t2 + 1, kfb, qfb, vtb, decb, bttb);                    \
            DO_STEP(t2, kfa, qfa, vta, deca, btta);                          \
            if (t2 + 2 < (TE))                                               \
                LOAD_STEP(t2 + 2, kfa, qfa, vta, deca, btta);                \
            DO_STEP(t2 + 1, kfb, qfb, vtb, decb, bttb);                      \
        }                                                                    \
        if (t2 < (TE))                                                       \
            DO_STEP(t2, kfa, qfa, vta, deca, btta);                          \
    }

__global__ __launch_bounds__(512)
void scan_fused(const float* __restrict__ qk, float* __restrict__ vbuf,
                const float* __restrict__ qcw, const float* __restrict__ kcw, const float* __restrict__ vcw,
                const float* __restrict__ g, const float* __restrict__ beta) {
    int blk = blockIdx.x;
    int vh  = blk & 1;
    int bh  = blk >> 1;
    int b   = bh >> 4;
    int h   = bh & 15;
    int tid = threadIdx.x;

    __shared__ __align__(16) float rawq[2][(CT_ + 3) * 64];
    __shared__ __align__(16) float rawk[2][(CT_ + 3) * 64];
    __shared__ __align__(16) float rawv[2][(CT_ + 3) * 64];
    __shared__ __align__(16) float sq[2][CT_ * 68];
    __shared__ __align__(16) float sk[2][CT_ * 68];
    __shared__ __align__(16) float sv[2][CT_ * 68];
    __shared__ float sg[2][CT_];
    __shared__ float sb[2][CT_];

    const size_t qbase = (size_t)b * T_ * 2048 + h * 64;
    const size_t kbase = qbase + 1024;
    const size_t vbase = (size_t)b * T_ * 2048 + h * 128 + vh * 64;
    const size_t gbase = (size_t)b * T_ * H_ + h;

    const bool is_cons = (tid < 256);

    // ---------------- producer-local state (waves 4-7)
    const int ptid = tid - 256;
    const int pc   = ptid & 63;   // column 0..63
    const int pw   = ptid >> 6;   // producer wave 0..3
    float wqa[4], wka[4], wva[4];
    if (!is_cons) {
        float4 a4 = *(const float4*)(qcw + (size_t)(h * 64 + pc) * 4);
        float4 b4 = *(const float4*)(kcw + (size_t)(h * 64 + pc) * 4);
        float4 c4 = *(const float4*)(vcw + (size_t)(h * 128 + vh * 64 + pc) * 4);
        wqa[0]=a4.x; wqa[1]=a4.y; wqa[2]=a4.z; wqa[3]=a4.w;
        wka[0]=b4.x; wka[1]=b4.y; wka[2]=b4.z; wka[3]=b4.w;
        wva[0]=c4.x; wva[1]=c4.y; wva[2]=c4.z; wva[3]=c4.w;
        // chunk 0 pulls its causal zero-pad carry from buffer 1: zero those rows.
        if (ptid < 192) {
            int bsel = ptid >> 6, c = ptid & 63;
            float* rb = bsel == 0 ? rawq[1] : (bsel == 1 ? rawk[1] : rawv[1]);
#pragma unroll
            for (int j = 0; j < 3; j++) rb[(CT_ + j) * 64 + c] = 0.f;
        }
    }

    // phase1: carry-copy (from OTHER raw buffer) + fresh global stage + gates
    auto prod_phase1 = [&](int ci) {
        int rp = ci & 1;
        int tcc = ci * CT_;
        float* rq = rawq[rp]; float* rk = rawk[rp]; float* rv = rawv[rp];
        const float* pq = rawq[rp ^ 1]; const float* pk = rawk[rp ^ 1]; const float* pv = rawv[rp ^ 1];
        if (ptid < 192) {
            int bsel = ptid >> 6, c = ptid & 63;
            float*       db = bsel == 0 ? rq : (bsel == 1 ? rk : rv);
            const float* sc = bsel == 0 ? pq : (bsel == 1 ? pk : pv);
#pragma unroll
            for (int j = 0; j < 3; j++) db[j * 64 + c] = sc[(CT_ + j) * 64 + c];
        }
#pragma unroll
        for (int u = 0; u < 2; u++) {
            int idx = u * 256 + ptid;
            int r   = idx >> 4;
            int c4  = (idx & 15) * 4;
            size_t row = (size_t)(tcc + r) * 2048;
            *(float4*)(rq + (3 + r) * 64 + c4) = *(const float4*)(qk + qbase + row + c4);
            *(float4*)(rk + (3 + r) * 64 + c4) = *(const float4*)(qk + kbase + row + c4);
            *(float4*)(rv + (3 + r) * 64 + c4) = *(const float4*)(vbuf + vbase + row + c4);
        }
        if (ptid < CT_)          sg[rp][ptid]       = expf(g[gbase + (size_t)(tcc + ptid) * H_]);
        else if (ptid < 2 * CT_) sb[rp][ptid - CT_] = beta[gbase + (size_t)(tcc + ptid - CT_) * H_];
    };

    // phase2: conv(4)+silu, weights in registers
    auto prod_phase2 = [&](int ci) {
        int rp = ci & 1;
        const float* rq = rawq[rp]; const float* rk = rawk[rp]; const float* rv = rawv[rp];
        float* dq = sq[rp]; float* dk = sk[rp]; float* dv = sv[rp];
#pragma unroll
        for (int it = 0; it < 8; it++) {
            int r = pw + it * 4;
            float aq = 0.f, ak = 0.f, av = 0.f;
#pragma unroll
            for (int j = 0; j < 4; j++) {
                aq += wqa[j] * rq[(r + j) * 64 + pc];
                ak += wka[j] * rk[(r + j) * 64 + pc];
                av += wva[j] * rv[(r + j) * 64 + pc];
            }
            dq[r * 68 + pc] = siluf(aq);
            dk[r * 68 + pc] = siluf(ak);
            dv[r * 68 + pc] = siluf(av);
        }
    };

    // phase3: l2norm q,k rows (8 lanes/row), float4 loads/stores
    auto prod_phase3 = [&](int ci) {
        int rp = ci & 1;
        int r = ptid >> 3;
        int j = ptid & 7;
        float* kr = sk[rp] + r * 68 + j * 8;
        float* qr = sq[rp] + r * 68 + j * 8;
        float4 k0 = ((const float4*)kr)[0], k1 = ((const float4*)kr)[1];
        float4 q0 = ((const float4*)qr)[0], q1 = ((const float4*)qr)[1];
        float ssk = k0.x*k0.x + k0.y*k0.y + k0.z*k0.z + k0.w*k0.w
                  + k1.x*k1.x + k1.y*k1.y + k1.z*k1.z + k1.w*k1.w;
        float ssq = q0.x*q0.x + q0.y*q0.y + q0.z*q0.z + q0.w*q0.w
                  + q1.x*q1.x + q1.y*q1.y + q1.z*q1.z + q1.w*q1.w;
        ssk += __shfl_xor(ssk, 1); ssk += __shfl_xor(ssk, 2); ssk += __shfl_xor(ssk, 4);
        ssq += __shfl_xor(ssq, 1); ssq += __shfl_xor(ssq, 2); ssq += __shfl_xor(ssq, 4);
        float rk_ = rsqrtf(ssk + 1e-6f);
        float rq_ = rsqrtf(ssq + 1e-6f) * 0.125f;   // fold SCALE = DK^-0.5
        k0.x*=rk_; k0.y*=rk_; k0.z*=rk_; k0.w*=rk_;
        k1.x*=rk_; k1.y*=rk_; k1.z*=rk_; k1.w*=rk_;
        q0.x*=rq_; q0.y*=rq_; q0.z*=rq_; q0.w*=rq_;
        q1.x*=rq_; q1.y*=rq_; q1.z*=rq_; q1.w*=rq_;
        ((float4*)kr)[0] = k0; ((float4*)kr)[1] = k1;
        ((float4*)qr)[0] = q0; ((float4*)qr)[1] = q1;
    };

    // ---------------- consumer-local state (waves 0-3)
    const int dkq = tid & 3;
    const int dvl = tid >> 2;
    const int dk0 = dkq * 16;
    float S[16];
#pragma unroll
    for (int i = 0; i < 16; i++) S[i] = 0.f;

    // prologue: produce chunk 0 into buffer 0 (consumers idle at barriers)
    if (!is_cons) prod_phase1(0);
    __syncthreads();
    if (!is_cons) prod_phase2(0);
    __syncthreads();
    if (!is_cons) prod_phase3(0);
    __syncthreads();

    for (int ci = 0; ci < NCH_; ci++) {
        const int p  = ci & 1;
        const int tc = ci * CT_;
        const float* sqp  = sq[p];
        const float* skp  = sk[p];
        const float* svp  = sv[p];
        const float* sgp_ = sg[p];
        const float* sbp_ = sb[p];

        if (is_cons) { CONSUME_GROUP(0, 11); }
        else if (ci + 1 < NCH_) prod_phase1(ci + 1);
        __syncthreads();
        if (is_cons) { CONSUME_GROUP(11, 22); }
        else if (ci + 1 < NCH_) prod_phase2(ci + 1);
        __syncthreads();
        if (is_cons) { CONSUME_GROUP(22, 32); }
        else if (ci + 1 < NCH_) prod_phase3(ci + 1);
        __syncthreads();
    }
}

// ---------------------------------------------------------------- postnorm: rms(o)*silu(g_out) -> og bf16
__global__ __launch_bounds__(256)
void postnorm_k(float* __restrict__ vbuf, const unsigned short* __restrict__ gout) {
    int bt  = blockIdx.x;
    int tid = threadIdx.x;
    const float* orow = vbuf + (size_t)bt * 2048 + tid * 8;
    float4 a = ((const float4*)orow)[0];
    float4 c = ((const float4*)orow)[1];
    float ss = a.x*a.x + a.y*a.y + a.z*a.z + a.w*a.w
             + c.x*c.x + c.y*c.y + c.z*c.z + c.w*c.w;
    ss += __shfl_xor(ss, 1); ss += __shfl_xor(ss, 2); ss += __shfl_xor(ss, 4); ss += __shfl_xor(ss, 8);
    float rms = rsqrtf(ss * (1.f / 128.f) + 1.1920928955078125e-07f);
    const unsigned short* grow = gout + (size_t)bt * 2048 + tid * 8;
    ushort4 g1 = ((const ushort4*)grow)[0];
    ushort4 g2 = ((const ushort4*)grow)[1];
    ushort4 r0, r1;
    r0.x = f2bf(a.x * rms * siluf(bf2f(g1.x)));
    r0.y = f2bf(a.y * rms * siluf(bf2f(g1.y)));
    r0.z = f2bf(a.z * rms * siluf(bf2f(g1.z)));
    r0.w = f2bf(a.w * rms * siluf(bf2f(g1.w)));
    r1.x = f2bf(c.x * rms * siluf(bf2f(g2.x)));
    r1.y = f2bf(c.y * rms * siluf(bf2f(g2.y)));
    r1.z = f2bf(c.z * rms * siluf(bf2f(g2.z)));
    r1.w = f2bf(c.w * rms * siluf(bf2f(g2.w)));
    __syncthreads();   // all reads of this row done before in-place overwrite
    unsigned short* og = (unsigned short*)vbuf + (size_t)bt * 4096 + tid * 8;
    *(ushort4*)og       = r0;
    *(ushort4*)(og + 4) = r1;
}

// ---------------------------------------------------------------- launch
// ws (121 MiB peak):
//   [0,8)    qkw_h    [8,16)   qkw_l
//   [16,32)  vgw_h    [32,48)  vgw_l   (lo cast only for v-half rows 0..2047)
//   [48,56)  ow_bf
//   [56,120) vbuf f32: GEMM2v out -> o (scan, in-place) -> og bf16 (postnorm, stride 4096)
//   [120,121) gbuf, bbuf
// d_out (64 MiB f32): qk f32 (GEMM1) -> consumed by scan -> g_out bf16 [0,32MiB)
//   (GEMMg, after scan) -> final f32 output (overwrites everything).
extern "C" void kernel_launch(void* const* d_in, const int* in_sizes, int n_in,
                              void* d_out, int out_size, void* d_ws, size_t ws_size,
                              hipStream_t stream) {
    (void)in_sizes; (void)n_in; (void)out_size; (void)ws_size;
    const float* x        = (const float*)d_in[0];
    const float* qk_w     = (const float*)d_in[1];
    const float* vg_w     = (const float*)d_in[2];
    const float* o_w      = (const float*)d_in[3];
    const float* a_w      = (const float*)d_in[4];
    const float* b_w      = (const float*)d_in[5];
    const float* b_bias   = (const float*)d_in[6];
    const float* beta_b   = (const float*)d_in[7];
    const float* A_log    = (const float*)d_in[8];
    const float* dt_bias  = (const float*)d_in[9];
    const float* q_conv_w = (const float*)d_in[10];
    const float* k_conv_w = (const float*)d_in[11];
    const float* v_conv_w = (const float*)d_in[12];

    char* ws = (char*)d_ws;
    unsigned short* qkw_h = (unsigned short*)(ws);
    unsigned short* qkw_l = (unsigned short*)(ws + (8u  << 20));
    unsigned short* vgw_h = (unsigned short*)(ws + (16u << 20));
    unsigned short* vgw_l = (unsigned short*)(ws + (32u << 20));
    unsigned short* ow_bf = (unsigned short*)(ws + (48u << 20));
    float*          vbuf  = (float*)(ws + (56u << 20));
    float*          gbuf  = (float*)(ws + (120u << 20));
    float*          bbuf  = (float*)(ws + (120u << 20) + (512u << 10));

    float* qkf            = (float*)d_out;                 // qk f32 (GEMM1)
    unsigned short* goutb = (unsigned short*)d_out;        // g_out bf16 (after scan)
    float* outp           = (float*)d_out;                 // final f32 output

    // 1) weight casts (vg: split v-half only; g-half hi-only)
    cast_split_k<<<(2048 * 2048 / 4 + 255) / 256, 256, 0, stream>>>(qk_w, qkw_h, qkw_l, 2048 * 2048 / 4);
    cast_split_k<<<(2048 * 2048 / 4 + 255) / 256, 256, 0, stream>>>(vg_w, vgw_h, vgw_l, 2048 * 2048 / 4);
    cast_plain_k<<<(2048 * 2048 / 4 + 255) / 256, 256, 0, stream>>>(
        vg_w + (size_t)2048 * 2048, vgw_h + (size_t)2048 * 2048, 2048 * 2048 / 4);
    cast_plain_k<<<(2048 * 2048 / 4 + 255) / 256, 256, 0, stream>>>(o_w, ow_bf, 2048 * 2048 / 4);

    // 2) split-precision GEMMs (producer/consumer): qk f32 -> d_out; v f32 -> vbuf
    gemm_pc<true, true, true><<<dim3(16, 64), 512, 0, stream>>>(x, 2048, qkw_h, qkw_l, qkf, BT_, 2048, 2048);
    gemm_pc<true, true, true><<<dim3(16, 64), 512, 0, stream>>>(x, 2048, vgw_h, vgw_l, vbuf, BT_, 2048, 2048);

    // 3) gates (exact fp32)
    gates_k<<<BT_, 256, 0, stream>>>(x, a_w, b_w, b_bias, beta_b, A_log, dt_bias, gbuf, bbuf);

    // 4) fused conv+silu+l2norm+scan -> o f32 in-place over vbuf (producer/consumer, 512 thr)
    scan_fused<<<B_ * H_ * 2, 512, 0, stream>>>(qkf, vbuf, q_conv_w, k_conv_w, v_conv_w, gbuf, bbuf);

    // 5) g_out = x @ vg_w[2048:].T, hi-only bf16 -> d_out[0,32MiB) (qk consumed)
    gemm_pc<false, false, true><<<dim3(16, 64), 512, 0, stream>>>(
        x, 2048, vgw_h + (size_t)2048 * 2048, nullptr, goutb, BT_, 2048, 2048);

    // 6) postnorm -> og bf16 in-place over vbuf (stride 4096 ushort)
    postnorm_k<<<BT_, 256, 0, stream>>>(vbuf, goutb);

    // 7) final GEMM: og @ o_w.T -> d_out f32 (A bf16 path, lda=4096)
    gemm_pc<false, true, false><<<dim3(16, 64), 512, 0, stream>>>(
        (const void*)vbuf, 4096, ow_bf, nullptr, outp, BT_, 2048, 2048);
}

// Round 4
// 1482.941 us; speedup vs baseline: 1.5727x; 1.1492x over previous
//
#include <hip/hip_runtime.h>
#include <hip/hip_bf16.h>
#include <stdint.h>

// Problem constants
#define B_ 4
#define T_ 2048
#define C_ 2048
#define H_ 16
#define DK_ 64
#define DV_ 128
#define BT_ (B_ * T_)   // 8192

typedef __attribute__((ext_vector_type(8))) __bf16 bf16x8;
typedef __attribute__((ext_vector_type(4))) float f32x4;

__device__ __forceinline__ unsigned short f2bf(float f) {
    union { float f; uint32_t u; } v; v.f = f;
    uint32_t u = v.u;
    uint32_t r = u + 0x7FFFu + ((u >> 16) & 1u);   // RNE
    return (unsigned short)(r >> 16);
}
__device__ __forceinline__ float bf2f(unsigned short h) {
    union { uint32_t u; float f; } v; v.u = ((uint32_t)h) << 16; return v.f;
}
__device__ __forceinline__ float siluf(float x) { return x / (1.f + expf(-x)); }

// DPP quad-reduce helpers: sum across the 4 lanes of a quad (lanes grouped as tid&3).
__device__ __forceinline__ float dpp_xor1_add(float x) {
    int t = __builtin_amdgcn_update_dpp(0, __float_as_int(x), 0xB1, 0xF, 0xF, true);
    return x + __int_as_float(t);
}
__device__ __forceinline__ float dpp_xor2_add(float x) {
    int t = __builtin_amdgcn_update_dpp(0, __float_as_int(x), 0x4E, 0xF, 0xF, true);
    return x + __int_as_float(t);
}

// hi = RNE bf16 of x; lo = trunc bf16 of (x - hi). x ≈ hi + lo to ~2^-17 rel.
__device__ __forceinline__ void split_hl(float x, unsigned short& h, unsigned short& l) {
    unsigned short hu = f2bf(x);
    float lo = x - bf2f(hu);
    h = hu;
    l = (unsigned short)(__float_as_uint(lo) >> 16);
}

// ---------------------------------------------------------------- casts
__global__ void cast_split_k(const float* __restrict__ in,
                             unsigned short* __restrict__ oh, unsigned short* __restrict__ ol, int n4) {
    int i = blockIdx.x * blockDim.x + threadIdx.x;
    if (i >= n4) return;
    float4 v = ((const float4*)in)[i];
    ushort4 h, l;
    split_hl(v.x, h.x, l.x); split_hl(v.y, h.y, l.y);
    split_hl(v.z, h.z, l.z); split_hl(v.w, h.w, l.w);
    ((ushort4*)oh)[i] = h;
    ((ushort4*)ol)[i] = l;
}

__global__ void cast_plain_k(const float* __restrict__ in, unsigned short* __restrict__ out, int n4) {
    int i = blockIdx.x * blockDim.x + threadIdx.x;
    if (i >= n4) return;
    float4 v = ((const float4*)in)[i];
    ushort4 o;
    o.x = f2bf(v.x); o.y = f2bf(v.y); o.z = f2bf(v.z); o.w = f2bf(v.w);
    ((ushort4*)out)[i] = o;
}

// ---------------------------------------------------------------- async global->LDS (16B/lane)
__device__ __forceinline__ void gld_lds16(const unsigned short* gptr,
                                          unsigned short* lds_base) {
    __builtin_amdgcn_global_load_lds(
        (const __attribute__((address_space(1))) uint32_t*)(uintptr_t)gptr,
        (__attribute__((address_space(3))) uint32_t*)(uint32_t)(uintptr_t)lds_base,
        16, 0, 0);
}

// ---------------------------------------------------------------- all-bf16 GEMM (m97 structure)
// C[M,N] = (Ah+Al)[M,K] * (Wh+Wl)[N,K]^T, all operands pre-cast bf16, staged purely via
// global_load_lds (no VALU staging). 256 thr, 64 KB LDS (DO_LO) -> 2 blocks/CU so one
// block's staging overlaps the other's MFMA (m114 implicit wave-level overlap).
// DO_LO: acc = AhWh + AhWl + AlWh (bitwise identical to the old in-GEMM f32 split).
template<bool DO_LO, bool F32OUT>
__global__ __launch_bounds__(256)
void gemm_bf(const unsigned short* __restrict__ Ah, const unsigned short* __restrict__ Al, int lda,
             const unsigned short* __restrict__ Wh, const unsigned short* __restrict__ Wl,
             void* __restrict__ Cout, int M, int N, int K) {
    __shared__ __align__(16) unsigned short sAh[128 * 64];
    __shared__ __align__(16) unsigned short sWh[128 * 64];
    __shared__ __align__(16) unsigned short sAl[DO_LO ? 128 * 64 : 16];
    __shared__ __align__(16) unsigned short sWl[DO_LO ? 128 * 64 : 16];
    const int tid  = threadIdx.x;
    const int wave = tid >> 6;
    const int lane = tid & 63;
    const int wm = (wave >> 1) * 64;
    const int wn = (wave & 1) * 64;
    const int bm = blockIdx.y, bn = blockIdx.x;
    const int srow = lane >> 3;
    const int scol = (lane & 7) * 8;

    const unsigned short* Agh = Ah + (size_t)(bm * 128) * lda;
    const unsigned short* Agl = DO_LO ? (Al + (size_t)(bm * 128) * lda) : nullptr;
    const unsigned short* Wgh = Wh + (size_t)(bn * 128) * K;
    const unsigned short* Wgl = DO_LO ? (Wl + (size_t)(bn * 128) * K) : nullptr;

    f32x4 acc[4][4];
#pragma unroll
    for (int i = 0; i < 4; i++)
#pragma unroll
        for (int j = 0; j < 4; j++) { acc[i][j][0]=0.f; acc[i][j][1]=0.f; acc[i][j][2]=0.f; acc[i][j][3]=0.f; }

    const int mrow = lane & 15;
    const int kq   = (lane >> 4) * 8;

    for (int k0 = 0; k0 < K; k0 += 64) {
#pragma unroll
        for (int i = 0; i < 4; i++) {
            int rbase = wave * 32 + i * 8;
            gld_lds16(Agh + (size_t)(rbase + srow) * lda + k0 + scol, sAh + rbase * 64);
            gld_lds16(Wgh + (size_t)(rbase + srow) * K   + k0 + scol, sWh + rbase * 64);
            if (DO_LO) {
                gld_lds16(Agl + (size_t)(rbase + srow) * lda + k0 + scol, sAl + rbase * 64);
                gld_lds16(Wgl + (size_t)(rbase + srow) * K   + k0 + scol, sWl + rbase * 64);
            }
        }
        __syncthreads();
#pragma unroll
        for (int kk = 0; kk < 2; kk++) {
            bf16x8 afh[4], wfh[4];
#pragma unroll
            for (int i = 0; i < 4; i++)
                afh[i] = *(const bf16x8*)(sAh + (wm + i * 16 + mrow) * 64 + kk * 32 + kq);
#pragma unroll
            for (int j = 0; j < 4; j++)
                wfh[j] = *(const bf16x8*)(sWh + (wn + j * 16 + mrow) * 64 + kk * 32 + kq);
#pragma unroll
            for (int i = 0; i < 4; i++)
#pragma unroll
                for (int j = 0; j < 4; j++)
                    acc[i][j] = __builtin_amdgcn_mfma_f32_16x16x32_bf16(afh[i], wfh[j], acc[i][j], 0, 0, 0);
            if (DO_LO) {
                bf16x8 afl[4], wfl[4];
#pragma unroll
                for (int i = 0; i < 4; i++)
                    afl[i] = *(const bf16x8*)(sAl + (wm + i * 16 + mrow) * 64 + kk * 32 + kq);
#pragma unroll
                for (int j = 0; j < 4; j++)
                    wfl[j] = *(const bf16x8*)(sWl + (wn + j * 16 + mrow) * 64 + kk * 32 + kq);
#pragma unroll
                for (int i = 0; i < 4; i++)
#pragma unroll
                    for (int j = 0; j < 4; j++) {
                        acc[i][j] = __builtin_amdgcn_mfma_f32_16x16x32_bf16(afh[i], wfl[j], acc[i][j], 0, 0, 0);
                        acc[i][j] = __builtin_amdgcn_mfma_f32_16x16x32_bf16(afl[i], wfh[j], acc[i][j], 0, 0, 0);
                    }
            }
        }
        __syncthreads();
    }
    // epilogue: D[m][n]: m=(lane>>4)*4+r, n=lane&15 (m89-verified)
    const int r0 = (lane >> 4) * 4;
    const int cn = lane & 15;
#pragma unroll
    for (int i = 0; i < 4; i++) {
#pragma unroll
        for (int r = 0; r < 4; r++) {
            int row = bm * 128 + wm + i * 16 + r0 + r;
            size_t base = (size_t)row * N + bn * 128 + wn + cn;
            if constexpr (F32OUT) {
                float* Crow = (float*)Cout + base;
#pragma unroll
                for (int j = 0; j < 4; j++) Crow[j * 16] = acc[i][j][r];
            } else {
                unsigned short* Crow = (unsigned short*)Cout + base;
#pragma unroll
                for (int j = 0; j < 4; j++) Crow[j * 16] = f2bf(acc[i][j][r]);
            }
        }
    }
}

// ---------------------------------------------------------------- legacy producer/consumer GEMM (ws-tight fallback)
template<bool DO_LO, bool F32OUT, bool A_F32>
__global__ __launch_bounds__(512, 2)
void gemm_pc(const void* __restrict__ Aptr, int lda,
             const unsigned short* __restrict__ Wh, const unsigned short* __restrict__ Wl,
             void* __restrict__ Cout, int M, int N, int K) {
    __shared__ __align__(16) unsigned short sAh[2][128 * 64];
    __shared__ __align__(16) unsigned short sWh[2][128 * 64];
    __shared__ __align__(16) unsigned short sAl[DO_LO ? 2 : 1][DO_LO ? 128 * 64 : 16];
    __shared__ __align__(16) unsigned short sWl[DO_LO ? 2 : 1][DO_LO ? 128 * 64 : 16];

    const int tid  = threadIdx.x;
    const bool is_cons = (tid < 256);
    const int bm = blockIdx.y, bn = blockIdx.x;
    const int NK = K >> 6;

    const int ptid  = tid - 256;
    const int pw    = ptid >> 6;
    const int plane = ptid & 63;
    const int wrow  = plane >> 3;
    const int wcol  = (plane & 7) * 8;

    const float*          Agf = (const float*)Aptr + (size_t)(bm * 128) * lda;
    const unsigned short* Agb = (const unsigned short*)Aptr + (size_t)(bm * 128) * lda;
    const unsigned short* Whg = Wh + (size_t)(bn * 128) * K;
    const unsigned short* Wlg = DO_LO ? (Wl + (size_t)(bn * 128) * K) : nullptr;

    auto stage = [&](int p, int k0) {
#pragma unroll
        for (int i = 0; i < 4; i++) {
            int rbase = pw * 32 + i * 8;
            gld_lds16(Whg + (size_t)(rbase + wrow) * K + k0 + wcol, sWh[p] + rbase * 64);
            if (DO_LO)
                gld_lds16(Wlg + (size_t)(rbase + wrow) * K + k0 + wcol, sWl[p] + rbase * 64);
            if (!A_F32)
                gld_lds16(Agb + (size_t)(rbase + wrow) * lda + k0 + wcol, sAh[p] + rbase * 64);
        }
        if (A_F32) {
#pragma unroll
            for (int it = 0; it < 8; it++) {
                int idx = it * 256 + ptid;
                int r   = idx >> 4;
                int c4  = (idx & 15) * 4;
                float4 v = *(const float4*)(Agf + (size_t)r * lda + k0 + c4);
                ushort4 h, l;
                split_hl(v.x, h.x, l.x); split_hl(v.y, h.y, l.y);
                split_hl(v.z, h.z, l.z); split_hl(v.w, h.w, l.w);
                *(ushort4*)(sAh[p] + r * 64 + c4) = h;
                if (DO_LO) *(ushort4*)(sAl[p] + r * 64 + c4) = l;
            }
        }
    };

    const int wave = tid >> 6;
    const int lane = tid & 63;
    const int wm = (wave >> 1) * 64;
    const int wn = (wave & 1) * 64;
    const int mrow = lane & 15;
    const int kq   = (lane >> 4) * 8;

    f32x4 acc[4][4];
#pragma unroll
    for (int i = 0; i < 4; i++)
#pragma unroll
        for (int j = 0; j < 4; j++) { acc[i][j][0]=0.f; acc[i][j][1]=0.f; acc[i][j][2]=0.f; acc[i][j][3]=0.f; }

    if (!is_cons) stage(0, 0);
    __syncthreads();

    for (int ks = 0; ks < NK; ks++) {
        const int p = ks & 1;
        if (is_cons) {
            const unsigned short* pAh = sAh[p];
            const unsigned short* pWh = sWh[p];
            const unsigned short* pAl = sAl[DO_LO ? p : 0];
            const unsigned short* pWl = sWl[DO_LO ? p : 0];
#pragma unroll
            for (int kk = 0; kk < 2; kk++) {
                bf16x8 afh[4], wfh[4];
#pragma unroll
                for (int i = 0; i < 4; i++)
                    afh[i] = *(const bf16x8*)(pAh + (wm + i * 16 + mrow) * 64 + kk * 32 + kq);
#pragma unroll
                for (int j = 0; j < 4; j++)
                    wfh[j] = *(const bf16x8*)(pWh + (wn + j * 16 + mrow) * 64 + kk * 32 + kq);
#pragma unroll
                for (int i = 0; i < 4; i++)
#pragma unroll
                    for (int j = 0; j < 4; j++)
                        acc[i][j] = __builtin_amdgcn_mfma_f32_16x16x32_bf16(afh[i], wfh[j], acc[i][j], 0, 0, 0);
                if (DO_LO) {
                    bf16x8 afl[4], wfl[4];
#pragma unroll
                    for (int i = 0; i < 4; i++)
                        afl[i] = *(const bf16x8*)(pAl + (wm + i * 16 + mrow) * 64 + kk * 32 + kq);
#pragma unroll
                    for (int j = 0; j < 4; j++)
                        wfl[j] = *(const bf16x8*)(pWl + (wn + j * 16 + mrow) * 64 + kk * 32 + kq);
#pragma unroll
                    for (int i = 0; i < 4; i++)
#pragma unroll
                        for (int j = 0; j < 4; j++) {
                            acc[i][j] = __builtin_amdgcn_mfma_f32_16x16x32_bf16(afh[i], wfl[j], acc[i][j], 0, 0, 0);
                            acc[i][j] = __builtin_amdgcn_mfma_f32_16x16x32_bf16(afl[i], wfh[j], acc[i][j], 0, 0, 0);
                        }
                }
            }
        } else if (ks + 1 < NK) {
            stage(p ^ 1, (ks + 1) * 64);
        }
        __syncthreads();
    }

    if (is_cons) {
        const int r0 = (lane >> 4) * 4;
        const int cn = lane & 15;
#pragma unroll
        for (int i = 0; i < 4; i++) {
#pragma unroll
            for (int r = 0; r < 4; r++) {
                int row = bm * 128 + wm + i * 16 + r0 + r;
                size_t base = (size_t)row * N + bn * 128 + wn + cn;
                if constexpr (F32OUT) {
                    float* Crow = (float*)Cout + base;
#pragma unroll
                    for (int j = 0; j < 4; j++) Crow[j * 16] = acc[i][j][r];
                } else {
                    unsigned short* Crow = (unsigned short*)Cout + base;
#pragma unroll
                    for (int j = 0; j < 4; j++) Crow[j * 16] = f2bf(acc[i][j][r]);
                }
            }
        }
    }
}

// ---------------------------------------------------------------- per-head gates (exact fp32)
__device__ __forceinline__ float softplusf(float x) {
    return (x > 20.f) ? x : log1pf(expf(x));
}

__global__ __launch_bounds__(256)
void gates_k(const float* __restrict__ x, const float* __restrict__ a_w, const float* __restrict__ b_w,
             const float* __restrict__ b_bias, const float* __restrict__ beta_bias,
             const float* __restrict__ A_log, const float* __restrict__ dt_bias,
             float* __restrict__ g, float* __restrict__ beta) {
    int bt = blockIdx.x;
    int wave = threadIdx.x >> 6, lane = threadIdx.x & 63;
    const float* xr = x + (size_t)bt * C_;
#pragma unroll
    for (int dd = 0; dd < 8; dd++) {
        int d = wave * 8 + dd;
        int h = d & 15;
        const float* wr = (d < 16 ? a_w : b_w) + (size_t)h * C_;
        float acc = 0.f;
#pragma unroll
        for (int it = 0; it < 8; it++) {
            float4 xv = ((const float4*)xr)[lane + it * 64];
            float4 wv = ((const float4*)wr)[lane + it * 64];
            acc += xv.x * wv.x + xv.y * wv.y + xv.z * wv.z + xv.w * wv.w;
        }
        acc += __shfl_xor(acc, 1);  acc += __shfl_xor(acc, 2);  acc += __shfl_xor(acc, 4);
        acc += __shfl_xor(acc, 8);  acc += __shfl_xor(acc, 16); acc += __shfl_xor(acc, 32);
        if (lane == 0) {
            if (d < 16) {
                g[(size_t)bt * H_ + h] = -expf(A_log[h]) * softplusf(acc + dt_bias[h]);
            } else {
                float s = 1.f / (1.f + expf(-(acc + b_bias[h] + beta_bias[h])));
                beta[(size_t)bt * H_ + h] = 2.f * s;
            }
        }
    }
}

// ---------------------------------------------------------------- fused conv+silu+l2norm+scan (all f32)
#define CT_ 32
#define NCH_ (T_ / CT_)

#define LOAD_STEP(t2, kf, qf, vt, dec, btt)                                  \
    {                                                                        \
        _Pragma("unroll")                                                    \
        for (int u = 0; u < 4; u++) {                                        \
            float4 k4 = ((const float4*)(skp + (t2) * 68 + dk0))[u];         \
            float4 q4 = ((const float4*)(sqp + (t2) * 68 + dk0))[u];         \
            kf[u*4+0]=k4.x; kf[u*4+1]=k4.y; kf[u*4+2]=k4.z; kf[u*4+3]=k4.w;  \
            qf[u*4+0]=q4.x; qf[u*4+1]=q4.y; qf[u*4+2]=q4.z; qf[u*4+3]=q4.w;  \
        }                                                                    \
        vt  = svp[(t2) * 68 + dvl];                                          \
        dec = sgp_[(t2)];                                                    \
        btt = sbp_[(t2)];                                                    \
    }

#define DO_STEP(t2, kf, qf, vt, dec, btt)                                    \
    {                                                                        \
        float m0=0.f, m1=0.f, m2=0.f, m3=0.f;                                \
        _Pragma("unroll")                                                    \
        for (int u = 0; u < 4; u++) {                                        \
            m0 += kf[u*4+0]*S[u*4+0]; m1 += kf[u*4+1]*S[u*4+1];              \
            m2 += kf[u*4+2]*S[u*4+2]; m3 += kf[u*4+3]*S[u*4+3];              \
        }                                                                    \
        float m = (m0 + m1) + (m2 + m3);                                     \
        m = dpp_xor1_add(m);                                                 \
        m = dpp_xor2_add(m);                                                 \
        _Pragma("unroll")                                                    \
        for (int i = 0; i < 16; i++) S[i] *= dec;                            \
        float delta = (vt - m * dec) * btt;                                  \
        float o0=0.f, o1=0.f, o2=0.f, o3=0.f;                                \
        _Pragma("unroll")                                                    \
        for (int u = 0; u < 4; u++) {                                        \
            S[u*4+0] += kf[u*4+0]*delta; o0 += qf[u*4+0]*S[u*4+0];           \
            S[u*4+1] += kf[u*4+1]*delta; o1 += qf[u*4+1]*S[u*4+1];           \
            S[u*4+2] += kf[u*4+2]*delta; o2 += qf[u*4+2]*S[u*4+2];           \
            S[u*4+3] += kf[u*4+3]*delta; o3 += qf[u*4+3]*S[u*4+3];           \
        }                                                                    \
        float ov = (o0 + o1) + (o2 + o3);                                    \
        ov = dpp_xor1_add(ov);                                               \
        ov = dpp_xor2_add(ov);                                               \
        if (dkq == 0)                                                        \
            vbuf[vbase + (size_t)(tc + (t2)) * 2048 + dvl] = ov;             \
    }

#define CONSUME_GROUP(TB, TE)                                                \
    {                                                                        \
        float kfa[16], qfa[16], kfb[16], qfb[16];                            \
        float vta, deca, btta, vtb, decb, bttb;                              \
        LOAD_STEP(TB, kfa, qfa, vta, deca, btta);                            \
        int t2 = TB;                                                         \
        _Pragma("unroll 1")                                                  \
        for (; t2 + 2 <= (TE); t2 += 2) {                                    \
            LOAD_STEP(t2 + 1, kfb, qfb, vtb, decb, bttb);                    \
            DO_STEP(t2, kfa, qfa, vta, deca, btta);                          \
            if (t2 + 2 < (TE))                                               \
                LOAD_STEP(t2 + 2, kfa, qfa, vta, deca, btta);                \
            DO_STEP(t2 + 1, kfb, qfb, vtb, decb, bttb);                      \
        }                                                                    \
        if (t2 < (TE))                                                       \
            DO_STEP(t2, kfa, qfa, vta, deca, btta);                          \
    }

__global__ __launch_bounds__(512)
void scan_fused(const float* __restrict__ qk, float* __restrict__ vbuf,
                const float* __restrict__ qcw, const float* __restrict__ kcw, const float* __restrict__ vcw,
                const float* __restrict__ g, const float* __restrict__ beta) {
    int blk = blockIdx.x;
    int vh  = blk & 1;
    int bh  = blk >> 1;
    int b   = bh >> 4;
    int h   = bh & 15;
    int tid = threadIdx.x;

    __shared__ __align__(16) float rawq[2][(CT_ + 3) * 64];
    __shared__ __align__(16) float rawk[2][(CT_ + 3) * 64];
    __shared__ __align__(16) float rawv[2][(CT_ + 3) * 64];
    __shared__ __align__(16) float sq[2][CT_ * 68];
    __shared__ __align__(16) float sk[2][CT_ * 68];
    __shared__ __align__(16) float sv[2][CT_ * 68];
    __shared__ float sg[2][CT_];
    __shared__ float sb[2][CT_];

    const size_t qbase = (size_t)b * T_ * 2048 + h * 64;
    const size_t kbase = qbase + 1024;
    const size_t vbase = (size_t)b * T_ * 2048 + h * 128 + vh * 64;
    const size_t gbase = (size_t)b * T_ * H_ + h;

    const bool is_cons = (tid < 256);

    const int ptid = tid - 256;
    const int pc   = ptid & 63;
    const int pw   = ptid >> 6;
    float wqa[4], wka[4], wva[4];
    if (!is_cons) {
        float4 a4 = *(const float4*)(qcw + (size_t)(h * 64 + pc) * 4);
        float4 b4 = *(const float4*)(kcw + (size_t)(h * 64 + pc) * 4);
        float4 c4 = *(const float4*)(vcw + (size_t)(h * 128 + vh * 64 + pc) * 4);
        wqa[0]=a4.x; wqa[1]=a4.y; wqa[2]=a4.z; wqa[3]=a4.w;
        wka[0]=b4.x; wka[1]=b4.y; wka[2]=b4.z; wka[3]=b4.w;
        wva[0]=c4.x; wva[1]=c4.y; wva[2]=c4.z; wva[3]=c4.w;
        if (ptid < 192) {
            int bsel = ptid >> 6, c = ptid & 63;
            float* rb = bsel == 0 ? rawq[1] : (bsel == 1 ? rawk[1] : rawv[1]);
#pragma unroll
            for (int j = 0; j < 3; j++) rb[(CT_ + j) * 64 + c] = 0.f;
        }
    }

    auto prod_phase1 = [&](int ci) {
        int rp = ci & 1;
        int tcc = ci * CT_;
        float* rq = rawq[rp]; float* rk = rawk[rp]; float* rv = rawv[rp];
        const float* pq = rawq[rp ^ 1]; const float* pk = rawk[rp ^ 1]; const float* pv = rawv[rp ^ 1];
        if (ptid < 192) {
            int bsel = ptid >> 6, c = ptid & 63;
            float*       db = bsel == 0 ? rq : (bsel == 1 ? rk : rv);
            const float* sc = bsel == 0 ? pq : (bsel == 1 ? pk : pv);
#pragma unroll
            for (int j = 0; j < 3; j++) db[j * 64 + c] = sc[(CT_ + j) * 64 + c];
        }
#pragma unroll
        for (int u = 0; u < 2; u++) {
            int idx = u * 256 + ptid;
            int r   = idx >> 4;
            int c4  = (idx & 15) * 4;
            size_t row = (size_t)(tcc + r) * 2048;
            *(float4*)(rq + (3 + r) * 64 + c4) = *(const float4*)(qk + qbase + row + c4);
            *(float4*)(rk + (3 + r) * 64 + c4) = *(const float4*)(qk + kbase + row + c4);
            *(float4*)(rv + (3 + r) * 64 + c4) = *(const float4*)(vbuf + vbase + row + c4);
        }
        if (ptid < CT_)          sg[rp][ptid]       = expf(g[gbase + (size_t)(tcc + ptid) * H_]);
        else if (ptid < 2 * CT_) sb[rp][ptid - CT_] = beta[gbase + (size_t)(tcc + ptid - CT_) * H_];
    };

    auto prod_phase2 = [&](int ci) {
        int rp = ci & 1;
        const float* rq = rawq[rp]; const float* rk = rawk[rp]; const float* rv = rawv[rp];
        float* dq = sq[rp]; float* dk = sk[rp]; float* dv = sv[rp];
#pragma unroll
        for (int it = 0; it < 8; it++) {
            int r = pw + it * 4;
            float aq = 0.f, ak = 0.f, av = 0.f;
#pragma unroll
            for (int j = 0; j < 4; j++) {
                aq += wqa[j] * rq[(r + j) * 64 + pc];
                ak += wka[j] * rk[(r + j) * 64 + pc];
                av += wva[j] * rv[(r + j) * 64 + pc];
            }
            dq[r * 68 + pc] = siluf(aq);
            dk[r * 68 + pc] = siluf(ak);
            dv[r * 68 + pc] = siluf(av);
        }
    };

    auto prod_phase3 = [&](int ci) {
        int rp = ci & 1;
        int r = ptid >> 3;
        int j = ptid & 7;
        float* kr = sk[rp] + r * 68 + j * 8;
        float* qr = sq[rp] + r * 68 + j * 8;
        float4 k0 = ((const float4*)kr)[0], k1 = ((const float4*)kr)[1];
        float4 q0 = ((const float4*)qr)[0], q1 = ((const float4*)qr)[1];
        float ssk = k0.x*k0.x + k0.y*k0.y + k0.z*k0.z + k0.w*k0.w
                  + k1.x*k1.x + k1.y*k1.y + k1.z*k1.z + k1.w*k1.w;
        float ssq = q0.x*q0.x + q0.y*q0.y + q0.z*q0.z + q0.w*q0.w
                  + q1.x*q1.x + q1.y*q1.y + q1.z*q1.z + q1.w*q1.w;
        ssk += __shfl_xor(ssk, 1); ssk += __shfl_xor(ssk, 2); ssk += __shfl_xor(ssk, 4);
        ssq += __shfl_xor(ssq, 1); ssq += __shfl_xor(ssq, 2); ssq += __shfl_xor(ssq, 4);
        float rk_ = rsqrtf(ssk + 1e-6f);
        float rq_ = rsqrtf(ssq + 1e-6f) * 0.125f;   // fold SCALE = DK^-0.5
        k0.x*=rk_; k0.y*=rk_; k0.z*=rk_; k0.w*=rk_;
        k1.x*=rk_; k1.y*=rk_; k1.z*=rk_; k1.w*=rk_;
        q0.x*=rq_; q0.y*=rq_; q0.z*=rq_; q0.w*=rq_;
        q1.x*=rq_; q1.y*=rq_; q1.z*=rq_; q1.w*=rq_;
        ((float4*)kr)[0] = k0; ((float4*)kr)[1] = k1;
        ((float4*)qr)[0] = q0; ((float4*)qr)[1] = q1;
    };

    const int dkq = tid & 3;
    const int dvl = tid >> 2;
    const int dk0 = dkq * 16;
    float S[16];
#pragma unroll
    for (int i = 0; i < 16; i++) S[i] = 0.f;

    if (!is_cons) prod_phase1(0);
    __syncthreads();
    if (!is_cons) prod_phase2(0);
    __syncthreads();
    if (!is_cons) prod_phase3(0);
    __syncthreads();

    for (int ci = 0; ci < NCH_; ci++) {
        const int p  = ci & 1;
        const int tc = ci * CT_;
        const float* sqp  = sq[p];
        const float* skp  = sk[p];
        const float* svp  = sv[p];
        const float* sgp_ = sg[p];
        const float* sbp_ = sb[p];

        if (is_cons) { CONSUME_GROUP(0, 11); }
        else if (ci + 1 < NCH_) prod_phase1(ci + 1);
        __syncthreads();
        if (is_cons) { CONSUME_GROUP(11, 22); }
        else if (ci + 1 < NCH_) prod_phase2(ci + 1);
        __syncthreads();
        if (is_cons) { CONSUME_GROUP(22, 32); }
        else if (ci + 1 < NCH_) prod_phase3(ci + 1);
        __syncthreads();
    }
}

// ---------------------------------------------------------------- postnorm: rms(o)*silu(g_out) -> og bf16
__global__ __launch_bounds__(256)
void postnorm_k(float* __restrict__ vbuf, const unsigned short* __restrict__ gout) {
    int bt  = blockIdx.x;
    int tid = threadIdx.x;
    const float* orow = vbuf + (size_t)bt * 2048 + tid * 8;
    float4 a = ((const float4*)orow)[0];
    float4 c = ((const float4*)orow)[1];
    float ss = a.x*a.x + a.y*a.y + a.z*a.z + a.w*a.w
             + c.x*c.x + c.y*c.y + c.z*c.z + c.w*c.w;
    ss += __shfl_xor(ss, 1); ss += __shfl_xor(ss, 2); ss += __shfl_xor(ss, 4); ss += __shfl_xor(ss, 8);
    float rms = rsqrtf(ss * (1.f / 128.f) + 1.1920928955078125e-07f);
    const unsigned short* grow = gout + (size_t)bt * 2048 + tid * 8;
    ushort4 g1 = ((const ushort4*)grow)[0];
    ushort4 g2 = ((const ushort4*)grow)[1];
    ushort4 r0, r1;
    r0.x = f2bf(a.x * rms * siluf(bf2f(g1.x)));
    r0.y = f2bf(a.y * rms * siluf(bf2f(g1.y)));
    r0.z = f2bf(a.z * rms * siluf(bf2f(g1.z)));
    r0.w = f2bf(a.w * rms * siluf(bf2f(g1.w)));
    r1.x = f2bf(c.x * rms * siluf(bf2f(g2.x)));
    r1.y = f2bf(c.y * rms * siluf(bf2f(g2.y)));
    r1.z = f2bf(c.z * rms * siluf(bf2f(g2.z)));
    r1.w = f2bf(c.w * rms * siluf(bf2f(g2.w)));
    __syncthreads();   // all reads of this row done before in-place overwrite
    unsigned short* og = (unsigned short*)vbuf + (size_t)bt * 4096 + tid * 8;
    *(ushort4*)og       = r0;
    *(ushort4*)(og + 4) = r1;
}

// ---------------------------------------------------------------- launch
// CLEAN layout (needs ws >= 177 MiB):
//   [0,32)    xh      [32,64)  xl          (x pre-split bf16)
//   [64,72)   qkw_h   [72,80)  qkw_l
//   [80,96)   vgw_h (v rows then g rows)   [96,104) vgw_l (v-half)
//   [104,112) ow_bf
//   [112,176) vbuf f32 (v -> o in-place -> og bf16 stride 4096)
//   [176,177) gbuf, bbuf
// LEGACY layout (ws-tight fallback): identical to previous round (121 MiB peak).
extern "C" void kernel_launch(void* const* d_in, const int* in_sizes, int n_in,
                              void* d_out, int out_size, void* d_ws, size_t ws_size,
                              hipStream_t stream) {
    (void)in_sizes; (void)n_in; (void)out_size;
    const float* x        = (const float*)d_in[0];
    const float* qk_w     = (const float*)d_in[1];
    const float* vg_w     = (const float*)d_in[2];
    const float* o_w      = (const float*)d_in[3];
    const float* a_w      = (const float*)d_in[4];
    const float* b_w      = (const float*)d_in[5];
    const float* b_bias   = (const float*)d_in[6];
    const float* beta_b   = (const float*)d_in[7];
    const float* A_log    = (const float*)d_in[8];
    const float* dt_bias  = (const float*)d_in[9];
    const float* q_conv_w = (const float*)d_in[10];
    const float* k_conv_w = (const float*)d_in[11];
    const float* v_conv_w = (const float*)d_in[12];

    char* ws = (char*)d_ws;
    float* qkf            = (float*)d_out;                 // qk f32 (GEMM1)
    unsigned short* goutb = (unsigned short*)d_out;        // g_out bf16 (after scan)
    float* outp           = (float*)d_out;                 // final f32 output

    if (ws_size >= (size_t)177u * 1024u * 1024u) {
        // ---------------- CLEAN path: pre-split x, all GEMMs pure-bf16 gld_lds
        unsigned short* xh    = (unsigned short*)(ws);
        unsigned short* xl    = (unsigned short*)(ws + (32u << 20));
        unsigned short* qkw_h = (unsigned short*)(ws + (64u << 20));
        unsigned short* qkw_l = (unsigned short*)(ws + (72u << 20));
        unsigned short* vgw_h = (unsigned short*)(ws + (80u << 20));
        unsigned short* vgw_l = (unsigned short*)(ws + (96u << 20));
        unsigned short* ow_bf = (unsigned short*)(ws + (104u << 20));
        float*          vbuf  = (float*)(ws + (112u << 20));
        float*          gbuf  = (float*)(ws + (176u << 20));
        float*          bbuf  = (float*)(ws + (176u << 20) + (512u << 10));

        // 1) casts: x split; weights
        cast_split_k<<<(BT_ * C_ / 4 + 255) / 256, 256, 0, stream>>>(x, xh, xl, BT_ * C_ / 4);
        cast_split_k<<<(2048 * 2048 / 4 + 255) / 256, 256, 0, stream>>>(qk_w, qkw_h, qkw_l, 2048 * 2048 / 4);
        cast_split_k<<<(2048 * 2048 / 4 + 255) / 256, 256, 0, stream>>>(vg_w, vgw_h, vgw_l, 2048 * 2048 / 4);
        cast_plain_k<<<(2048 * 2048 / 4 + 255) / 256, 256, 0, stream>>>(
            vg_w + (size_t)2048 * 2048, vgw_h + (size_t)2048 * 2048, 2048 * 2048 / 4);
        cast_plain_k<<<(2048 * 2048 / 4 + 255) / 256, 256, 0, stream>>>(o_w, ow_bf, 2048 * 2048 / 4);

        // 2) split-precision GEMMs (pure bf16 staging): qk -> d_out; v -> vbuf
        gemm_bf<true, true><<<dim3(16, 64), 256, 0, stream>>>(xh, xl, 2048, qkw_h, qkw_l, qkf, BT_, 2048, 2048);
        gemm_bf<true, true><<<dim3(16, 64), 256, 0, stream>>>(xh, xl, 2048, vgw_h, vgw_l, vbuf, BT_, 2048, 2048);

        // 3) gates (exact fp32)
        gates_k<<<BT_, 256, 0, stream>>>(x, a_w, b_w, b_bias, beta_b, A_log, dt_bias, gbuf, bbuf);

        // 4) fused scan -> o f32 in-place over vbuf
        scan_fused<<<B_ * H_ * 2, 512, 0, stream>>>(qkf, vbuf, q_conv_w, k_conv_w, v_conv_w, gbuf, bbuf);

        // 5) g_out = xh @ vg_w[2048:].T hi-only -> d_out[0,32MiB)
        gemm_bf<false, false><<<dim3(16, 64), 256, 0, stream>>>(
            xh, nullptr, 2048, vgw_h + (size_t)2048 * 2048, nullptr, goutb, BT_, 2048, 2048);

        // 6) postnorm -> og bf16 in-place over vbuf (stride 4096 ushort)
        postnorm_k<<<BT_, 256, 0, stream>>>(vbuf, goutb);

        // 7) final GEMM: og @ o_w.T -> d_out f32
        gemm_bf<false, true><<<dim3(16, 64), 256, 0, stream>>>(
            (const unsigned short*)vbuf, nullptr, 4096, ow_bf, nullptr, outp, BT_, 2048, 2048);
    } else {
        // ---------------- LEGACY path (exact previous round)
        unsigned short* qkw_h = (unsigned short*)(ws);
        unsigned short* qkw_l = (unsigned short*)(ws + (8u  << 20));
        unsigned short* vgw_h = (unsigned short*)(ws + (16u << 20));
        unsigned short* vgw_l = (unsigned short*)(ws + (32u << 20));
        unsigned short* ow_bf = (unsigned short*)(ws + (48u << 20));
        float*          vbuf  = (float*)(ws + (56u << 20));
        float*          gbuf  = (float*)(ws + (120u << 20));
        float*          bbuf  = (float*)(ws + (120u << 20) + (512u << 10));

        cast_split_k<<<(2048 * 2048 / 4 + 255) / 256, 256, 0, stream>>>(qk_w, qkw_h, qkw_l, 2048 * 2048 / 4);
        cast_split_k<<<(2048 * 2048 / 4 + 255) / 256, 256, 0, stream>>>(vg_w, vgw_h, vgw_l, 2048 * 2048 / 4);
        cast_plain_k<<<(2048 * 2048 / 4 + 255) / 256, 256, 0, stream>>>(
            vg_w + (size_t)2048 * 2048, vgw_h + (size_t)2048 * 2048, 2048 * 2048 / 4);
        cast_plain_k<<<(2048 * 2048 / 4 + 255) / 256, 256, 0, stream>>>(o_w, ow_bf, 2048 * 2048 / 4);

        gemm_pc<true, true, true><<<dim3(16, 64), 512, 0, stream>>>(x, 2048, qkw_h, qkw_l, qkf, BT_, 2048, 2048);
        gemm_pc<true, true, true><<<dim3(16, 64), 512, 0, stream>>>(x, 2048, vgw_h, vgw_l, vbuf, BT_, 2048, 2048);

        gates_k<<<BT_, 256, 0, stream>>>(x, a_w, b_w, b_bias, beta_b, A_log, dt_bias, gbuf, bbuf);

        scan_fused<<<B_ * H_ * 2, 512, 0, stream>>>(qkf, vbuf, q_conv_w, k_conv_w, v_conv_w, gbuf, bbuf);

        gemm_pc<false, false, true><<<dim3(16, 64), 512, 0, stream>>>(
            x, 2048, vgw_h + (size_t)2048 * 2048, nullptr, goutb, BT_, 2048, 2048);

        postnorm_k<<<BT_, 256, 0, stream>>>(vbuf, goutb);

        gemm_pc<false, true, false><<<dim3(16, 64), 512, 0, stream>>>(
            (const void*)vbuf, 4096, ow_bf, nullptr, outp, BT_, 2048, 2048);
    }
}

// Round 5
// 1358.145 us; speedup vs baseline: 1.7172x; 1.0919x over previous
//
#include <hip/hip_runtime.h>
#include <hip/hip_bf16.h>
#include <stdint.h>

// Problem constants
#define B_ 4
#define T_ 2048
#define C_ 2048
#define H_ 16
#define DK_ 64
#define DV_ 128
#define BT_ (B_ * T_)   // 8192

typedef __attribute__((ext_vector_type(8))) __bf16 bf16x8;
typedef __attribute__((ext_vector_type(4))) float f32x4;

__device__ __forceinline__ unsigned short f2bf(float f) {
    union { float f; uint32_t u; } v; v.f = f;
    uint32_t u = v.u;
    uint32_t r = u + 0x7FFFu + ((u >> 16) & 1u);   // RNE
    return (unsigned short)(r >> 16);
}
__device__ __forceinline__ float bf2f(unsigned short h) {
    union { uint32_t u; float f; } v; v.u = ((uint32_t)h) << 16; return v.f;
}
__device__ __forceinline__ float siluf(float x) { return x / (1.f + expf(-x)); }

// DPP quad-reduce helpers: sum across the 4 lanes of a quad (lanes grouped as tid&3).
__device__ __forceinline__ float dpp_xor1_add(float x) {
    int t = __builtin_amdgcn_update_dpp(0, __float_as_int(x), 0xB1, 0xF, 0xF, true);
    return x + __int_as_float(t);
}
__device__ __forceinline__ float dpp_xor2_add(float x) {
    int t = __builtin_amdgcn_update_dpp(0, __float_as_int(x), 0x4E, 0xF, 0xF, true);
    return x + __int_as_float(t);
}

// hi = RNE bf16 of x; lo = trunc bf16 of (x - hi). x ≈ hi + lo to ~2^-17 rel.
__device__ __forceinline__ void split_hl(float x, unsigned short& h, unsigned short& l) {
    unsigned short hu = f2bf(x);
    float lo = x - bf2f(hu);
    h = hu;
    l = (unsigned short)(__float_as_uint(lo) >> 16);
}

// ---------------------------------------------------------------- casts
__global__ void cast_split_k(const float* __restrict__ in,
                             unsigned short* __restrict__ oh, unsigned short* __restrict__ ol, int n4) {
    int i = blockIdx.x * blockDim.x + threadIdx.x;
    if (i >= n4) return;
    float4 v = ((const float4*)in)[i];
    ushort4 h, l;
    split_hl(v.x, h.x, l.x); split_hl(v.y, h.y, l.y);
    split_hl(v.z, h.z, l.z); split_hl(v.w, h.w, l.w);
    ((ushort4*)oh)[i] = h;
    ((ushort4*)ol)[i] = l;
}

__global__ void cast_plain_k(const float* __restrict__ in, unsigned short* __restrict__ out, int n4) {
    int i = blockIdx.x * blockDim.x + threadIdx.x;
    if (i >= n4) return;
    float4 v = ((const float4*)in)[i];
    ushort4 o;
    o.x = f2bf(v.x); o.y = f2bf(v.y); o.z = f2bf(v.z); o.w = f2bf(v.w);
    ((ushort4*)out)[i] = o;
}

// merged cast: x split + qk_w split + vg_w(v) split + vg_w(g) plain + o_w plain, one launch
__global__ __launch_bounds__(256)
void cast_all_k(const float* __restrict__ x, const float* __restrict__ qk_w,
                const float* __restrict__ vg_w, const float* __restrict__ o_w,
                unsigned short* __restrict__ xh, unsigned short* __restrict__ xl,
                unsigned short* __restrict__ qkw_h, unsigned short* __restrict__ qkw_l,
                unsigned short* __restrict__ vgw_h, unsigned short* __restrict__ vgw_l,
                unsigned short* __restrict__ ow_bf) {
    const int NX = BT_ * C_ / 4;        // 4,194,304
    const int NW = 2048 * 2048 / 4;     // 1,048,576
    int i = blockIdx.x * blockDim.x + threadIdx.x;
    const float* src; unsigned short *dh, *dl; int j; bool split;
    if (i < NX)               { j = i;            src = x;                          dh = xh;    dl = xl;    split = true; }
    else if (i < NX + NW)     { j = i - NX;       src = qk_w;                       dh = qkw_h; dl = qkw_l; split = true; }
    else if (i < NX + 2 * NW) { j = i - NX - NW;  src = vg_w;                       dh = vgw_h; dl = vgw_l; split = true; }
    else if (i < NX + 3 * NW) { j = i - NX - 2*NW; src = vg_w + (size_t)2048*2048;  dh = vgw_h + (size_t)2048*2048; dl = nullptr; split = false; }
    else                      { j = i - NX - 3*NW; src = o_w;                       dh = ow_bf; dl = nullptr; split = false; }
    float4 v = ((const float4*)src)[j];
    ushort4 h, l;
    if (split) {
        split_hl(v.x, h.x, l.x); split_hl(v.y, h.y, l.y);
        split_hl(v.z, h.z, l.z); split_hl(v.w, h.w, l.w);
        ((ushort4*)dh)[j] = h;
        ((ushort4*)dl)[j] = l;
    } else {
        h.x = f2bf(v.x); h.y = f2bf(v.y); h.z = f2bf(v.z); h.w = f2bf(v.w);
        ((ushort4*)dh)[j] = h;
    }
}

// ---------------------------------------------------------------- async global->LDS (16B/lane)
__device__ __forceinline__ void gld_lds16(const unsigned short* gptr,
                                          unsigned short* lds_base) {
    __builtin_amdgcn_global_load_lds(
        (const __attribute__((address_space(1))) uint32_t*)(uintptr_t)gptr,
        (__attribute__((address_space(3))) uint32_t*)(uint32_t)(uintptr_t)lds_base,
        16, 0, 0);
}

// ---------------------------------------------------------------- all-bf16 GEMM (m97 structure)
template<bool DO_LO, bool F32OUT>
__global__ __launch_bounds__(256)
void gemm_bf(const unsigned short* __restrict__ Ah, const unsigned short* __restrict__ Al, int lda,
             const unsigned short* __restrict__ Wh, const unsigned short* __restrict__ Wl,
             void* __restrict__ Cout, int M, int N, int K) {
    __shared__ __align__(16) unsigned short sAh[128 * 64];
    __shared__ __align__(16) unsigned short sWh[128 * 64];
    __shared__ __align__(16) unsigned short sAl[DO_LO ? 128 * 64 : 16];
    __shared__ __align__(16) unsigned short sWl[DO_LO ? 128 * 64 : 16];
    const int tid  = threadIdx.x;
    const int wave = tid >> 6;
    const int lane = tid & 63;
    const int wm = (wave >> 1) * 64;
    const int wn = (wave & 1) * 64;
    const int bm = blockIdx.y, bn = blockIdx.x;
    const int srow = lane >> 3;
    const int scol = (lane & 7) * 8;

    const unsigned short* Agh = Ah + (size_t)(bm * 128) * lda;
    const unsigned short* Agl = DO_LO ? (Al + (size_t)(bm * 128) * lda) : nullptr;
    const unsigned short* Wgh = Wh + (size_t)(bn * 128) * K;
    const unsigned short* Wgl = DO_LO ? (Wl + (size_t)(bn * 128) * K) : nullptr;

    f32x4 acc[4][4];
#pragma unroll
    for (int i = 0; i < 4; i++)
#pragma unroll
        for (int j = 0; j < 4; j++) { acc[i][j][0]=0.f; acc[i][j][1]=0.f; acc[i][j][2]=0.f; acc[i][j][3]=0.f; }

    const int mrow = lane & 15;
    const int kq   = (lane >> 4) * 8;

    for (int k0 = 0; k0 < K; k0 += 64) {
#pragma unroll
        for (int i = 0; i < 4; i++) {
            int rbase = wave * 32 + i * 8;
            gld_lds16(Agh + (size_t)(rbase + srow) * lda + k0 + scol, sAh + rbase * 64);
            gld_lds16(Wgh + (size_t)(rbase + srow) * K   + k0 + scol, sWh + rbase * 64);
            if (DO_LO) {
                gld_lds16(Agl + (size_t)(rbase + srow) * lda + k0 + scol, sAl + rbase * 64);
                gld_lds16(Wgl + (size_t)(rbase + srow) * K   + k0 + scol, sWl + rbase * 64);
            }
        }
        __syncthreads();
#pragma unroll
        for (int kk = 0; kk < 2; kk++) {
            bf16x8 afh[4], wfh[4];
#pragma unroll
            for (int i = 0; i < 4; i++)
                afh[i] = *(const bf16x8*)(sAh + (wm + i * 16 + mrow) * 64 + kk * 32 + kq);
#pragma unroll
            for (int j = 0; j < 4; j++)
                wfh[j] = *(const bf16x8*)(sWh + (wn + j * 16 + mrow) * 64 + kk * 32 + kq);
#pragma unroll
            for (int i = 0; i < 4; i++)
#pragma unroll
                for (int j = 0; j < 4; j++)
                    acc[i][j] = __builtin_amdgcn_mfma_f32_16x16x32_bf16(afh[i], wfh[j], acc[i][j], 0, 0, 0);
            if (DO_LO) {
                bf16x8 afl[4], wfl[4];
#pragma unroll
                for (int i = 0; i < 4; i++)
                    afl[i] = *(const bf16x8*)(sAl + (wm + i * 16 + mrow) * 64 + kk * 32 + kq);
#pragma unroll
                for (int j = 0; j < 4; j++)
                    wfl[j] = *(const bf16x8*)(sWl + (wn + j * 16 + mrow) * 64 + kk * 32 + kq);
#pragma unroll
                for (int i = 0; i < 4; i++)
#pragma unroll
                    for (int j = 0; j < 4; j++) {
                        acc[i][j] = __builtin_amdgcn_mfma_f32_16x16x32_bf16(afh[i], wfl[j], acc[i][j], 0, 0, 0);
                        acc[i][j] = __builtin_amdgcn_mfma_f32_16x16x32_bf16(afl[i], wfh[j], acc[i][j], 0, 0, 0);
                    }
            }
        }
        __syncthreads();
    }
    const int r0 = (lane >> 4) * 4;
    const int cn = lane & 15;
#pragma unroll
    for (int i = 0; i < 4; i++) {
#pragma unroll
        for (int r = 0; r < 4; r++) {
            int row = bm * 128 + wm + i * 16 + r0 + r;
            size_t base = (size_t)row * N + bn * 128 + wn + cn;
            if constexpr (F32OUT) {
                float* Crow = (float*)Cout + base;
#pragma unroll
                for (int j = 0; j < 4; j++) Crow[j * 16] = acc[i][j][r];
            } else {
                unsigned short* Crow = (unsigned short*)Cout + base;
#pragma unroll
                for (int j = 0; j < 4; j++) Crow[j * 16] = f2bf(acc[i][j][r]);
            }
        }
    }
}

// ---------------------------------------------------------------- dual DO_LO GEMM: qk + v in one dispatch (shared A)
__global__ __launch_bounds__(256)
void gemm_dual(const unsigned short* __restrict__ Ah, const unsigned short* __restrict__ Al,
               const unsigned short* __restrict__ Wh0, const unsigned short* __restrict__ Wl0, float* __restrict__ C0,
               const unsigned short* __restrict__ Wh1, const unsigned short* __restrict__ Wl1, float* __restrict__ C1) {
    __shared__ __align__(16) unsigned short sAh[128 * 64];
    __shared__ __align__(16) unsigned short sWh[128 * 64];
    __shared__ __align__(16) unsigned short sAl[128 * 64];
    __shared__ __align__(16) unsigned short sWl[128 * 64];
    const int K = 2048, N = 2048, lda = 2048;
    const int tid  = threadIdx.x;
    const int wave = tid >> 6;
    const int lane = tid & 63;
    const int wm = (wave >> 1) * 64;
    const int wn = (wave & 1) * 64;
    const int bm = blockIdx.y;
    const int bnx = blockIdx.x;           // 0..31
    const unsigned short* Wh = (bnx < 16) ? Wh0 : Wh1;
    const unsigned short* Wl = (bnx < 16) ? Wl0 : Wl1;
    float* Csel              = (bnx < 16) ? C0  : C1;
    const int bn = bnx & 15;
    const int srow = lane >> 3;
    const int scol = (lane & 7) * 8;

    const unsigned short* Agh = Ah + (size_t)(bm * 128) * lda;
    const unsigned short* Agl = Al + (size_t)(bm * 128) * lda;
    const unsigned short* Wgh = Wh + (size_t)(bn * 128) * K;
    const unsigned short* Wgl = Wl + (size_t)(bn * 128) * K;

    f32x4 acc[4][4];
#pragma unroll
    for (int i = 0; i < 4; i++)
#pragma unroll
        for (int j = 0; j < 4; j++) { acc[i][j][0]=0.f; acc[i][j][1]=0.f; acc[i][j][2]=0.f; acc[i][j][3]=0.f; }

    const int mrow = lane & 15;
    const int kq   = (lane >> 4) * 8;

    for (int k0 = 0; k0 < K; k0 += 64) {
#pragma unroll
        for (int i = 0; i < 4; i++) {
            int rbase = wave * 32 + i * 8;
            gld_lds16(Agh + (size_t)(rbase + srow) * lda + k0 + scol, sAh + rbase * 64);
            gld_lds16(Wgh + (size_t)(rbase + srow) * K   + k0 + scol, sWh + rbase * 64);
            gld_lds16(Agl + (size_t)(rbase + srow) * lda + k0 + scol, sAl + rbase * 64);
            gld_lds16(Wgl + (size_t)(rbase + srow) * K   + k0 + scol, sWl + rbase * 64);
        }
        __syncthreads();
#pragma unroll
        for (int kk = 0; kk < 2; kk++) {
            bf16x8 afh[4], wfh[4];
#pragma unroll
            for (int i = 0; i < 4; i++)
                afh[i] = *(const bf16x8*)(sAh + (wm + i * 16 + mrow) * 64 + kk * 32 + kq);
#pragma unroll
            for (int j = 0; j < 4; j++)
                wfh[j] = *(const bf16x8*)(sWh + (wn + j * 16 + mrow) * 64 + kk * 32 + kq);
#pragma unroll
            for (int i = 0; i < 4; i++)
#pragma unroll
                for (int j = 0; j < 4; j++)
                    acc[i][j] = __builtin_amdgcn_mfma_f32_16x16x32_bf16(afh[i], wfh[j], acc[i][j], 0, 0, 0);
            bf16x8 afl[4], wfl[4];
#pragma unroll
            for (int i = 0; i < 4; i++)
                afl[i] = *(const bf16x8*)(sAl + (wm + i * 16 + mrow) * 64 + kk * 32 + kq);
#pragma unroll
            for (int j = 0; j < 4; j++)
                wfl[j] = *(const bf16x8*)(sWl + (wn + j * 16 + mrow) * 64 + kk * 32 + kq);
#pragma unroll
            for (int i = 0; i < 4; i++)
#pragma unroll
                for (int j = 0; j < 4; j++) {
                    acc[i][j] = __builtin_amdgcn_mfma_f32_16x16x32_bf16(afh[i], wfl[j], acc[i][j], 0, 0, 0);
                    acc[i][j] = __builtin_amdgcn_mfma_f32_16x16x32_bf16(afl[i], wfh[j], acc[i][j], 0, 0, 0);
                }
        }
        __syncthreads();
    }
    const int r0 = (lane >> 4) * 4;
    const int cn = lane & 15;
#pragma unroll
    for (int i = 0; i < 4; i++) {
#pragma unroll
        for (int r = 0; r < 4; r++) {
            int row = bm * 128 + wm + i * 16 + r0 + r;
            float* Crow = Csel + (size_t)row * N + bn * 128 + wn + cn;
#pragma unroll
            for (int j = 0; j < 4; j++) Crow[j * 16] = acc[i][j][r];
        }
    }
}

// ---------------------------------------------------------------- legacy producer/consumer GEMM (ws-tight fallback)
template<bool DO_LO, bool F32OUT, bool A_F32>
__global__ __launch_bounds__(512, 2)
void gemm_pc(const void* __restrict__ Aptr, int lda,
             const unsigned short* __restrict__ Wh, const unsigned short* __restrict__ Wl,
             void* __restrict__ Cout, int M, int N, int K) {
    __shared__ __align__(16) unsigned short sAh[2][128 * 64];
    __shared__ __align__(16) unsigned short sWh[2][128 * 64];
    __shared__ __align__(16) unsigned short sAl[DO_LO ? 2 : 1][DO_LO ? 128 * 64 : 16];
    __shared__ __align__(16) unsigned short sWl[DO_LO ? 2 : 1][DO_LO ? 128 * 64 : 16];

    const int tid  = threadIdx.x;
    const bool is_cons = (tid < 256);
    const int bm = blockIdx.y, bn = blockIdx.x;
    const int NK = K >> 6;

    const int ptid  = tid - 256;
    const int pw    = ptid >> 6;
    const int plane = ptid & 63;
    const int wrow  = plane >> 3;
    const int wcol  = (plane & 7) * 8;

    const float*          Agf = (const float*)Aptr + (size_t)(bm * 128) * lda;
    const unsigned short* Agb = (const unsigned short*)Aptr + (size_t)(bm * 128) * lda;
    const unsigned short* Whg = Wh + (size_t)(bn * 128) * K;
    const unsigned short* Wlg = DO_LO ? (Wl + (size_t)(bn * 128) * K) : nullptr;

    auto stage = [&](int p, int k0) {
#pragma unroll
        for (int i = 0; i < 4; i++) {
            int rbase = pw * 32 + i * 8;
            gld_lds16(Whg + (size_t)(rbase + wrow) * K + k0 + wcol, sWh[p] + rbase * 64);
            if (DO_LO)
                gld_lds16(Wlg + (size_t)(rbase + wrow) * K + k0 + wcol, sWl[p] + rbase * 64);
            if (!A_F32)
                gld_lds16(Agb + (size_t)(rbase + wrow) * lda + k0 + wcol, sAh[p] + rbase * 64);
        }
        if (A_F32) {
#pragma unroll
            for (int it = 0; it < 8; it++) {
                int idx = it * 256 + ptid;
                int r   = idx >> 4;
                int c4  = (idx & 15) * 4;
                float4 v = *(const float4*)(Agf + (size_t)r * lda + k0 + c4);
                ushort4 h, l;
                split_hl(v.x, h.x, l.x); split_hl(v.y, h.y, l.y);
                split_hl(v.z, h.z, l.z); split_hl(v.w, h.w, l.w);
                *(ushort4*)(sAh[p] + r * 64 + c4) = h;
                if (DO_LO) *(ushort4*)(sAl[p] + r * 64 + c4) = l;
            }
        }
    };

    const int wave = tid >> 6;
    const int lane = tid & 63;
    const int wm = (wave >> 1) * 64;
    const int wn = (wave & 1) * 64;
    const int mrow = lane & 15;
    const int kq   = (lane >> 4) * 8;

    f32x4 acc[4][4];
#pragma unroll
    for (int i = 0; i < 4; i++)
#pragma unroll
        for (int j = 0; j < 4; j++) { acc[i][j][0]=0.f; acc[i][j][1]=0.f; acc[i][j][2]=0.f; acc[i][j][3]=0.f; }

    if (!is_cons) stage(0, 0);
    __syncthreads();

    for (int ks = 0; ks < NK; ks++) {
        const int p = ks & 1;
        if (is_cons) {
            const unsigned short* pAh = sAh[p];
            const unsigned short* pWh = sWh[p];
            const unsigned short* pAl = sAl[DO_LO ? p : 0];
            const unsigned short* pWl = sWl[DO_LO ? p : 0];
#pragma unroll
            for (int kk = 0; kk < 2; kk++) {
                bf16x8 afh[4], wfh[4];
#pragma unroll
                for (int i = 0; i < 4; i++)
                    afh[i] = *(const bf16x8*)(pAh + (wm + i * 16 + mrow) * 64 + kk * 32 + kq);
#pragma unroll
                for (int j = 0; j < 4; j++)
                    wfh[j] = *(const bf16x8*)(pWh + (wn + j * 16 + mrow) * 64 + kk * 32 + kq);
#pragma unroll
                for (int i = 0; i < 4; i++)
#pragma unroll
                    for (int j = 0; j < 4; j++)
                        acc[i][j] = __builtin_amdgcn_mfma_f32_16x16x32_bf16(afh[i], wfh[j], acc[i][j], 0, 0, 0);
                if (DO_LO) {
                    bf16x8 afl[4], wfl[4];
#pragma unroll
                    for (int i = 0; i < 4; i++)
                        afl[i] = *(const bf16x8*)(pAl + (wm + i * 16 + mrow) * 64 + kk * 32 + kq);
#pragma unroll
                    for (int j = 0; j < 4; j++)
                        wfl[j] = *(const bf16x8*)(pWl + (wn + j * 16 + mrow) * 64 + kk * 32 + kq);
#pragma unroll
                    for (int i = 0; i < 4; i++)
#pragma unroll
                        for (int j = 0; j < 4; j++) {
                            acc[i][j] = __builtin_amdgcn_mfma_f32_16x16x32_bf16(afh[i], wfl[j], acc[i][j], 0, 0, 0);
                            acc[i][j] = __builtin_amdgcn_mfma_f32_16x16x32_bf16(afl[i], wfh[j], acc[i][j], 0, 0, 0);
                        }
                }
            }
        } else if (ks + 1 < NK) {
            stage(p ^ 1, (ks + 1) * 64);
        }
        __syncthreads();
    }

    if (is_cons) {
        const int r0 = (lane >> 4) * 4;
        const int cn = lane & 15;
#pragma unroll
        for (int i = 0; i < 4; i++) {
#pragma unroll
            for (int r = 0; r < 4; r++) {
                int row = bm * 128 + wm + i * 16 + r0 + r;
                size_t base = (size_t)row * N + bn * 128 + wn + cn;
                if constexpr (F32OUT) {
                    float* Crow = (float*)Cout + base;
#pragma unroll
                    for (int j = 0; j < 4; j++) Crow[j * 16] = acc[i][j][r];
                } else {
                    unsigned short* Crow = (unsigned short*)Cout + base;
#pragma unroll
                    for (int j = 0; j < 4; j++) Crow[j * 16] = f2bf(acc[i][j][r]);
                }
            }
        }
    }
}

// ---------------------------------------------------------------- per-head gates (exact fp32)
__device__ __forceinline__ float softplusf(float x) {
    return (x > 20.f) ? x : log1pf(expf(x));
}

__global__ __launch_bounds__(256)
void gates_k(const float* __restrict__ x, const float* __restrict__ a_w, const float* __restrict__ b_w,
             const float* __restrict__ b_bias, const float* __restrict__ beta_bias,
             const float* __restrict__ A_log, const float* __restrict__ dt_bias,
             float* __restrict__ g, float* __restrict__ beta) {
    int bt = blockIdx.x;
    int wave = threadIdx.x >> 6, lane = threadIdx.x & 63;
    const float* xr = x + (size_t)bt * C_;
#pragma unroll
    for (int dd = 0; dd < 8; dd++) {
        int d = wave * 8 + dd;
        int h = d & 15;
        const float* wr = (d < 16 ? a_w : b_w) + (size_t)h * C_;
        float acc = 0.f;
#pragma unroll
        for (int it = 0; it < 8; it++) {
            float4 xv = ((const float4*)xr)[lane + it * 64];
            float4 wv = ((const float4*)wr)[lane + it * 64];
            acc += xv.x * wv.x + xv.y * wv.y + xv.z * wv.z + xv.w * wv.w;
        }
        acc += __shfl_xor(acc, 1);  acc += __shfl_xor(acc, 2);  acc += __shfl_xor(acc, 4);
        acc += __shfl_xor(acc, 8);  acc += __shfl_xor(acc, 16); acc += __shfl_xor(acc, 32);
        if (lane == 0) {
            if (d < 16) {
                g[(size_t)bt * H_ + h] = -expf(A_log[h]) * softplusf(acc + dt_bias[h]);
            } else {
                float s = 1.f / (1.f + expf(-(acc + b_bias[h] + beta_bias[h])));
                beta[(size_t)bt * H_ + h] = 2.f * s;
            }
        }
    }
}

// ---------------------------------------------------------------- scan step machinery (shared)
#define CT_ 32
#define NCH_ (T_ / CT_)

#define LOAD_STEP(t2, kf, qf, vt, dec, btt)                                  \
    {                                                                        \
        _Pragma("unroll")                                                    \
        for (int u = 0; u < 4; u++) {                                        \
            float4 k4 = ((const float4*)(skp + (t2) * 68 + dk0))[u];         \
            float4 q4 = ((const float4*)(sqp + (t2) * 68 + dk0))[u];         \
            kf[u*4+0]=k4.x; kf[u*4+1]=k4.y; kf[u*4+2]=k4.z; kf[u*4+3]=k4.w;  \
            qf[u*4+0]=q4.x; qf[u*4+1]=q4.y; qf[u*4+2]=q4.z; qf[u*4+3]=q4.w;  \
        }                                                                    \
        vt  = svp[(t2) * 68 + dvl];                                          \
        dec = sgp_[(t2)];                                                    \
        btt = sbp_[(t2)];                                                    \
    }

#define DO_STEP(t2, kf, qf, vt, dec, btt)                                    \
    {                                                                        \
        float m0=0.f, m1=0.f, m2=0.f, m3=0.f;                                \
        _Pragma("unroll")                                                    \
        for (int u = 0; u < 4; u++) {                                        \
            m0 += kf[u*4+0]*S[u*4+0]; m1 += kf[u*4+1]*S[u*4+1];              \
            m2 += kf[u*4+2]*S[u*4+2]; m3 += kf[u*4+3]*S[u*4+3];              \
        }                                                                    \
        float m = (m0 + m1) + (m2 + m3);                                     \
        m = dpp_xor1_add(m);                                                 \
        m = dpp_xor2_add(m);                                                 \
        _Pragma("unroll")                                                    \
        for (int i = 0; i < 16; i++) S[i] *= dec;                            \
        float delta = (vt - m * dec) * btt;                                  \
        float o0=0.f, o1=0.f, o2=0.f, o3=0.f;                                \
        _Pragma("unroll")                                                    \
        for (int u = 0; u < 4; u++) {                                        \
            S[u*4+0] += kf[u*4+0]*delta; o0 += qf[u*4+0]*S[u*4+0];           \
            S[u*4+1] += kf[u*4+1]*delta; o1 += qf[u*4+1]*S[u*4+1];           \
            S[u*4+2] += kf[u*4+2]*delta; o2 += qf[u*4+2]*S[u*4+2];           \
            S[u*4+3] += kf[u*4+3]*delta; o3 += qf[u*4+3]*S[u*4+3];           \
        }                                                                    \
        float ov = (o0 + o1) + (o2 + o3);                                    \
        ov = dpp_xor1_add(ov);                                               \
        ov = dpp_xor2_add(ov);                                               \
        if (dkq == 0)                                                        \
            vbuf[vbase + (size_t)(tc + (t2)) * 2048 + dvl] = ov;             \
    }

#define CONSUME_GROUP(TB, TE)                                                \
    {                                                                        \
        float kfa[16], qfa[16], kfb[16], qfb[16];                            \
        float vta, deca, btta, vtb, decb, bttb;                              \
        LOAD_STEP(TB, kfa, qfa, vta, deca, btta);                            \
        int t2 = TB;                                                         \
        _Pragma("unroll 1")                                                  \
        for (; t2 + 2 <= (TE); t2 += 2) {                                    \
            LOAD_STEP(t2 + 1, kfb, qfb, vtb, decb, bttb);                    \
            DO_STEP(t2, kfa, qfa, vta, deca, btta);                          \
            if (t2 + 2 < (TE))                                               \
                LOAD_STEP(t2 + 2, kfa, qfa, vta, deca, btta);                \
            DO_STEP(t2 + 1, kfb, qfb, vtb, decb, bttb);                      \
        }                                                                    \
        if (t2 < (TE))                                                       \
            DO_STEP(t2, kfa, qfa, vta, deca, btta);                          \
    }

// ---------------------------------------------------------------- FUSED scan + g_out GEMM (clean path)
// Blocks 0..127: scan (b,h,vh). Producer waves 4-7 conv directly from GLOBAL (qkf read-only;
// v needs a 3-row LDS carry captured before consumer overwrite), same-wave conv->l2norm,
// ONE barrier/chunk, LDS 53 KB (dynamic). Consumer waves 0-3: delta-rule, math UNCHANGED
// (bitwise-identical o). Blocks 128..1151: g_out GEMM tiles (hi-only, bf16 out over xl),
// hidden under the scan.
__global__ __launch_bounds__(512, 4)
void scan_gemm_k(const float* __restrict__ qk, float* __restrict__ vbuf,
                 const float* __restrict__ qcw, const float* __restrict__ kcw, const float* __restrict__ vcw,
                 const float* __restrict__ g, const float* __restrict__ beta,
                 const unsigned short* __restrict__ xh, const unsigned short* __restrict__ gwh,
                 unsigned short* __restrict__ gout) {
    extern __shared__ char smem_raw[];
    const int blk = blockIdx.x;
    const int tid = threadIdx.x;

    if (blk >= 128) {
        // ---------------- g_out GEMM tile: waves 0-3 active, 4-7 idle (barriers kept aligned)
        const int bid = blk - 128;
        const int bm = bid >> 4;
        const int bn = bid & 15;
        unsigned short* sA = (unsigned short*)smem_raw;
        unsigned short* sB = sA + 128 * 64;
        const bool act = tid < 256;
        const int wave = tid >> 6;
        const int lane = tid & 63;
        const int wm = (wave >> 1) * 64;
        const int wn = (wave & 1) * 64;
        const int srow = lane >> 3;
        const int scol = (lane & 7) * 8;
        const int mrow = lane & 15;
        const int kq   = (lane >> 4) * 8;
        const unsigned short* Ag = xh  + (size_t)(bm * 128) * 2048;
        const unsigned short* Wg = gwh + (size_t)(bn * 128) * 2048;
        f32x4 acc[4][4];
#pragma unroll
        for (int i = 0; i < 4; i++)
#pragma unroll
            for (int j = 0; j < 4; j++) { acc[i][j][0]=0.f; acc[i][j][1]=0.f; acc[i][j][2]=0.f; acc[i][j][3]=0.f; }
        for (int k0 = 0; k0 < 2048; k0 += 64) {
            if (act) {
#pragma unroll
                for (int i = 0; i < 4; i++) {
                    int rbase = wave * 32 + i * 8;
                    gld_lds16(Ag + (size_t)(rbase + srow) * 2048 + k0 + scol, sA + rbase * 64);
                    gld_lds16(Wg + (size_t)(rbase + srow) * 2048 + k0 + scol, sB + rbase * 64);
                }
            }
            __syncthreads();
            if (act) {
#pragma unroll
                for (int kk = 0; kk < 2; kk++) {
                    bf16x8 af[4], bfr[4];
#pragma unroll
                    for (int i = 0; i < 4; i++)
                        af[i] = *(const bf16x8*)(sA + (wm + i * 16 + mrow) * 64 + kk * 32 + kq);
#pragma unroll
                    for (int j = 0; j < 4; j++)
                        bfr[j] = *(const bf16x8*)(sB + (wn + j * 16 + mrow) * 64 + kk * 32 + kq);
#pragma unroll
                    for (int i = 0; i < 4; i++)
#pragma unroll
                        for (int j = 0; j < 4; j++)
                            acc[i][j] = __builtin_amdgcn_mfma_f32_16x16x32_bf16(af[i], bfr[j], acc[i][j], 0, 0, 0);
                }
            }
            __syncthreads();
        }
        if (act) {
            const int r0 = (lane >> 4) * 4;
            const int cn = lane & 15;
#pragma unroll
            for (int i = 0; i < 4; i++) {
#pragma unroll
                for (int r = 0; r < 4; r++) {
                    int row = bm * 128 + wm + i * 16 + r0 + r;
                    unsigned short* Crow = gout + (size_t)row * 2048 + bn * 128 + wn + cn;
#pragma unroll
                    for (int j = 0; j < 4; j++) Crow[j * 16] = f2bf(acc[i][j][r]);
                }
            }
        }
        return;
    }

    // ---------------- scan block
    const int vh  = blk & 1;
    const int bh  = blk >> 1;
    const int b   = bh >> 4;
    const int h   = bh & 15;

    float* sqb  = (float*)smem_raw;                 // [2][CT_*68]
    float* skb  = sqb + 2 * CT_ * 68;
    float* svb  = skb + 2 * CT_ * 68;
    float* sgb  = svb + 2 * CT_ * 68;               // [2][CT_]
    float* sbb  = sgb + 2 * CT_;
    float* vcar = sbb + 2 * CT_;                    // [2][3*64]

    const size_t qbase = (size_t)b * T_ * 2048 + h * 64;
    const size_t kbase = qbase + 1024;
    const size_t vbase = (size_t)b * T_ * 2048 + h * 128 + vh * 64;
    const size_t gbase = (size_t)b * T_ * H_ + h;

    const bool is_cons = (tid < 256);

    // producer locals (waves 4-7): wave pw owns chunk rows 8*pw..8*pw+7, column pc
    const int ptid = tid - 256;
    const int pc   = ptid & 63;
    const int pw   = ptid >> 6;
    const int R0   = pw * 8;
    float wqa[4], wka[4], wva[4];
    if (!is_cons) {
        float4 a4 = *(const float4*)(qcw + (size_t)(h * 64 + pc) * 4);
        float4 b4 = *(const float4*)(kcw + (size_t)(h * 64 + pc) * 4);
        float4 c4 = *(const float4*)(vcw + (size_t)(h * 128 + vh * 64 + pc) * 4);
        wqa[0]=a4.x; wqa[1]=a4.y; wqa[2]=a4.z; wqa[3]=a4.w;
        wka[0]=b4.x; wka[1]=b4.y; wka[2]=b4.z; wka[3]=b4.w;
        wva[0]=c4.x; wva[1]=c4.y; wva[2]=c4.z; wva[3]=c4.w;
    }

    // stage chunk ci into buffer ci&1 (producer only). Conv inputs come straight from
    // global; v rows tc-3..tc-1 come from vcar (captured fresh last chunk, pre-overwrite).
    auto stage = [&](int ci) {
        const int rp  = ci & 1;
        const int tcc = ci * CT_;
        float* dq = sqb + rp * (CT_ * 68);
        float* dk = skb + rp * (CT_ * 68);
        float* dv = svb + rp * (CT_ * 68);
        float qin[11], kin[11], vin[11];
#pragma unroll
        for (int j = 0; j < 11; j++) {
            int rr = tcc + R0 - 3 + j;
            bool ok = (rr >= 0);
            qin[j] = ok ? qk[qbase + (size_t)rr * 2048 + pc] : 0.f;
            kin[j] = ok ? qk[kbase + (size_t)rr * 2048 + pc] : 0.f;
        }
        if (pw == 0) {
#pragma unroll
            for (int j = 0; j < 3; j++) vin[j] = vcar[(rp ^ 1) * 192 + j * 64 + pc];
#pragma unroll
            for (int j = 3; j < 11; j++) vin[j] = vbuf[vbase + (size_t)(tcc + j - 3) * 2048 + pc];
        } else {
#pragma unroll
            for (int j = 0; j < 11; j++) vin[j] = vbuf[vbase + (size_t)(tcc + R0 - 3 + j) * 2048 + pc];
        }
        if (pw == 3) {   // capture fresh v rows 29..31 for next chunk's causal window
#pragma unroll
            for (int j = 0; j < 3; j++) vcar[rp * 192 + j * 64 + pc] = vin[8 + j];
        }
#pragma unroll
        for (int it = 0; it < 8; it++) {
            const int r = R0 + it;
            float aq = 0.f, ak = 0.f, av = 0.f;
#pragma unroll
            for (int j = 0; j < 4; j++) {
                aq += wqa[j] * qin[it + j];
                ak += wka[j] * kin[it + j];
                av += wva[j] * vin[it + j];
            }
            dq[r * 68 + pc] = siluf(aq);
            dk[r * 68 + pc] = siluf(ak);
            dv[r * 68 + pc] = siluf(av);
        }
        if (ptid < CT_)          sgb[rp * CT_ + ptid]       = expf(g[gbase + (size_t)(tcc + ptid) * H_]);
        else if (ptid < 2 * CT_) sbb[rp * CT_ + ptid - CT_] = beta[gbase + (size_t)(tcc + ptid - CT_) * H_];
        // l2norm: same wave's rows (R0 + pc>>3), col-chunk pc&7 — wave-internal LDS ordering
        {
            const int rl = R0 + (pc >> 3);
            const int jc = pc & 7;
            float* kr = dk + rl * 68 + jc * 8;
            float* qr = dq + rl * 68 + jc * 8;
            float4 k0 = ((const float4*)kr)[0], k1 = ((const float4*)kr)[1];
            float4 q0 = ((const float4*)qr)[0], q1 = ((const float4*)qr)[1];
            float ssk = k0.x*k0.x + k0.y*k0.y + k0.z*k0.z + k0.w*k0.w
                      + k1.x*k1.x + k1.y*k1.y + k1.z*k1.z + k1.w*k1.w;
            float ssq = q0.x*q0.x + q0.y*q0.y + q0.z*q0.z + q0.w*q0.w
                      + q1.x*q1.x + q1.y*q1.y + q1.z*q1.z + q1.w*q1.w;
            ssk += __shfl_xor(ssk, 1); ssk += __shfl_xor(ssk, 2); ssk += __shfl_xor(ssk, 4);
            ssq += __shfl_xor(ssq, 1); ssq += __shfl_xor(ssq, 2); ssq += __shfl_xor(ssq, 4);
            float rk_ = rsqrtf(ssk + 1e-6f);
            float rq_ = rsqrtf(ssq + 1e-6f) * 0.125f;   // fold SCALE = DK^-0.5
            k0.x*=rk_; k0.y*=rk_; k0.z*=rk_; k0.w*=rk_;
            k1.x*=rk_; k1.y*=rk_; k1.z*=rk_; k1.w*=rk_;
            q0.x*=rq_; q0.y*=rq_; q0.z*=rq_; q0.w*=rq_;
            q1.x*=rq_; q1.y*=rq_; q1.z*=rq_; q1.w*=rq_;
            ((float4*)kr)[0] = k0; ((float4*)kr)[1] = k1;
            ((float4*)qr)[0] = q0; ((float4*)qr)[1] = q1;
        }
    };

    // consumer locals (waves 0-3) — UNCHANGED math
    const int dkq = tid & 3;
    const int dvl = tid >> 2;
    const int dk0 = dkq * 16;
    float S[16];
#pragma unroll
    for (int i = 0; i < 16; i++) S[i] = 0.f;

    if (!is_cons) {
        if (pw == 0) {   // zero the carry buffer chunk 0 reads (same-wave: no barrier needed)
#pragma unroll
            for (int j = 0; j < 3; j++) vcar[192 + j * 64 + pc] = 0.f;
        }
        stage(0);
    }
    __syncthreads();

    for (int ci = 0; ci < NCH_; ci++) {
        const int p  = ci & 1;
        const int tc = ci * CT_;
        const float* sqp  = sqb + p * (CT_ * 68);
        const float* skp  = skb + p * (CT_ * 68);
        const float* svp  = svb + p * (CT_ * 68);
        const float* sgp_ = sgb + p * CT_;
        const float* sbp_ = sbb + p * CT_;

        if (is_cons) { CONSUME_GROUP(0, CT_); }
        else if (ci + 1 < NCH_) stage(ci + 1);
        __syncthreads();
    }
}

// ---------------------------------------------------------------- legacy 3-phase scan (ws-tight fallback)
__global__ __launch_bounds__(512)
void scan_fused(const float* __restrict__ qk, float* __restrict__ vbuf,
                const float* __restrict__ qcw, const float* __restrict__ kcw, const float* __restrict__ vcw,
                const float* __restrict__ g, const float* __restrict__ beta) {
    int blk = blockIdx.x;
    int vh  = blk & 1;
    int bh  = blk >> 1;
    int b   = bh >> 4;
    int h   = bh & 15;
    int tid = threadIdx.x;

    __shared__ __align__(16) float rawq[2][(CT_ + 3) * 64];
    __shared__ __align__(16) float rawk[2][(CT_ + 3) * 64];
    __shared__ __align__(16) float rawv[2][(CT_ + 3) * 64];
    __shared__ __align__(16) float sq[2][CT_ * 68];
    __shared__ __align__(16) float sk[2][CT_ * 68];
    __shared__ __align__(16) float sv[2][CT_ * 68];
    __shared__ float sg[2][CT_];
    __shared__ float sb[2][CT_];

    const size_t qbase = (size_t)b * T_ * 2048 + h * 64;
    const size_t kbase = qbase + 1024;
    const size_t vbase = (size_t)b * T_ * 2048 + h * 128 + vh * 64;
    const size_t gbase = (size_t)b * T_ * H_ + h;

    const bool is_cons = (tid < 256);

    const int ptid = tid - 256;
    const int pc   = ptid & 63;
    const int pw   = ptid >> 6;
    float wqa[4], wka[4], wva[4];
    if (!is_cons) {
        float4 a4 = *(const float4*)(qcw + (size_t)(h * 64 + pc) * 4);
        float4 b4 = *(const float4*)(kcw + (size_t)(h * 64 + pc) * 4);
        float4 c4 = *(const float4*)(vcw + (size_t)(h * 128 + vh * 64 + pc) * 4);
        wqa[0]=a4.x; wqa[1]=a4.y; wqa[2]=a4.z; wqa[3]=a4.w;
        wka[0]=b4.x; wka[1]=b4.y; wka[2]=b4.z; wka[3]=b4.w;
        wva[0]=c4.x; wva[1]=c4.y; wva[2]=c4.z; wva[3]=c4.w;
        if (ptid < 192) {
            int bsel = ptid >> 6, c = ptid & 63;
            float* rb = bsel == 0 ? rawq[1] : (bsel == 1 ? rawk[1] : rawv[1]);
#pragma unroll
            for (int j = 0; j < 3; j++) rb[(CT_ + j) * 64 + c] = 0.f;
        }
    }

    auto prod_phase1 = [&](int ci) {
        int rp = ci & 1;
        int tcc = ci * CT_;
        float* rq = rawq[rp]; float* rk = rawk[rp]; float* rv = rawv[rp];
        const float* pq = rawq[rp ^ 1]; const float* pk = rawk[rp ^ 1]; const float* pv = rawv[rp ^ 1];
        if (ptid < 192) {
            int bsel = ptid >> 6, c = ptid & 63;
            float*       db = bsel == 0 ? rq : (bsel == 1 ? rk : rv);
            const float* sc = bsel == 0 ? pq : (bsel == 1 ? pk : pv);
#pragma unroll
            for (int j = 0; j < 3; j++) db[j * 64 + c] = sc[(CT_ + j) * 64 + c];
        }
#pragma unroll
        for (int u = 0; u < 2; u++) {
            int idx = u * 256 + ptid;
            int r   = idx >> 4;
            int c4  = (idx & 15) * 4;
            size_t row = (size_t)(tcc + r) * 2048;
            *(float4*)(rq + (3 + r) * 64 + c4) = *(const float4*)(qk + qbase + row + c4);
            *(float4*)(rk + (3 + r) * 64 + c4) = *(const float4*)(qk + kbase + row + c4);
            *(float4*)(rv + (3 + r) * 64 + c4) = *(const float4*)(vbuf + vbase + row + c4);
        }
        if (ptid < CT_)          sg[rp][ptid]       = expf(g[gbase + (size_t)(tcc + ptid) * H_]);
        else if (ptid < 2 * CT_) sb[rp][ptid - CT_] = beta[gbase + (size_t)(tcc + ptid - CT_) * H_];
    };

    auto prod_phase2 = [&](int ci) {
        int rp = ci & 1;
        const float* rq = rawq[rp]; const float* rk = rawk[rp]; const float* rv = rawv[rp];
        float* dq = sq[rp]; float* dk = sk[rp]; float* dv = sv[rp];
#pragma unroll
        for (int it = 0; it < 8; it++) {
            int r = pw + it * 4;
            float aq = 0.f, ak = 0.f, av = 0.f;
#pragma unroll
            for (int j = 0; j < 4; j++) {
                aq += wqa[j] * rq[(r + j) * 64 + pc];
                ak += wka[j] * rk[(r + j) * 64 + pc];
                av += wva[j] * rv[(r + j) * 64 + pc];
            }
            dq[r * 68 + pc] = siluf(aq);
            dk[r * 68 + pc] = siluf(ak);
            dv[r * 68 + pc] = siluf(av);
        }
    };

    auto prod_phase3 = [&](int ci) {
        int rp = ci & 1;
        int r = ptid >> 3;
        int j = ptid & 7;
        float* kr = sk[rp] + r * 68 + j * 8;
        float* qr = sq[rp] + r * 68 + j * 8;
        float4 k0 = ((const float4*)kr)[0], k1 = ((const float4*)kr)[1];
        float4 q0 = ((const float4*)qr)[0], q1 = ((const float4*)qr)[1];
        float ssk = k0.x*k0.x + k0.y*k0.y + k0.z*k0.z + k0.w*k0.w
                  + k1.x*k1.x + k1.y*k1.y + k1.z*k1.z + k1.w*k1.w;
        float ssq = q0.x*q0.x + q0.y*q0.y + q0.z*q0.z + q0.w*q0.w
                  + q1.x*q1.x + q1.y*q1.y + q1.z*q1.z + q1.w*q1.w;
        ssk += __shfl_xor(ssk, 1); ssk += __shfl_xor(ssk, 2); ssk += __shfl_xor(ssk, 4);
        ssq += __shfl_xor(ssq, 1); ssq += __shfl_xor(ssq, 2); ssq += __shfl_xor(ssq, 4);
        float rk_ = rsqrtf(ssk + 1e-6f);
        float rq_ = rsqrtf(ssq + 1e-6f) * 0.125f;
        k0.x*=rk_; k0.y*=rk_; k0.z*=rk_; k0.w*=rk_;
        k1.x*=rk_; k1.y*=rk_; k1.z*=rk_; k1.w*=rk_;
        q0.x*=rq_; q0.y*=rq_; q0.z*=rq_; q0.w*=rq_;
        q1.x*=rq_; q1.y*=rq_; q1.z*=rq_; q1.w*=rq_;
        ((float4*)kr)[0] = k0; ((float4*)kr)[1] = k1;
        ((float4*)qr)[0] = q0; ((float4*)qr)[1] = q1;
    };

    const int dkq = tid & 3;
    const int dvl = tid >> 2;
    const int dk0 = dkq * 16;
    float S[16];
#pragma unroll
    for (int i = 0; i < 16; i++) S[i] = 0.f;

    if (!is_cons) prod_phase1(0);
    __syncthreads();
    if (!is_cons) prod_phase2(0);
    __syncthreads();
    if (!is_cons) prod_phase3(0);
    __syncthreads();

    for (int ci = 0; ci < NCH_; ci++) {
        const int p  = ci & 1;
        const int tc = ci * CT_;
        const float* sqp  = sq[p];
        const float* skp  = sk[p];
        const float* svp  = sv[p];
        const float* sgp_ = sg[p];
        const float* sbp_ = sb[p];

        if (is_cons) { CONSUME_GROUP(0, 11); }
        else if (ci + 1 < NCH_) prod_phase1(ci + 1);
        __syncthreads();
        if (is_cons) { CONSUME_GROUP(11, 22); }
        else if (ci + 1 < NCH_) prod_phase2(ci + 1);
        __syncthreads();
        if (is_cons) { CONSUME_GROUP(22, 32); }
        else if (ci + 1 < NCH_) prod_phase3(ci + 1);
        __syncthreads();
    }
}

// ---------------------------------------------------------------- postnorm: rms(o)*silu(g_out) -> og bf16
__global__ __launch_bounds__(256)
void postnorm_k(float* __restrict__ vbuf, const unsigned short* __restrict__ gout) {
    int bt  = blockIdx.x;
    int tid = threadIdx.x;
    const float* orow = vbuf + (size_t)bt * 2048 + tid * 8;
    float4 a = ((const float4*)orow)[0];
    float4 c = ((const float4*)orow)[1];
    float ss = a.x*a.x + a.y*a.y + a.z*a.z + a.w*a.w
             + c.x*c.x + c.y*c.y + c.z*c.z + c.w*c.w;
    ss += __shfl_xor(ss, 1); ss += __shfl_xor(ss, 2); ss += __shfl_xor(ss, 4); ss += __shfl_xor(ss, 8);
    float rms = rsqrtf(ss * (1.f / 128.f) + 1.1920928955078125e-07f);
    const unsigned short* grow = gout + (size_t)bt * 2048 + tid * 8;
    ushort4 g1 = ((const ushort4*)grow)[0];
    ushort4 g2 = ((const ushort4*)grow)[1];
    ushort4 r0, r1;
    r0.x = f2bf(a.x * rms * siluf(bf2f(g1.x)));
    r0.y = f2bf(a.y * rms * siluf(bf2f(g1.y)));
    r0.z = f2bf(a.z * rms * siluf(bf2f(g1.z)));
    r0.w = f2bf(a.w * rms * siluf(bf2f(g1.w)));
    r1.x = f2bf(c.x * rms * siluf(bf2f(g2.x)));
    r1.y = f2bf(c.y * rms * siluf(bf2f(g2.y)));
    r1.z = f2bf(c.z * rms * siluf(bf2f(g2.z)));
    r1.w = f2bf(c.w * rms * siluf(bf2f(g2.w)));
    __syncthreads();   // all reads of this row done before in-place overwrite
    unsigned short* og = (unsigned short*)vbuf + (size_t)bt * 4096 + tid * 8;
    *(ushort4*)og       = r0;
    *(ushort4*)(og + 4) = r1;
}

// ---------------------------------------------------------------- launch
// CLEAN layout (needs ws >= 177 MiB):
//   [0,32)    xh      [32,64)  xl  (xl later reused as g_out bf16 — xl dead after gemm_dual)
//   [64,72)   qkw_h   [72,80)  qkw_l
//   [80,96)   vgw_h (v rows then g rows)   [96,104) vgw_l (v-half)
//   [104,112) ow_bf
//   [112,176) vbuf f32 (v -> o in-place -> og bf16 stride 4096)
//   [176,177) gbuf, bbuf
// d_out: qk f32 (GEMM1) -> consumed by scan -> final f32 output.
extern "C" void kernel_launch(void* const* d_in, const int* in_sizes, int n_in,
                              void* d_out, int out_size, void* d_ws, size_t ws_size,
                              hipStream_t stream) {
    (void)in_sizes; (void)n_in; (void)out_size;
    const float* x        = (const float*)d_in[0];
    const float* qk_w     = (const float*)d_in[1];
    const float* vg_w     = (const float*)d_in[2];
    const float* o_w      = (const float*)d_in[3];
    const float* a_w      = (const float*)d_in[4];
    const float* b_w      = (const float*)d_in[5];
    const float* b_bias   = (const float*)d_in[6];
    const float* beta_b   = (const float*)d_in[7];
    const float* A_log    = (const float*)d_in[8];
    const float* dt_bias  = (const float*)d_in[9];
    const float* q_conv_w = (const float*)d_in[10];
    const float* k_conv_w = (const float*)d_in[11];
    const float* v_conv_w = (const float*)d_in[12];

    char* ws = (char*)d_ws;
    float* qkf            = (float*)d_out;
    float* outp           = (float*)d_out;

    if (ws_size >= (size_t)177u * 1024u * 1024u) {
        unsigned short* xh    = (unsigned short*)(ws);
        unsigned short* xl    = (unsigned short*)(ws + (32u << 20));
        unsigned short* qkw_h = (unsigned short*)(ws + (64u << 20));
        unsigned short* qkw_l = (unsigned short*)(ws + (72u << 20));
        unsigned short* vgw_h = (unsigned short*)(ws + (80u << 20));
        unsigned short* vgw_l = (unsigned short*)(ws + (96u << 20));
        unsigned short* ow_bf = (unsigned short*)(ws + (104u << 20));
        float*          vbuf  = (float*)(ws + (112u << 20));
        float*          gbuf  = (float*)(ws + (176u << 20));
        float*          bbuf  = (float*)(ws + (176u << 20) + (512u << 10));
        unsigned short* goutb = xl;   // g_out bf16 overwrites xl (dead after gemm_dual)

        // 1) all casts, one launch
        {
            const int NTOT = BT_ * C_ / 4 + 4 * (2048 * 2048 / 4);   // 8,388,608
            cast_all_k<<<NTOT / 256, 256, 0, stream>>>(x, qk_w, vg_w, o_w,
                xh, xl, qkw_h, qkw_l, vgw_h, vgw_l, ow_bf);
        }

        // 2) dual DO_LO GEMM: qk -> d_out, v -> vbuf (one dispatch, shared A)
        gemm_dual<<<dim3(32, 64), 256, 0, stream>>>(xh, xl, qkw_h, qkw_l, qkf, vgw_h, vgw_l, vbuf);

        // 3) gates (exact fp32)
        gates_k<<<BT_, 256, 0, stream>>>(x, a_w, b_w, b_bias, beta_b, A_log, dt_bias, gbuf, bbuf);

        // 4) fused scan + g_out GEMM (g_out hidden under the scan; writes goutb over xl)
        scan_gemm_k<<<128 + 1024, 512, 54272, stream>>>(
            qkf, vbuf, q_conv_w, k_conv_w, v_conv_w, gbuf, bbuf,
            xh, vgw_h + (size_t)2048 * 2048, goutb);

        // 5) postnorm -> og bf16 in-place over vbuf (stride 4096 ushort)
        postnorm_k<<<BT_, 256, 0, stream>>>(vbuf, goutb);

        // 6) final GEMM: og @ o_w.T -> d_out f32
        gemm_bf<false, true><<<dim3(16, 64), 256, 0, stream>>>(
            (const unsigned short*)vbuf, nullptr, 4096, ow_bf, nullptr, outp, BT_, 2048, 2048);
    } else {
        // ---------------- LEGACY path (121 MiB)
        unsigned short* qkw_h = (unsigned short*)(ws);
        unsigned short* qkw_l = (unsigned short*)(ws + (8u  << 20));
        unsigned short* vgw_h = (unsigned short*)(ws + (16u << 20));
        unsigned short* vgw_l = (unsigned short*)(ws + (32u << 20));
        unsigned short* ow_bf = (unsigned short*)(ws + (48u << 20));
        float*          vbuf  = (float*)(ws + (56u << 20));
        float*          gbuf  = (float*)(ws + (120u << 20));
        float*          bbuf  = (float*)(ws + (120u << 20) + (512u << 10));
        unsigned short* goutb = (unsigned short*)d_out;

        cast_split_k<<<(2048 * 2048 / 4 + 255) / 256, 256, 0, stream>>>(qk_w, qkw_h, qkw_l, 2048 * 2048 / 4);
        cast_split_k<<<(2048 * 2048 / 4 + 255) / 256, 256, 0, stream>>>(vg_w, vgw_h, vgw_l, 2048 * 2048 / 4);
        cast_plain_k<<<(2048 * 2048 / 4 + 255) / 256, 256, 0, stream>>>(
            vg_w + (size_t)2048 * 2048, vgw_h + (size_t)2048 * 2048, 2048 * 2048 / 4);
        cast_plain_k<<<(2048 * 2048 / 4 + 255) / 256, 256, 0, stream>>>(o_w, ow_bf, 2048 * 2048 / 4);

        gemm_pc<true, true, true><<<dim3(16, 64), 512, 0, stream>>>(x, 2048, qkw_h, qkw_l, qkf, BT_, 2048, 2048);
        gemm_pc<true, true, true><<<dim3(16, 64), 512, 0, stream>>>(x, 2048, vgw_h, vgw_l, vbuf, BT_, 2048, 2048);

        gates_k<<<BT_, 256, 0, stream>>>(x, a_w, b_w, b_bias, beta_b, A_log, dt_bias, gbuf, bbuf);

        scan_fused<<<B_ * H_ * 2, 512, 0, stream>>>(qkf, vbuf, q_conv_w, k_conv_w, v_conv_w, gbuf, bbuf);

        gemm_pc<false, false, true><<<dim3(16, 64), 512, 0, stream>>>(
            x, 2048, vgw_h + (size_t)2048 * 2048, nullptr, goutb, BT_, 2048, 2048);

        postnorm_k<<<BT_, 256, 0, stream>>>(vbuf, goutb);

        gemm_pc<false, true, false><<<dim3(16, 64), 512, 0, stream>>>(
            (const void*)vbuf, 4096, ow_bf, nullptr, outp, BT_, 2048, 2048);
    }
}

// Round 6
// 1273.138 us; speedup vs baseline: 1.8318x; 1.0668x over previous
//
#include <hip/hip_runtime.h>
#include <hip/hip_bf16.h>
#include <stdint.h>

// Problem constants
#define B_ 4
#define T_ 2048
#define C_ 2048
#define H_ 16
#define DK_ 64
#define DV_ 128
#define BT_ (B_ * T_)   // 8192

typedef __attribute__((ext_vector_type(8))) __bf16 bf16x8;
typedef __attribute__((ext_vector_type(4))) float f32x4;

__device__ __forceinline__ unsigned short f2bf(float f) {
    union { float f; uint32_t u; } v; v.f = f;
    uint32_t u = v.u;
    uint32_t r = u + 0x7FFFu + ((u >> 16) & 1u);   // RNE
    return (unsigned short)(r >> 16);
}
__device__ __forceinline__ float bf2f(unsigned short h) {
    union { uint32_t u; float f; } v; v.u = ((uint32_t)h) << 16; return v.f;
}
__device__ __forceinline__ float siluf(float x) { return x / (1.f + expf(-x)); }

// DPP reduce helpers. quad_perm(1,0,3,2)=0xB1 (xor1), quad_perm(2,3,0,1)=0x4E (xor2),
// row_half_mirror=0x141 (pairs quads within an 8-lane half-row -> completes an 8-lane sum
// after xor1+xor2 have made each quad hold its quad-sum).
__device__ __forceinline__ float dpp_xor1_add(float x) {
    int t = __builtin_amdgcn_update_dpp(0, __float_as_int(x), 0xB1, 0xF, 0xF, true);
    return x + __int_as_float(t);
}
__device__ __forceinline__ float dpp_xor2_add(float x) {
    int t = __builtin_amdgcn_update_dpp(0, __float_as_int(x), 0x4E, 0xF, 0xF, true);
    return x + __int_as_float(t);
}
__device__ __forceinline__ float dpp_mir8_add(float x) {
    int t = __builtin_amdgcn_update_dpp(0, __float_as_int(x), 0x141, 0xF, 0xF, true);
    return x + __int_as_float(t);
}

// hi = RNE bf16 of x; lo = trunc bf16 of (x - hi). x ≈ hi + lo to ~2^-17 rel.
__device__ __forceinline__ void split_hl(float x, unsigned short& h, unsigned short& l) {
    unsigned short hu = f2bf(x);
    float lo = x - bf2f(hu);
    h = hu;
    l = (unsigned short)(__float_as_uint(lo) >> 16);
}

// ---------------------------------------------------------------- casts
__global__ void cast_split_k(const float* __restrict__ in,
                             unsigned short* __restrict__ oh, unsigned short* __restrict__ ol, int n4) {
    int i = blockIdx.x * blockDim.x + threadIdx.x;
    if (i >= n4) return;
    float4 v = ((const float4*)in)[i];
    ushort4 h, l;
    split_hl(v.x, h.x, l.x); split_hl(v.y, h.y, l.y);
    split_hl(v.z, h.z, l.z); split_hl(v.w, h.w, l.w);
    ((ushort4*)oh)[i] = h;
    ((ushort4*)ol)[i] = l;
}

__global__ void cast_plain_k(const float* __restrict__ in, unsigned short* __restrict__ out, int n4) {
    int i = blockIdx.x * blockDim.x + threadIdx.x;
    if (i >= n4) return;
    float4 v = ((const float4*)in)[i];
    ushort4 o;
    o.x = f2bf(v.x); o.y = f2bf(v.y); o.z = f2bf(v.z); o.w = f2bf(v.w);
    ((ushort4*)out)[i] = o;
}

// merged cast: x split + qk_w split + vg_w(v) split + vg_w(g) plain + o_w plain, one launch
__global__ __launch_bounds__(256)
void cast_all_k(const float* __restrict__ x, const float* __restrict__ qk_w,
                const float* __restrict__ vg_w, const float* __restrict__ o_w,
                unsigned short* __restrict__ xh, unsigned short* __restrict__ xl,
                unsigned short* __restrict__ qkw_h, unsigned short* __restrict__ qkw_l,
                unsigned short* __restrict__ vgw_h, unsigned short* __restrict__ vgw_l,
                unsigned short* __restrict__ ow_bf) {
    const int NX = BT_ * C_ / 4;        // 4,194,304
    const int NW = 2048 * 2048 / 4;     // 1,048,576
    int i = blockIdx.x * blockDim.x + threadIdx.x;
    const float* src; unsigned short *dh, *dl; int j; bool split;
    if (i < NX)               { j = i;            src = x;                          dh = xh;    dl = xl;    split = true; }
    else if (i < NX + NW)     { j = i - NX;       src = qk_w;                       dh = qkw_h; dl = qkw_l; split = true; }
    else if (i < NX + 2 * NW) { j = i - NX - NW;  src = vg_w;                       dh = vgw_h; dl = vgw_l; split = true; }
    else if (i < NX + 3 * NW) { j = i - NX - 2*NW; src = vg_w + (size_t)2048*2048;  dh = vgw_h + (size_t)2048*2048; dl = nullptr; split = false; }
    else                      { j = i - NX - 3*NW; src = o_w;                       dh = ow_bf; dl = nullptr; split = false; }
    float4 v = ((const float4*)src)[j];
    ushort4 h, l;
    if (split) {
        split_hl(v.x, h.x, l.x); split_hl(v.y, h.y, l.y);
        split_hl(v.z, h.z, l.z); split_hl(v.w, h.w, l.w);
        ((ushort4*)dh)[j] = h;
        ((ushort4*)dl)[j] = l;
    } else {
        h.x = f2bf(v.x); h.y = f2bf(v.y); h.z = f2bf(v.z); h.w = f2bf(v.w);
        ((ushort4*)dh)[j] = h;
    }
}

// ---------------------------------------------------------------- async global->LDS (16B/lane)
__device__ __forceinline__ void gld_lds16(const unsigned short* gptr,
                                          unsigned short* lds_base) {
    __builtin_amdgcn_global_load_lds(
        (const __attribute__((address_space(1))) uint32_t*)(uintptr_t)gptr,
        (__attribute__((address_space(3))) uint32_t*)(uint32_t)(uintptr_t)lds_base,
        16, 0, 0);
}

// ---------------------------------------------------------------- all-bf16 GEMM (m97 structure)
template<bool DO_LO, bool F32OUT>
__global__ __launch_bounds__(256)
void gemm_bf(const unsigned short* __restrict__ Ah, const unsigned short* __restrict__ Al, int lda,
             const unsigned short* __restrict__ Wh, const unsigned short* __restrict__ Wl,
             void* __restrict__ Cout, int M, int N, int K) {
    __shared__ __align__(16) unsigned short sAh[128 * 64];
    __shared__ __align__(16) unsigned short sWh[128 * 64];
    __shared__ __align__(16) unsigned short sAl[DO_LO ? 128 * 64 : 16];
    __shared__ __align__(16) unsigned short sWl[DO_LO ? 128 * 64 : 16];
    const int tid  = threadIdx.x;
    const int wave = tid >> 6;
    const int lane = tid & 63;
    const int wm = (wave >> 1) * 64;
    const int wn = (wave & 1) * 64;
    const int bm = blockIdx.y, bn = blockIdx.x;
    const int srow = lane >> 3;
    const int scol = (lane & 7) * 8;

    const unsigned short* Agh = Ah + (size_t)(bm * 128) * lda;
    const unsigned short* Agl = DO_LO ? (Al + (size_t)(bm * 128) * lda) : nullptr;
    const unsigned short* Wgh = Wh + (size_t)(bn * 128) * K;
    const unsigned short* Wgl = DO_LO ? (Wl + (size_t)(bn * 128) * K) : nullptr;

    f32x4 acc[4][4];
#pragma unroll
    for (int i = 0; i < 4; i++)
#pragma unroll
        for (int j = 0; j < 4; j++) { acc[i][j][0]=0.f; acc[i][j][1]=0.f; acc[i][j][2]=0.f; acc[i][j][3]=0.f; }

    const int mrow = lane & 15;
    const int kq   = (lane >> 4) * 8;

    for (int k0 = 0; k0 < K; k0 += 64) {
#pragma unroll
        for (int i = 0; i < 4; i++) {
            int rbase = wave * 32 + i * 8;
            gld_lds16(Agh + (size_t)(rbase + srow) * lda + k0 + scol, sAh + rbase * 64);
            gld_lds16(Wgh + (size_t)(rbase + srow) * K   + k0 + scol, sWh + rbase * 64);
            if (DO_LO) {
                gld_lds16(Agl + (size_t)(rbase + srow) * lda + k0 + scol, sAl + rbase * 64);
                gld_lds16(Wgl + (size_t)(rbase + srow) * K   + k0 + scol, sWl + rbase * 64);
            }
        }
        __syncthreads();
#pragma unroll
        for (int kk = 0; kk < 2; kk++) {
            bf16x8 afh[4], wfh[4];
#pragma unroll
            for (int i = 0; i < 4; i++)
                afh[i] = *(const bf16x8*)(sAh + (wm + i * 16 + mrow) * 64 + kk * 32 + kq);
#pragma unroll
            for (int j = 0; j < 4; j++)
                wfh[j] = *(const bf16x8*)(sWh + (wn + j * 16 + mrow) * 64 + kk * 32 + kq);
#pragma unroll
            for (int i = 0; i < 4; i++)
#pragma unroll
                for (int j = 0; j < 4; j++)
                    acc[i][j] = __builtin_amdgcn_mfma_f32_16x16x32_bf16(afh[i], wfh[j], acc[i][j], 0, 0, 0);
            if (DO_LO) {
                bf16x8 afl[4], wfl[4];
#pragma unroll
                for (int i = 0; i < 4; i++)
                    afl[i] = *(const bf16x8*)(sAl + (wm + i * 16 + mrow) * 64 + kk * 32 + kq);
#pragma unroll
                for (int j = 0; j < 4; j++)
                    wfl[j] = *(const bf16x8*)(sWl + (wn + j * 16 + mrow) * 64 + kk * 32 + kq);
#pragma unroll
                for (int i = 0; i < 4; i++)
#pragma unroll
                    for (int j = 0; j < 4; j++) {
                        acc[i][j] = __builtin_amdgcn_mfma_f32_16x16x32_bf16(afh[i], wfl[j], acc[i][j], 0, 0, 0);
                        acc[i][j] = __builtin_amdgcn_mfma_f32_16x16x32_bf16(afl[i], wfh[j], acc[i][j], 0, 0, 0);
                    }
            }
        }
        __syncthreads();
    }
    const int r0 = (lane >> 4) * 4;
    const int cn = lane & 15;
#pragma unroll
    for (int i = 0; i < 4; i++) {
#pragma unroll
        for (int r = 0; r < 4; r++) {
            int row = bm * 128 + wm + i * 16 + r0 + r;
            size_t base = (size_t)row * N + bn * 128 + wn + cn;
            if constexpr (F32OUT) {
                float* Crow = (float*)Cout + base;
#pragma unroll
                for (int j = 0; j < 4; j++) Crow[j * 16] = acc[i][j][r];
            } else {
                unsigned short* Crow = (unsigned short*)Cout + base;
#pragma unroll
                for (int j = 0; j < 4; j++) Crow[j * 16] = f2bf(acc[i][j][r]);
            }
        }
    }
}

// ---------------------------------------------------------------- per-head gates body (exact fp32)
__device__ __forceinline__ float softplusf(float x) {
    return (x > 20.f) ? x : log1pf(expf(x));
}

__device__ __forceinline__ void gates_body(int bt, int tid,
             const float* __restrict__ x, const float* __restrict__ a_w, const float* __restrict__ b_w,
             const float* __restrict__ b_bias, const float* __restrict__ beta_bias,
             const float* __restrict__ A_log, const float* __restrict__ dt_bias,
             float* __restrict__ g, float* __restrict__ beta) {
    int wave = tid >> 6, lane = tid & 63;
    const float* xr = x + (size_t)bt * C_;
#pragma unroll
    for (int dd = 0; dd < 8; dd++) {
        int d = wave * 8 + dd;
        int h = d & 15;
        const float* wr = (d < 16 ? a_w : b_w) + (size_t)h * C_;
        float acc = 0.f;
#pragma unroll
        for (int it = 0; it < 8; it++) {
            float4 xv = ((const float4*)xr)[lane + it * 64];
            float4 wv = ((const float4*)wr)[lane + it * 64];
            acc += xv.x * wv.x + xv.y * wv.y + xv.z * wv.z + xv.w * wv.w;
        }
        acc += __shfl_xor(acc, 1);  acc += __shfl_xor(acc, 2);  acc += __shfl_xor(acc, 4);
        acc += __shfl_xor(acc, 8);  acc += __shfl_xor(acc, 16); acc += __shfl_xor(acc, 32);
        if (lane == 0) {
            if (d < 16) {
                g[(size_t)bt * H_ + h] = -expf(A_log[h]) * softplusf(acc + dt_bias[h]);
            } else {
                float s = 1.f / (1.f + expf(-(acc + b_bias[h] + beta_bias[h])));
                beta[(size_t)bt * H_ + h] = 2.f * s;
            }
        }
    }
}

__global__ __launch_bounds__(256)
void gates_k(const float* __restrict__ x, const float* __restrict__ a_w, const float* __restrict__ b_w,
             const float* __restrict__ b_bias, const float* __restrict__ beta_bias,
             const float* __restrict__ A_log, const float* __restrict__ dt_bias,
             float* __restrict__ g, float* __restrict__ beta) {
    gates_body(blockIdx.x, threadIdx.x, x, a_w, b_w, b_bias, beta_bias, A_log, dt_bias, g, beta);
}

// ---------------------------------------------------------------- dual DO_LO GEMM + gates (one dispatch)
// bid < 2048: 128x128 DO_LO tile, XCD-chunk-swizzled (bijective, 2048 = 8*256) so each
// XCD works 8 consecutive bm A-panels (L2 A-reuse). bid >= 2048: gates block (BW/L3-bound,
// backfills behind the MFMA-bound GEMM blocks).
__global__ __launch_bounds__(256)
void gemm_dual_gates(const unsigned short* __restrict__ Ah, const unsigned short* __restrict__ Al,
                     const unsigned short* __restrict__ Wh0, const unsigned short* __restrict__ Wl0, float* __restrict__ C0,
                     const unsigned short* __restrict__ Wh1, const unsigned short* __restrict__ Wl1, float* __restrict__ C1,
                     const float* __restrict__ x, const float* __restrict__ a_w, const float* __restrict__ b_w,
                     const float* __restrict__ b_bias, const float* __restrict__ beta_bias,
                     const float* __restrict__ A_log, const float* __restrict__ dt_bias,
                     float* __restrict__ g, float* __restrict__ beta) {
    const int bid = blockIdx.x;
    const int tid = threadIdx.x;
    if (bid >= 2048) {
        gates_body(bid - 2048, tid, x, a_w, b_w, b_bias, beta_bias, A_log, dt_bias, g, beta);
        return;
    }
    __shared__ __align__(16) unsigned short sAh[128 * 64];
    __shared__ __align__(16) unsigned short sWh[128 * 64];
    __shared__ __align__(16) unsigned short sAl[128 * 64];
    __shared__ __align__(16) unsigned short sWl[128 * 64];
    // XCD-chunk swizzle: xcd = bid&7 -> wg in [xcd*256, xcd*256+256) -> 8 contiguous bm
    const int wg  = ((bid & 7) << 8) | (bid >> 3);
    const int bm  = wg >> 5;
    const int bnx = wg & 31;
    const int K = 2048, N = 2048, lda = 2048;
    const int wave = tid >> 6;
    const int lane = tid & 63;
    const int wm = (wave >> 1) * 64;
    const int wn = (wave & 1) * 64;
    const unsigned short* Wh = (bnx < 16) ? Wh0 : Wh1;
    const unsigned short* Wl = (bnx < 16) ? Wl0 : Wl1;
    float* Csel              = (bnx < 16) ? C0  : C1;
    const int bn = bnx & 15;
    const int srow = lane >> 3;
    const int scol = (lane & 7) * 8;

    const unsigned short* Agh = Ah + (size_t)(bm * 128) * lda;
    const unsigned short* Agl = Al + (size_t)(bm * 128) * lda;
    const unsigned short* Wgh = Wh + (size_t)(bn * 128) * K;
    const unsigned short* Wgl = Wl + (size_t)(bn * 128) * K;

    f32x4 acc[4][4];
#pragma unroll
    for (int i = 0; i < 4; i++)
#pragma unroll
        for (int j = 0; j < 4; j++) { acc[i][j][0]=0.f; acc[i][j][1]=0.f; acc[i][j][2]=0.f; acc[i][j][3]=0.f; }

    const int mrow = lane & 15;
    const int kq   = (lane >> 4) * 8;

    for (int k0 = 0; k0 < K; k0 += 64) {
#pragma unroll
        for (int i = 0; i < 4; i++) {
            int rbase = wave * 32 + i * 8;
            gld_lds16(Agh + (size_t)(rbase + srow) * lda + k0 + scol, sAh + rbase * 64);
            gld_lds16(Wgh + (size_t)(rbase + srow) * K   + k0 + scol, sWh + rbase * 64);
            gld_lds16(Agl + (size_t)(rbase + srow) * lda + k0 + scol, sAl + rbase * 64);
            gld_lds16(Wgl + (size_t)(rbase + srow) * K   + k0 + scol, sWl + rbase * 64);
        }
        __syncthreads();
#pragma unroll
        for (int kk = 0; kk < 2; kk++) {
            bf16x8 afh[4], wfh[4];
#pragma unroll
            for (int i = 0; i < 4; i++)
                afh[i] = *(const bf16x8*)(sAh + (wm + i * 16 + mrow) * 64 + kk * 32 + kq);
#pragma unroll
            for (int j = 0; j < 4; j++)
                wfh[j] = *(const bf16x8*)(sWh + (wn + j * 16 + mrow) * 64 + kk * 32 + kq);
#pragma unroll
            for (int i = 0; i < 4; i++)
#pragma unroll
                for (int j = 0; j < 4; j++)
                    acc[i][j] = __builtin_amdgcn_mfma_f32_16x16x32_bf16(afh[i], wfh[j], acc[i][j], 0, 0, 0);
            bf16x8 afl[4], wfl[4];
#pragma unroll
            for (int i = 0; i < 4; i++)
                afl[i] = *(const bf16x8*)(sAl + (wm + i * 16 + mrow) * 64 + kk * 32 + kq);
#pragma unroll
            for (int j = 0; j < 4; j++)
                wfl[j] = *(const bf16x8*)(sWl + (wn + j * 16 + mrow) * 64 + kk * 32 + kq);
#pragma unroll
            for (int i = 0; i < 4; i++)
#pragma unroll
                for (int j = 0; j < 4; j++) {
                    acc[i][j] = __builtin_amdgcn_mfma_f32_16x16x32_bf16(afh[i], wfl[j], acc[i][j], 0, 0, 0);
                    acc[i][j] = __builtin_amdgcn_mfma_f32_16x16x32_bf16(afl[i], wfh[j], acc[i][j], 0, 0, 0);
                }
        }
        __syncthreads();
    }
    const int r0 = (lane >> 4) * 4;
    const int cn = lane & 15;
#pragma unroll
    for (int i = 0; i < 4; i++) {
#pragma unroll
        for (int r = 0; r < 4; r++) {
            int row = bm * 128 + wm + i * 16 + r0 + r;
            float* Crow = Csel + (size_t)row * N + bn * 128 + wn + cn;
#pragma unroll
            for (int j = 0; j < 4; j++) Crow[j * 16] = acc[i][j][r];
        }
    }
}

// ---------------------------------------------------------------- legacy producer/consumer GEMM (ws-tight fallback)
template<bool DO_LO, bool F32OUT, bool A_F32>
__global__ __launch_bounds__(512, 2)
void gemm_pc(const void* __restrict__ Aptr, int lda,
             const unsigned short* __restrict__ Wh, const unsigned short* __restrict__ Wl,
             void* __restrict__ Cout, int M, int N, int K) {
    __shared__ __align__(16) unsigned short sAh[2][128 * 64];
    __shared__ __align__(16) unsigned short sWh[2][128 * 64];
    __shared__ __align__(16) unsigned short sAl[DO_LO ? 2 : 1][DO_LO ? 128 * 64 : 16];
    __shared__ __align__(16) unsigned short sWl[DO_LO ? 2 : 1][DO_LO ? 128 * 64 : 16];

    const int tid  = threadIdx.x;
    const bool is_cons = (tid < 256);
    const int bm = blockIdx.y, bn = blockIdx.x;
    const int NK = K >> 6;

    const int ptid  = tid - 256;
    const int pw    = ptid >> 6;
    const int plane = ptid & 63;
    const int wrow  = plane >> 3;
    const int wcol  = (plane & 7) * 8;

    const float*          Agf = (const float*)Aptr + (size_t)(bm * 128) * lda;
    const unsigned short* Agb = (const unsigned short*)Aptr + (size_t)(bm * 128) * lda;
    const unsigned short* Whg = Wh + (size_t)(bn * 128) * K;
    const unsigned short* Wlg = DO_LO ? (Wl + (size_t)(bn * 128) * K) : nullptr;

    auto stage = [&](int p, int k0) {
#pragma unroll
        for (int i = 0; i < 4; i++) {
            int rbase = pw * 32 + i * 8;
            gld_lds16(Whg + (size_t)(rbase + wrow) * K + k0 + wcol, sWh[p] + rbase * 64);
            if (DO_LO)
                gld_lds16(Wlg + (size_t)(rbase + wrow) * K + k0 + wcol, sWl[p] + rbase * 64);
            if (!A_F32)
                gld_lds16(Agb + (size_t)(rbase + wrow) * lda + k0 + wcol, sAh[p] + rbase * 64);
        }
        if (A_F32) {
#pragma unroll
            for (int it = 0; it < 8; it++) {
                int idx = it * 256 + ptid;
                int r   = idx >> 4;
                int c4  = (idx & 15) * 4;
                float4 v = *(const float4*)(Agf + (size_t)r * lda + k0 + c4);
                ushort4 h, l;
                split_hl(v.x, h.x, l.x); split_hl(v.y, h.y, l.y);
                split_hl(v.z, h.z, l.z); split_hl(v.w, h.w, l.w);
                *(ushort4*)(sAh[p] + r * 64 + c4) = h;
                if (DO_LO) *(ushort4*)(sAl[p] + r * 64 + c4) = l;
            }
        }
    };

    const int wave = tid >> 6;
    const int lane = tid & 63;
    const int wm = (wave >> 1) * 64;
    const int wn = (wave & 1) * 64;
    const int mrow = lane & 15;
    const int kq   = (lane >> 4) * 8;

    f32x4 acc[4][4];
#pragma unroll
    for (int i = 0; i < 4; i++)
#pragma unroll
        for (int j = 0; j < 4; j++) { acc[i][j][0]=0.f; acc[i][j][1]=0.f; acc[i][j][2]=0.f; acc[i][j][3]=0.f; }

    if (!is_cons) stage(0, 0);
    __syncthreads();

    for (int ks = 0; ks < NK; ks++) {
        const int p = ks & 1;
        if (is_cons) {
            const unsigned short* pAh = sAh[p];
            const unsigned short* pWh = sWh[p];
            const unsigned short* pAl = sAl[DO_LO ? p : 0];
            const unsigned short* pWl = sWl[DO_LO ? p : 0];
#pragma unroll
            for (int kk = 0; kk < 2; kk++) {
                bf16x8 afh[4], wfh[4];
#pragma unroll
                for (int i = 0; i < 4; i++)
                    afh[i] = *(const bf16x8*)(pAh + (wm + i * 16 + mrow) * 64 + kk * 32 + kq);
#pragma unroll
                for (int j = 0; j < 4; j++)
                    wfh[j] = *(const bf16x8*)(pWh + (wn + j * 16 + mrow) * 64 + kk * 32 + kq);
#pragma unroll
                for (int i = 0; i < 4; i++)
#pragma unroll
                    for (int j = 0; j < 4; j++)
                        acc[i][j] = __builtin_amdgcn_mfma_f32_16x16x32_bf16(afh[i], wfh[j], acc[i][j], 0, 0, 0);
                if (DO_LO) {
                    bf16x8 afl[4], wfl[4];
#pragma unroll
                    for (int i = 0; i < 4; i++)
                        afl[i] = *(const bf16x8*)(pAl + (wm + i * 16 + mrow) * 64 + kk * 32 + kq);
#pragma unroll
                    for (int j = 0; j < 4; j++)
                        wfl[j] = *(const bf16x8*)(pWl + (wn + j * 16 + mrow) * 64 + kk * 32 + kq);
#pragma unroll
                    for (int i = 0; i < 4; i++)
#pragma unroll
                        for (int j = 0; j < 4; j++) {
                            acc[i][j] = __builtin_amdgcn_mfma_f32_16x16x32_bf16(afh[i], wfl[j], acc[i][j], 0, 0, 0);
                            acc[i][j] = __builtin_amdgcn_mfma_f32_16x16x32_bf16(afl[i], wfh[j], acc[i][j], 0, 0, 0);
                        }
                }
            }
        } else if (ks + 1 < NK) {
            stage(p ^ 1, (ks + 1) * 64);
        }
        __syncthreads();
    }

    if (is_cons) {
        const int r0 = (lane >> 4) * 4;
        const int cn = lane & 15;
#pragma unroll
        for (int i = 0; i < 4; i++) {
#pragma unroll
            for (int r = 0; r < 4; r++) {
                int row = bm * 128 + wm + i * 16 + r0 + r;
                size_t base = (size_t)row * N + bn * 128 + wn + cn;
                if constexpr (F32OUT) {
                    float* Crow = (float*)Cout + base;
#pragma unroll
                    for (int j = 0; j < 4; j++) Crow[j * 16] = acc[i][j][r];
                } else {
                    unsigned short* Crow = (unsigned short*)Cout + base;
#pragma unroll
                    for (int j = 0; j < 4; j++) Crow[j * 16] = f2bf(acc[i][j][r]);
                }
            }
        }
    }
}

// ---------------------------------------------------------------- scan step machinery
#define CT_ 32
#define NCH_ (T_ / CT_)

// ---- 8-lane k-split step (clean path): S[8] per thread, dkq = tid&7, dvl = tid>>3
#define LOAD_STEP8(t2, kf, qf, vt, dec, btt)                                 \
    {                                                                        \
        float4 ka = ((const float4*)(skp + (t2) * 68 + dk0))[0];             \
        float4 kb = ((const float4*)(skp + (t2) * 68 + dk0))[1];             \
        float4 qa = ((const float4*)(sqp + (t2) * 68 + dk0))[0];             \
        float4 qb = ((const float4*)(sqp + (t2) * 68 + dk0))[1];             \
        kf[0]=ka.x; kf[1]=ka.y; kf[2]=ka.z; kf[3]=ka.w;                      \
        kf[4]=kb.x; kf[5]=kb.y; kf[6]=kb.z; kf[7]=kb.w;                      \
        qf[0]=qa.x; qf[1]=qa.y; qf[2]=qa.z; qf[3]=qa.w;                      \
        qf[4]=qb.x; qf[5]=qb.y; qf[6]=qb.z; qf[7]=qb.w;                      \
        vt  = svp[(t2) * 33 + dvl];                                          \
        dec = sgp_[(t2)];                                                    \
        btt = sbp_[(t2)];                                                    \
    }

#define DO_STEP8(t2, kf, qf, vt, dec, btt)                                   \
    {                                                                        \
        float m0 = kf[0]*S[0]; float m1 = kf[1]*S[1];                        \
        float m2 = kf[2]*S[2]; float m3 = kf[3]*S[3];                        \
        m0 += kf[4]*S[4]; m1 += kf[5]*S[5];                                  \
        m2 += kf[6]*S[6]; m3 += kf[7]*S[7];                                  \
        float m = (m0 + m1) + (m2 + m3);                                     \
        m = dpp_xor1_add(m); m = dpp_xor2_add(m); m = dpp_mir8_add(m);       \
        _Pragma("unroll")                                                    \
        for (int i = 0; i < 8; i++) S[i] *= dec;                             \
        float delta = (vt - m * dec) * btt;                                  \
        S[0] += kf[0]*delta; float o0 = qf[0]*S[0];                          \
        S[1] += kf[1]*delta; float o1 = qf[1]*S[1];                          \
        S[2] += kf[2]*delta; float o2 = qf[2]*S[2];                          \
        S[3] += kf[3]*delta; float o3 = qf[3]*S[3];                          \
        S[4] += kf[4]*delta; o0 += qf[4]*S[4];                               \
        S[5] += kf[5]*delta; o1 += qf[5]*S[5];                               \
        S[6] += kf[6]*delta; o2 += qf[6]*S[6];                               \
        S[7] += kf[7]*delta; o3 += qf[7]*S[7];                               \
        float ov = (o0 + o1) + (o2 + o3);                                    \
        ov = dpp_xor1_add(ov); ov = dpp_xor2_add(ov); ov = dpp_mir8_add(ov); \
        if (dkq == 0)                                                        \
            vbuf[vbase + (size_t)(tc + (t2)) * 2048 + dvl] = ov;             \
    }

#define CONSUME_GROUP8(TB, TE)                                               \
    {                                                                        \
        float kfa[8], qfa[8], kfb[8], qfb[8];                                \
        float vta, deca, btta, vtb, decb, bttb;                              \
        LOAD_STEP8(TB, kfa, qfa, vta, deca, btta);                           \
        int t2 = TB;                                                         \
        _Pragma("unroll 1")                                                  \
        for (; t2 + 2 <= (TE); t2 += 2) {                                    \
            LOAD_STEP8(t2 + 1, kfb, qfb, vtb, decb, bttb);                   \
            DO_STEP8(t2, kfa, qfa, vta, deca, btta);                         \
            if (t2 + 2 < (TE))                                               \
                LOAD_STEP8(t2 + 2, kfa, qfa, vta, deca, btta);               \
            DO_STEP8(t2 + 1, kfb, qfb, vtb, decb, bttb);                     \
        }                                                                    \
        if (t2 < (TE))                                                       \
            DO_STEP8(t2, kfa, qfa, vta, deca, btta);                         \
    }

// ---- legacy 4-lane step (ws-tight fallback)
#define LOAD_STEP(t2, kf, qf, vt, dec, btt)                                  \
    {                                                                        \
        _Pragma("unroll")                                                    \
        for (int u = 0; u < 4; u++) {                                        \
            float4 k4 = ((const float4*)(skp + (t2) * 68 + dk0))[u];         \
            float4 q4 = ((const float4*)(sqp + (t2) * 68 + dk0))[u];         \
            kf[u*4+0]=k4.x; kf[u*4+1]=k4.y; kf[u*4+2]=k4.z; kf[u*4+3]=k4.w;  \
            qf[u*4+0]=q4.x; qf[u*4+1]=q4.y; qf[u*4+2]=q4.z; qf[u*4+3]=q4.w;  \
        }                                                                    \
        vt  = svp[(t2) * 68 + dvl];                                          \
        dec = sgp_[(t2)];                                                    \
        btt = sbp_[(t2)];                                                    \
    }

#define DO_STEP(t2, kf, qf, vt, dec, btt)                                    \
    {                                                                        \
        float m0=0.f, m1=0.f, m2=0.f, m3=0.f;                                \
        _Pragma("unroll")                                                    \
        for (int u = 0; u < 4; u++) {                                        \
            m0 += kf[u*4+0]*S[u*4+0]; m1 += kf[u*4+1]*S[u*4+1];              \
            m2 += kf[u*4+2]*S[u*4+2]; m3 += kf[u*4+3]*S[u*4+3];              \
        }                                                                    \
        float m = (m0 + m1) + (m2 + m3);                                     \
        m = dpp_xor1_add(m);                                                 \
        m = dpp_xor2_add(m);                                                 \
        _Pragma("unroll")                                                    \
        for (int i = 0; i < 16; i++) S[i] *= dec;                            \
        float delta = (vt - m * dec) * btt;                                  \
        float o0=0.f, o1=0.f, o2=0.f, o3=0.f;                                \
        _Pragma("unroll")                                                    \
        for (int u = 0; u < 4; u++) {                                        \
            S[u*4+0] += kf[u*4+0]*delta; o0 += qf[u*4+0]*S[u*4+0];           \
            S[u*4+1] += kf[u*4+1]*delta; o1 += qf[u*4+1]*S[u*4+1];           \
            S[u*4+2] += kf[u*4+2]*delta; o2 += qf[u*4+2]*S[u*4+2];           \
            S[u*4+3] += kf[u*4+3]*delta; o3 += qf[u*4+3]*S[u*4+3];           \
        }                                                                    \
        float ov = (o0 + o1) + (o2 + o3);                                    \
        ov = dpp_xor1_add(ov);                                               \
        ov = dpp_xor2_add(ov);                                               \
        if (dkq == 0)                                                        \
            vbuf[vbase + (size_t)(tc + (t2)) * 2048 + dvl] = ov;             \
    }

#define CONSUME_GROUP(TB, TE)                                                \
    {                                                                        \
        float kfa[16], qfa[16], kfb[16], qfb[16];                            \
        float vta, deca, btta, vtb, decb, bttb;                              \
        LOAD_STEP(TB, kfa, qfa, vta, deca, btta);                            \
        int t2 = TB;                                                         \
        _Pragma("unroll 1")                                                  \
        for (; t2 + 2 <= (TE); t2 += 2) {                                    \
            LOAD_STEP(t2 + 1, kfb, qfb, vtb, decb, bttb);                    \
            DO_STEP(t2, kfa, qfa, vta, deca, btta);                          \
            if (t2 + 2 < (TE))                                               \
                LOAD_STEP(t2 + 2, kfa, qfa, vta, deca, btta);                \
            DO_STEP(t2 + 1, kfb, qfb, vtb, decb, bttb);                      \
        }                                                                    \
        if (t2 < (TE))                                                       \
            DO_STEP(t2, kfa, qfa, vta, deca, btta);                          \
    }

// ---------------------------------------------------------------- FUSED scan + g_out GEMM (clean path)
// Blocks 0..255: scan (b,h,vq) — DV quartered (32 v-cols/block) so the consumer k-split is
// 8 lanes/v-col (S[8]/thread: 32 FMA/step vs 64) while keeping 1 consumer wave/SIMD.
// Full 256-CU coverage. LDS 43.5 KB. Blocks 256..1279: g_out GEMM tiles (co-resident).
__global__ __launch_bounds__(512, 4)
void scan_gemm_k(const float* __restrict__ qk, float* __restrict__ vbuf,
                 const float* __restrict__ qcw, const float* __restrict__ kcw, const float* __restrict__ vcw,
                 const float* __restrict__ g, const float* __restrict__ beta,
                 const unsigned short* __restrict__ xh, const unsigned short* __restrict__ gwh,
                 unsigned short* __restrict__ gout) {
    extern __shared__ char smem_raw[];
    const int blk = blockIdx.x;
    const int tid = threadIdx.x;

    if (blk >= 256) {
        // ---------------- g_out GEMM tile: waves 0-3 active, 4-7 idle (aligned barriers)
        const int bid = blk - 256;
        const int bm = bid >> 4;
        const int bn = bid & 15;
        unsigned short* sA = (unsigned short*)smem_raw;
        unsigned short* sB = sA + 128 * 64;
        const bool act = tid < 256;
        const int wave = tid >> 6;
        const int lane = tid & 63;
        const int wm = (wave >> 1) * 64;
        const int wn = (wave & 1) * 64;
        const int srow = lane >> 3;
        const int scol = (lane & 7) * 8;
        const int mrow = lane & 15;
        const int kq   = (lane >> 4) * 8;
        const unsigned short* Ag = xh  + (size_t)(bm * 128) * 2048;
        const unsigned short* Wg = gwh + (size_t)(bn * 128) * 2048;
        f32x4 acc[4][4];
#pragma unroll
        for (int i = 0; i < 4; i++)
#pragma unroll
            for (int j = 0; j < 4; j++) { acc[i][j][0]=0.f; acc[i][j][1]=0.f; acc[i][j][2]=0.f; acc[i][j][3]=0.f; }
        for (int k0 = 0; k0 < 2048; k0 += 64) {
            if (act) {
#pragma unroll
                for (int i = 0; i < 4; i++) {
                    int rbase = wave * 32 + i * 8;
                    gld_lds16(Ag + (size_t)(rbase + srow) * 2048 + k0 + scol, sA + rbase * 64);
                    gld_lds16(Wg + (size_t)(rbase + srow) * 2048 + k0 + scol, sB + rbase * 64);
                }
            }
            __syncthreads();
            if (act) {
#pragma unroll
                for (int kk = 0; kk < 2; kk++) {
                    bf16x8 af[4], bfr[4];
#pragma unroll
                    for (int i = 0; i < 4; i++)
                        af[i] = *(const bf16x8*)(sA + (wm + i * 16 + mrow) * 64 + kk * 32 + kq);
#pragma unroll
                    for (int j = 0; j < 4; j++)
                        bfr[j] = *(const bf16x8*)(sB + (wn + j * 16 + mrow) * 64 + kk * 32 + kq);
#pragma unroll
                    for (int i = 0; i < 4; i++)
#pragma unroll
                        for (int j = 0; j < 4; j++)
                            acc[i][j] = __builtin_amdgcn_mfma_f32_16x16x32_bf16(af[i], bfr[j], acc[i][j], 0, 0, 0);
                }
            }
            __syncthreads();
        }
        if (act) {
            const int r0 = (lane >> 4) * 4;
            const int cn = lane & 15;
#pragma unroll
            for (int i = 0; i < 4; i++) {
#pragma unroll
                for (int r = 0; r < 4; r++) {
                    int row = bm * 128 + wm + i * 16 + r0 + r;
                    unsigned short* Crow = gout + (size_t)row * 2048 + bn * 128 + wn + cn;
#pragma unroll
                    for (int j = 0; j < 4; j++) Crow[j * 16] = f2bf(acc[i][j][r]);
                }
            }
        }
        return;
    }

    // ---------------- scan block: (b, h, vq) — vq owns v-cols [vq*32, vq*32+32)
    const int vq  = blk & 3;
    const int bh  = blk >> 2;
    const int b   = bh >> 4;
    const int h   = bh & 15;

    float* sqb  = (float*)smem_raw;                 // [2][CT_*68]
    float* skb  = sqb + 2 * CT_ * 68;
    float* svb  = skb + 2 * CT_ * 68;               // [2][CT_*33]
    float* sgb  = svb + 2 * CT_ * 33;               // [2][CT_]
    float* sbb  = sgb + 2 * CT_;
    float* vcar = sbb + 2 * CT_;                    // [2][3*32]

    const size_t qbase = (size_t)b * T_ * 2048 + h * 64;
    const size_t kbase = qbase + 1024;
    const size_t vbase = (size_t)b * T_ * 2048 + h * 128 + vq * 32;
    const size_t gbase = (size_t)b * T_ * H_ + h;

    const bool is_cons = (tid < 256);

    // producer locals (waves 4-7): wave pw owns rows 8*pw..8*pw+7; col pc (q/k 64-wide;
    // v handled by pc<32)
    const int ptid = tid - 256;
    const int pc   = ptid & 63;
    const int pw   = ptid >> 6;
    const int R0   = pw * 8;
    float wqa[4], wka[4], wva[4];
    if (!is_cons) {
        float4 a4 = *(const float4*)(qcw + (size_t)(h * 64 + pc) * 4);
        float4 b4 = *(const float4*)(kcw + (size_t)(h * 64 + pc) * 4);
        wqa[0]=a4.x; wqa[1]=a4.y; wqa[2]=a4.z; wqa[3]=a4.w;
        wka[0]=b4.x; wka[1]=b4.y; wka[2]=b4.z; wka[3]=b4.w;
        if (pc < 32) {
            float4 c4 = *(const float4*)(vcw + (size_t)(h * 128 + vq * 32 + pc) * 4);
            wva[0]=c4.x; wva[1]=c4.y; wva[2]=c4.z; wva[3]=c4.w;
        }
    }

    auto stage = [&](int ci) {
        const int rp  = ci & 1;
        const int tcc = ci * CT_;
        float* dq = sqb + rp * (CT_ * 68);
        float* dk = skb + rp * (CT_ * 68);
        float* dv = svb + rp * (CT_ * 33);
        float qin[11], kin[11], vin[11];
#pragma unroll
        for (int j = 0; j < 11; j++) {
            int rr = tcc + R0 - 3 + j;
            bool ok = (rr >= 0);
            qin[j] = ok ? qk[qbase + (size_t)rr * 2048 + pc] : 0.f;
            kin[j] = ok ? qk[kbase + (size_t)rr * 2048 + pc] : 0.f;
        }
        if (pc < 32) {
            if (pw == 0) {
#pragma unroll
                for (int j = 0; j < 3; j++) vin[j] = vcar[(rp ^ 1) * 96 + j * 32 + pc];
#pragma unroll
                for (int j = 3; j < 11; j++) vin[j] = vbuf[vbase + (size_t)(tcc + j - 3) * 2048 + pc];
            } else {
#pragma unroll
                for (int j = 0; j < 11; j++) vin[j] = vbuf[vbase + (size_t)(tcc + R0 - 3 + j) * 2048 + pc];
            }
            if (pw == 3) {   // capture fresh v rows 29..31 for next chunk's causal window
#pragma unroll
                for (int j = 0; j < 3; j++) vcar[rp * 96 + j * 32 + pc] = vin[8 + j];
            }
        }
#pragma unroll
        for (int it = 0; it < 8; it++) {
            const int r = R0 + it;
            float aq = 0.f, ak = 0.f;
#pragma unroll
            for (int j = 0; j < 4; j++) {
                aq += wqa[j] * qin[it + j];
                ak += wka[j] * kin[it + j];
            }
            dq[r * 68 + pc] = siluf(aq);
            dk[r * 68 + pc] = siluf(ak);
            if (pc < 32) {
                float av = 0.f;
#pragma unroll
                for (int j = 0; j < 4; j++) av += wva[j] * vin[it + j];
                dv[r * 33 + pc] = siluf(av);
            }
        }
        if (ptid < CT_)          sgb[rp * CT_ + ptid]       = expf(g[gbase + (size_t)(tcc + ptid) * H_]);
        else if (ptid < 2 * CT_) sbb[rp * CT_ + ptid - CT_] = beta[gbase + (size_t)(tcc + ptid - CT_) * H_];
        // l2norm: same wave's rows (wave-internal LDS ordering guarantees conv writes visible)
        {
            const int rl = R0 + (pc >> 3);
            const int jc = pc & 7;
            float* kr = dk + rl * 68 + jc * 8;
            float* qr = dq + rl * 68 + jc * 8;
            float4 k0 = ((const float4*)kr)[0], k1 = ((const float4*)kr)[1];
            float4 q0 = ((const float4*)qr)[0], q1 = ((const float4*)qr)[1];
            float ssk = k0.x*k0.x + k0.y*k0.y + k0.z*k0.z + k0.w*k0.w
                      + k1.x*k1.x + k1.y*k1.y + k1.z*k1.z + k1.w*k1.w;
            float ssq = q0.x*q0.x + q0.y*q0.y + q0.z*q0.z + q0.w*q0.w
                      + q1.x*q1.x + q1.y*q1.y + q1.z*q1.z + q1.w*q1.w;
            ssk += __shfl_xor(ssk, 1); ssk += __shfl_xor(ssk, 2); ssk += __shfl_xor(ssk, 4);
            ssq += __shfl_xor(ssq, 1); ssq += __shfl_xor(ssq, 2); ssq += __shfl_xor(ssq, 4);
            float rk_ = rsqrtf(ssk + 1e-6f);
            float rq_ = rsqrtf(ssq + 1e-6f) * 0.125f;   // fold SCALE = DK^-0.5
            k0.x*=rk_; k0.y*=rk_; k0.z*=rk_; k0.w*=rk_;
            k1.x*=rk_; k1.y*=rk_; k1.z*=rk_; k1.w*=rk_;
            q0.x*=rq_; q0.y*=rq_; q0.z*=rq_; q0.w*=rq_;
            q1.x*=rq_; q1.y*=rq_; q1.z*=rq_; q1.w*=rq_;
            ((float4*)kr)[0] = k0; ((float4*)kr)[1] = k1;
            ((float4*)qr)[0] = q0; ((float4*)qr)[1] = q1;
        }
    };

    // consumer locals (waves 0-3): 8-lane k-split
    const int dkq = tid & 7;
    const int dvl = (tid >> 3) & 31;
    const int dk0 = dkq * 8;
    float S[8];
#pragma unroll
    for (int i = 0; i < 8; i++) S[i] = 0.f;

    if (!is_cons) {
        if (pw == 0 && pc < 32) {   // zero the carry buffer chunk 0 reads (same-thread order)
#pragma unroll
            for (int j = 0; j < 3; j++) vcar[96 + j * 32 + pc] = 0.f;
        }
        stage(0);
    }
    __syncthreads();

    for (int ci = 0; ci < NCH_; ci++) {
        const int p  = ci & 1;
        const int tc = ci * CT_;
        const float* sqp  = sqb + p * (CT_ * 68);
        const float* skp  = skb + p * (CT_ * 68);
        const float* svp  = svb + p * (CT_ * 33);
        const float* sgp_ = sgb + p * CT_;
        const float* sbp_ = sbb + p * CT_;

        if (is_cons) { CONSUME_GROUP8(0, CT_); }
        else if (ci + 1 < NCH_) stage(ci + 1);
        __syncthreads();
    }
}

// ---------------------------------------------------------------- legacy 3-phase scan (ws-tight fallback)
__global__ __launch_bounds__(512)
void scan_fused(const float* __restrict__ qk, float* __restrict__ vbuf,
                const float* __restrict__ qcw, const float* __restrict__ kcw, const float* __restrict__ vcw,
                const float* __restrict__ g, const float* __restrict__ beta) {
    int blk = blockIdx.x;
    int vh  = blk & 1;
    int bh  = blk >> 1;
    int b   = bh >> 4;
    int h   = bh & 15;
    int tid = threadIdx.x;

    __shared__ __align__(16) float rawq[2][(CT_ + 3) * 64];
    __shared__ __align__(16) float rawk[2][(CT_ + 3) * 64];
    __shared__ __align__(16) float rawv[2][(CT_ + 3) * 64];
    __shared__ __align__(16) float sq[2][CT_ * 68];
    __shared__ __align__(16) float sk[2][CT_ * 68];
    __shared__ __align__(16) float sv[2][CT_ * 68];
    __shared__ float sg[2][CT_];
    __shared__ float sb[2][CT_];

    const size_t qbase = (size_t)b * T_ * 2048 + h * 64;
    const size_t kbase = qbase + 1024;
    const size_t vbase = (size_t)b * T_ * 2048 + h * 128 + vh * 64;
    const size_t gbase = (size_t)b * T_ * H_ + h;

    const bool is_cons = (tid < 256);

    const int ptid = tid - 256;
    const int pc   = ptid & 63;
    const int pw   = ptid >> 6;
    float wqa[4], wka[4], wva[4];
    if (!is_cons) {
        float4 a4 = *(const float4*)(qcw + (size_t)(h * 64 + pc) * 4);
        float4 b4 = *(const float4*)(kcw + (size_t)(h * 64 + pc) * 4);
        float4 c4 = *(const float4*)(vcw + (size_t)(h * 128 + vh * 64 + pc) * 4);
        wqa[0]=a4.x; wqa[1]=a4.y; wqa[2]=a4.z; wqa[3]=a4.w;
        wka[0]=b4.x; wka[1]=b4.y; wka[2]=b4.z; wka[3]=b4.w;
        wva[0]=c4.x; wva[1]=c4.y; wva[2]=c4.z; wva[3]=c4.w;
        if (ptid < 192) {
            int bsel = ptid >> 6, c = ptid & 63;
            float* rb = bsel == 0 ? rawq[1] : (bsel == 1 ? rawk[1] : rawv[1]);
#pragma unroll
            for (int j = 0; j < 3; j++) rb[(CT_ + j) * 64 + c] = 0.f;
        }
    }

    auto prod_phase1 = [&](int ci) {
        int rp = ci & 1;
        int tcc = ci * CT_;
        float* rq = rawq[rp]; float* rk = rawk[rp]; float* rv = rawv[rp];
        const float* pq = rawq[rp ^ 1]; const float* pk = rawk[rp ^ 1]; const float* pv = rawv[rp ^ 1];
        if (ptid < 192) {
            int bsel = ptid >> 6, c = ptid & 63;
            float*       db = bsel == 0 ? rq : (bsel == 1 ? rk : rv);
            const float* sc = bsel == 0 ? pq : (bsel == 1 ? pk : pv);
#pragma unroll
            for (int j = 0; j < 3; j++) db[j * 64 + c] = sc[(CT_ + j) * 64 + c];
        }
#pragma unroll
        for (int u = 0; u < 2; u++) {
            int idx = u * 256 + ptid;
            int r   = idx >> 4;
            int c4  = (idx & 15) * 4;
            size_t row = (size_t)(tcc + r) * 2048;
            *(float4*)(rq + (3 + r) * 64 + c4) = *(const float4*)(qk + qbase + row + c4);
            *(float4*)(rk + (3 + r) * 64 + c4) = *(const float4*)(qk + kbase + row + c4);
            *(float4*)(rv + (3 + r) * 64 + c4) = *(const float4*)(vbuf + vbase + row + c4);
        }
        if (ptid < CT_)          sg[rp][ptid]       = expf(g[gbase + (size_t)(tcc + ptid) * H_]);
        else if (ptid < 2 * CT_) sb[rp][ptid - CT_] = beta[gbase + (size_t)(tcc + ptid - CT_) * H_];
    };

    auto prod_phase2 = [&](int ci) {
        int rp = ci & 1;
        const float* rq = rawq[rp]; const float* rk = rawk[rp]; const float* rv = rawv[rp];
        float* dq = sq[rp]; float* dk = sk[rp]; float* dv = sv[rp];
#pragma unroll
        for (int it = 0; it < 8; it++) {
            int r = pw + it * 4;
            float aq = 0.f, ak = 0.f, av = 0.f;
#pragma unroll
            for (int j = 0; j < 4; j++) {
                aq += wqa[j] * rq[(r + j) * 64 + pc];
                ak += wka[j] * rk[(r + j) * 64 + pc];
                av += wva[j] * rv[(r + j) * 64 + pc];
            }
            dq[r * 68 + pc] = siluf(aq);
            dk[r * 68 + pc] = siluf(ak);
            dv[r * 68 + pc] = siluf(av);
        }
    };

    auto prod_phase3 = [&](int ci) {
        int rp = ci & 1;
        int r = ptid >> 3;
        int j = ptid & 7;
        float* kr = sk[rp] + r * 68 + j * 8;
        float* qr = sq[rp] + r * 68 + j * 8;
        float4 k0 = ((const float4*)kr)[0], k1 = ((const float4*)kr)[1];
        float4 q0 = ((const float4*)qr)[0], q1 = ((const float4*)qr)[1];
        float ssk = k0.x*k0.x + k0.y*k0.y + k0.z*k0.z + k0.w*k0.w
                  + k1.x*k1.x + k1.y*k1.y + k1.z*k1.z + k1.w*k1.w;
        float ssq = q0.x*q0.x + q0.y*q0.y + q0.z*q0.z + q0.w*q0.w
                  + q1.x*q1.x + q1.y*q1.y + q1.z*q1.z + q1.w*q1.w;
        ssk += __shfl_xor(ssk, 1); ssk += __shfl_xor(ssk, 2); ssk += __shfl_xor(ssk, 4);
        ssq += __shfl_xor(ssq, 1); ssq += __shfl_xor(ssq, 2); ssq += __shfl_xor(ssq, 4);
        float rk_ = rsqrtf(ssk + 1e-6f);
        float rq_ = rsqrtf(ssq + 1e-6f) * 0.125f;
        k0.x*=rk_; k0.y*=rk_; k0.z*=rk_; k0.w*=rk_;
        k1.x*=rk_; k1.y*=rk_; k1.z*=rk_; k1.w*=rk_;
        q0.x*=rq_; q0.y*=rq_; q0.z*=rq_; q0.w*=rq_;
        q1.x*=rq_; q1.y*=rq_; q1.z*=rq_; q1.w*=rq_;
        ((float4*)kr)[0] = k0; ((float4*)kr)[1] = k1;
        ((float4*)qr)[0] = q0; ((float4*)qr)[1] = q1;
    };

    const int dkq = tid & 3;
    const int dvl = tid >> 2;
    const int dk0 = dkq * 16;
    float S[16];
#pragma unroll
    for (int i = 0; i < 16; i++) S[i] = 0.f;

    if (!is_cons) prod_phase1(0);
    __syncthreads();
    if (!is_cons) prod_phase2(0);
    __syncthreads();
    if (!is_cons) prod_phase3(0);
    __syncthreads();

    for (int ci = 0; ci < NCH_; ci++) {
        const int p  = ci & 1;
        const int tc = ci * CT_;
        const float* sqp  = sq[p];
        const float* skp  = sk[p];
        const float* svp  = sv[p];
        const float* sgp_ = sg[p];
        const float* sbp_ = sb[p];

        if (is_cons) { CONSUME_GROUP(0, 11); }
        else if (ci + 1 < NCH_) prod_phase1(ci + 1);
        __syncthreads();
        if (is_cons) { CONSUME_GROUP(11, 22); }
        else if (ci + 1 < NCH_) prod_phase2(ci + 1);
        __syncthreads();
        if (is_cons) { CONSUME_GROUP(22, 32); }
        else if (ci + 1 < NCH_) prod_phase3(ci + 1);
        __syncthreads();
    }
}

// ---------------------------------------------------------------- postnorm: rms(o)*silu(g_out) -> og bf16
__global__ __launch_bounds__(256)
void postnorm_k(float* __restrict__ vbuf, const unsigned short* __restrict__ gout) {
    int bt  = blockIdx.x;
    int tid = threadIdx.x;
    const float* orow = vbuf + (size_t)bt * 2048 + tid * 8;
    float4 a = ((const float4*)orow)[0];
    float4 c = ((const float4*)orow)[1];
    float ss = a.x*a.x + a.y*a.y + a.z*a.z + a.w*a.w
             + c.x*c.x + c.y*c.y + c.z*c.z + c.w*c.w;
    ss += __shfl_xor(ss, 1); ss += __shfl_xor(ss, 2); ss += __shfl_xor(ss, 4); ss += __shfl_xor(ss, 8);
    float rms = rsqrtf(ss * (1.f / 128.f) + 1.1920928955078125e-07f);
    const unsigned short* grow = gout + (size_t)bt * 2048 + tid * 8;
    ushort4 g1 = ((const ushort4*)grow)[0];
    ushort4 g2 = ((const ushort4*)grow)[1];
    ushort4 r0, r1;
    r0.x = f2bf(a.x * rms * siluf(bf2f(g1.x)));
    r0.y = f2bf(a.y * rms * siluf(bf2f(g1.y)));
    r0.z = f2bf(a.z * rms * siluf(bf2f(g1.z)));
    r0.w = f2bf(a.w * rms * siluf(bf2f(g1.w)));
    r1.x = f2bf(c.x * rms * siluf(bf2f(g2.x)));
    r1.y = f2bf(c.y * rms * siluf(bf2f(g2.y)));
    r1.z = f2bf(c.z * rms * siluf(bf2f(g2.z)));
    r1.w = f2bf(c.w * rms * siluf(bf2f(g2.w)));
    __syncthreads();   // all reads of this row done before in-place overwrite
    unsigned short* og = (unsigned short*)vbuf + (size_t)bt * 4096 + tid * 8;
    *(ushort4*)og       = r0;
    *(ushort4*)(og + 4) = r1;
}

// ---------------------------------------------------------------- launch
// CLEAN layout (needs ws >= 177 MiB):
//   [0,32)    xh      [32,64)  xl  (xl reused as g_out bf16 after gemm_dual_gates)
//   [64,72)   qkw_h   [72,80)  qkw_l
//   [80,96)   vgw_h (v rows then g rows)   [96,104) vgw_l (v-half)
//   [104,112) ow_bf
//   [112,176) vbuf f32 (v -> o in-place -> og bf16 stride 4096)
//   [176,177) gbuf, bbuf
extern "C" void kernel_launch(void* const* d_in, const int* in_sizes, int n_in,
                              void* d_out, int out_size, void* d_ws, size_t ws_size,
                              hipStream_t stream) {
    (void)in_sizes; (void)n_in; (void)out_size;
    const float* x        = (const float*)d_in[0];
    const float* qk_w     = (const float*)d_in[1];
    const float* vg_w     = (const float*)d_in[2];
    const float* o_w      = (const float*)d_in[3];
    const float* a_w      = (const float*)d_in[4];
    const float* b_w      = (const float*)d_in[5];
    const float* b_bias   = (const float*)d_in[6];
    const float* beta_b   = (const float*)d_in[7];
    const float* A_log    = (const float*)d_in[8];
    const float* dt_bias  = (const float*)d_in[9];
    const float* q_conv_w = (const float*)d_in[10];
    const float* k_conv_w = (const float*)d_in[11];
    const float* v_conv_w = (const float*)d_in[12];

    char* ws = (char*)d_ws;
    float* qkf            = (float*)d_out;
    float* outp           = (float*)d_out;

    if (ws_size >= (size_t)177u * 1024u * 1024u) {
        unsigned short* xh    = (unsigned short*)(ws);
        unsigned short* xl    = (unsigned short*)(ws + (32u << 20));
        unsigned short* qkw_h = (unsigned short*)(ws + (64u << 20));
        unsigned short* qkw_l = (unsigned short*)(ws + (72u << 20));
        unsigned short* vgw_h = (unsigned short*)(ws + (80u << 20));
        unsigned short* vgw_l = (unsigned short*)(ws + (96u << 20));
        unsigned short* ow_bf = (unsigned short*)(ws + (104u << 20));
        float*          vbuf  = (float*)(ws + (112u << 20));
        float*          gbuf  = (float*)(ws + (176u << 20));
        float*          bbuf  = (float*)(ws + (176u << 20) + (512u << 10));
        unsigned short* goutb = xl;   // g_out bf16 overwrites xl (dead after gemm_dual_gates)

        // 1) all casts, one launch
        {
            const int NTOT = BT_ * C_ / 4 + 4 * (2048 * 2048 / 4);   // 8,388,608
            cast_all_k<<<NTOT / 256, 256, 0, stream>>>(x, qk_w, vg_w, o_w,
                xh, xl, qkw_h, qkw_l, vgw_h, vgw_l, ow_bf);
        }

        // 2) dual DO_LO GEMM (XCD-swizzled) + gates fused: qk -> d_out, v -> vbuf, g/beta
        gemm_dual_gates<<<2048 + BT_, 256, 0, stream>>>(
            xh, xl, qkw_h, qkw_l, qkf, vgw_h, vgw_l, vbuf,
            x, a_w, b_w, b_bias, beta_b, A_log, dt_bias, gbuf, bbuf);

        // 3) fused scan (256 blocks, 8-lane k-split) + g_out GEMM (hidden; writes over xl)
        {
            const int scan_lds = (2*CT_*68 + 2*CT_*68 + 2*CT_*33 + 2*CT_ + 2*CT_ + 2*3*32) * 4; // 44,544 B
            scan_gemm_k<<<256 + 1024, 512, scan_lds, stream>>>(
                qkf, vbuf, q_conv_w, k_conv_w, v_conv_w, gbuf, bbuf,
                xh, vgw_h + (size_t)2048 * 2048, goutb);
        }

        // 4) postnorm -> og bf16 in-place over vbuf (stride 4096 ushort)
        postnorm_k<<<BT_, 256, 0, stream>>>(vbuf, goutb);

        // 5) final GEMM: og @ o_w.T -> d_out f32
        gemm_bf<false, true><<<dim3(16, 64), 256, 0, stream>>>(
            (const unsigned short*)vbuf, nullptr, 4096, ow_bf, nullptr, outp, BT_, 2048, 2048);
    } else {
        // ---------------- LEGACY path (121 MiB)
        unsigned short* qkw_h = (unsigned short*)(ws);
        unsigned short* qkw_l = (unsigned short*)(ws + (8u  << 20));
        unsigned short* vgw_h = (unsigned short*)(ws + (16u << 20));
        unsigned short* vgw_l = (unsigned short*)(ws + (32u << 20));
        unsigned short* ow_bf = (unsigned short*)(ws + (48u << 20));
        float*          vbuf  = (float*)(ws + (56u << 20));
        float*          gbuf  = (float*)(ws + (120u << 20));
        float*          bbuf  = (float*)(ws + (120u << 20) + (512u << 10));
        unsigned short* goutb = (unsigned short*)d_out;

        cast_split_k<<<(2048 * 2048 / 4 + 255) / 256, 256, 0, stream>>>(qk_w, qkw_h, qkw_l, 2048 * 2048 / 4);
        cast_split_k<<<(2048 * 2048 / 4 + 255) / 256, 256, 0, stream>>>(vg_w, vgw_h, vgw_l, 2048 * 2048 / 4);
        cast_plain_k<<<(2048 * 2048 / 4 + 255) / 256, 256, 0, stream>>>(
            vg_w + (size_t)2048 * 2048, vgw_h + (size_t)2048 * 2048, 2048 * 2048 / 4);
        cast_plain_k<<<(2048 * 2048 / 4 + 255) / 256, 256, 0, stream>>>(o_w, ow_bf, 2048 * 2048 / 4);

        gemm_pc<true, true, true><<<dim3(16, 64), 512, 0, stream>>>(x, 2048, qkw_h, qkw_l, qkf, BT_, 2048, 2048);
        gemm_pc<true, true, true><<<dim3(16, 64), 512, 0, stream>>>(x, 2048, vgw_h, vgw_l, vbuf, BT_, 2048, 2048);

        gates_k<<<BT_, 256, 0, stream>>>(x, a_w, b_w, b_bias, beta_b, A_log, dt_bias, gbuf, bbuf);

        scan_fused<<<B_ * H_ * 2, 512, 0, stream>>>(qkf, vbuf, q_conv_w, k_conv_w, v_conv_w, gbuf, bbuf);

        gemm_pc<false, false, true><<<dim3(16, 64), 512, 0, stream>>>(
            x, 2048, vgw_h + (size_t)2048 * 2048, nullptr, goutb, BT_, 2048, 2048);

        postnorm_k<<<BT_, 256, 0, stream>>>(vbuf, goutb);

        gemm_pc<false, true, false><<<dim3(16, 64), 512, 0, stream>>>(
            (const void*)vbuf, 4096, ow_bf, nullptr, outp, BT_, 2048, 2048);
    }
}